// Round 6
// baseline (1013.915 us; speedup 1.0000x reference)
//
#include <hip/hip_runtime.h>
#include <math.h>

// ---------------- problem constants ----------------
constexpr int cB  = 32;     // batch
constexpr int cC  = 62;     // channels (graph nodes)
constexpr int cT  = 1024;   // time
constexpr int cNT = 32;     // temporal filters
constexpr int cLT = 708;    // concat conv-pool length (247+240+221)
constexpr int cLT2= 354;    // after avgpool(1,2)
constexpr int cFD = 11328;  // NT * 354
constexpr int cNBC = cB*cC; // 1984 blocks for per-(b,c) kernels

// element counts
constexpr size_t FEAT_N = (size_t)cB*cNT*cC*cLT;   // ~180 MB - conv logs, then in-place pooled mix
constexpr size_t P_N    = (size_t)cB*cC*cC;        // raw gram V V^T
constexpr size_t Q_N    = (size_t)cB*cC*96;        // raw V @ [entry_w|pool_w]
constexpr size_t R_N    = (size_t)cB*64;           // rowsums of V
constexpr size_t PART_N = (size_t)cNBC*64;
constexpr size_t ADJ_N  = P_N;
constexpr size_t HE_N   = (size_t)cB*cC*64;
constexpr size_t HP_N   = (size_t)cB*cC*32;
constexpr size_t HPRE_N = (size_t)cB*32*64;
constexpr size_t WPAD_N = 32*28 + 32*52 + 32*128;  // 6656 padded weights

// ---------------- prep: pad conv weights + wcol[j] = sum_k W[k][j] ----------------
__global__ __launch_bounds__(256) void k_prep(
    const float* __restrict__ w1, const float* __restrict__ w2,
    const float* __restrict__ w3, const float* __restrict__ entry_w,
    const float* __restrict__ pool_w, float* __restrict__ wpad,
    float* __restrict__ wcol)
{
  int blk = blockIdx.x, tid = threadIdx.x;
  if (blk < 26){
    int i = blk*256 + tid;
    if (i < 896){ int t=i/28, k=i-t*28; wpad[i] = (k<25) ? w1[t*25+k] : 0.f; }
    else if (i < 2560){ int j=i-896; int t=j/52, k=j-t*52; wpad[i] = (k<51) ? w2[t*51+k] : 0.f; }
    else if (i < 6656){ wpad[i] = w3[i-2560]; }
  } else {
    int j = blk - 26;          // 0..95
    float s = 0.f;
    if (j < 64){ for (int k=tid;k<cFD;k+=256) s += entry_w[(size_t)k*64 + j]; }
    else       { for (int k=tid;k<cFD;k+=256) s += pool_w[(size_t)k*32 + (j-64)]; }
    __shared__ float red[256];
    red[tid]=s; __syncthreads();
    for (int o=128;o>0;o>>=1){ if(tid<o) red[tid]+=red[tid+o]; __syncthreads(); }
    if (tid==0) wcol[j] = red[0];
  }
}

// ---------------- conv core: 8 filters x 4 positions per lane ----------------
// one ds_read_b128 feeds 128 FMA; weights via wave-uniform scalar loads.
template<int K4, int L, int G>
__device__ __forceinline__ void conv8(
    const float* xs, const float* __restrict__ wg, const float* __restrict__ bg,
    float* pt, int tid)
{
  if (tid >= G) return;
  int pos = 4*tid;
  float4 c = *(const float4*)&xs[pos];
  float x0=c.x, x1=c.y, x2=c.z, x3=c.w;
  float a[8][4];
  #pragma unroll
  for (int f=0;f<8;f++){ float bv=bg[f]; a[f][0]=bv; a[f][1]=bv; a[f][2]=bv; a[f][3]=bv; }
  #pragma unroll 2
  for (int i=0;i<K4;i+=4){
    float4 n = *(const float4*)&xs[pos+4+i];    // 16B-aligned, 16B/lane stride
    #pragma unroll
    for (int f=0;f<8;f++){
      const float* w = wg + f*K4 + i;           // wave-uniform -> scalar loads
      float w0=w[0], w1=w[1], w2=w[2], w3=w[3];
      a[f][0]=fmaf(x0,w0,a[f][0]); a[f][1]=fmaf(x1,w0,a[f][1]); a[f][2]=fmaf(x2,w0,a[f][2]); a[f][3]=fmaf(x3,w0,a[f][3]);
      a[f][0]=fmaf(x1,w1,a[f][0]); a[f][1]=fmaf(x2,w1,a[f][1]); a[f][2]=fmaf(x3,w1,a[f][2]); a[f][3]=fmaf(n.x,w1,a[f][3]);
      a[f][0]=fmaf(x2,w2,a[f][0]); a[f][1]=fmaf(x3,w2,a[f][1]); a[f][2]=fmaf(n.x,w2,a[f][2]); a[f][3]=fmaf(n.y,w2,a[f][3]);
      a[f][0]=fmaf(x3,w3,a[f][0]); a[f][1]=fmaf(n.x,w3,a[f][1]); a[f][2]=fmaf(n.y,w3,a[f][2]); a[f][3]=fmaf(n.z,w3,a[f][3]);
    }
    x0=n.x; x1=n.y; x2=n.z; x3=n.w;
  }
  #pragma unroll
  for (int f=0;f<8;f++){
    float p = (pos   < L ? a[f][0]*a[f][0] : 0.f)
            + (pos+1 < L ? a[f][1]*a[f][1] : 0.f)
            + (pos+2 < L ? a[f][2]*a[f][2] : 0.f)
            + (pos+3 < L ? a[f][3]*a[f][3] : 0.f);
    pt[f*256 + tid] = p;
  }
}

__global__ __launch_bounds__(256) void k_conv(
    const float* __restrict__ x,
    const float* __restrict__ wpad,
    const float* __restrict__ b1, const float* __restrict__ b2, const float* __restrict__ b3,
    float* __restrict__ feat, float* __restrict__ part1)
{
  __shared__ float xs[1152];
  __shared__ float pt1[2048], pt2[2048], pt3[2048];
  __shared__ float tsum[32], tsq[32];
  int b = blockIdx.x / cC, c = blockIdx.x % cC;
  int tid = threadIdx.x;
  for (int i=tid;i<1152;i+=256) xs[i] = (i<1024) ? x[(size_t)(b*cC+c)*cT + i] : 0.f;
  if (tid<32){ tsum[tid]=0.f; tsq[tid]=0.f; }
  for (int t0=0; t0<32; t0+=8){
    __syncthreads();
    conv8<28,1000,250>(xs, wpad + t0*28,        b1+t0, pt1, tid);
    conv8<52,974,244> (xs, wpad + 896 + t0*52,  b2+t0, pt2, tid);
    conv8<128,897,225>(xs, wpad + 2560 + t0*128,b3+t0, pt3, tid);
    __syncthreads();
    size_t base0 = ((size_t)(b*cNT+t0)*cC + c)*cLT;
    float val[8]={0,0,0,0,0,0,0,0}, vsq[8]={0,0,0,0,0,0,0,0};
    if (tid<247){
      #pragma unroll
      for (int f=0;f<8;f++){
        float p = (pt1[f*256+tid]+pt1[f*256+tid+1]+pt1[f*256+tid+2]+pt1[f*256+tid+3])*(1.f/16.f);
        float lv = __logf(p);
        feat[base0 + (size_t)f*cC*cLT + tid] = lv;
        val[f]+=lv; vsq[f]+=lv*lv;
      }
    }
    if (tid<240){
      #pragma unroll
      for (int f=0;f<8;f++){
        float p = (pt2[f*256+tid]+pt2[f*256+tid+1]+pt2[f*256+tid+2]+pt2[f*256+tid+3])*(1.f/16.f);
        float lv = __logf(p);
        feat[base0 + (size_t)f*cC*cLT + 247 + tid] = lv;
        val[f]+=lv; vsq[f]+=lv*lv;
      }
    }
    if (tid<221){
      #pragma unroll
      for (int f=0;f<8;f++){
        float p = (pt3[f*256+tid]+pt3[f*256+tid+1]+pt3[f*256+tid+2]+pt3[f*256+tid+3])*(1.f/16.f);
        float lv = __logf(p);
        feat[base0 + (size_t)f*cC*cLT + 487 + tid] = lv;
        val[f]+=lv; vsq[f]+=lv*lv;
      }
    }
    #pragma unroll
    for (int f=0;f<8;f++){
      float v=val[f], q=vsq[f];
      #pragma unroll
      for (int o=32;o>0;o>>=1){ v += __shfl_down(v,o,64); q += __shfl_down(q,o,64); }
      if ((tid&63)==0){ atomicAdd(&tsum[t0+f], v); atomicAdd(&tsq[t0+f], q); }
    }
  }
  __syncthreads();
  if (tid<32){
    part1[(size_t)blockIdx.x*64 + tid*2]   = tsum[tid];
    part1[(size_t)blockIdx.x*64 + tid*2+1] = tsq[tid];
  }
}

// ---------------- partial-stat reduction: [nblk][nch][2] f32 -> [nch][2] f64 ----------------
__global__ __launch_bounds__(256) void k_reduce_stats(
    const float* __restrict__ part, double* __restrict__ stat, int nblk, int nch)
{
  int ch = blockIdx.x, tid = threadIdx.x;
  double s=0,q=0;
  for (int i=tid;i<nblk;i+=256){
    s += (double)part[(size_t)i*nch*2 + ch*2];
    q += (double)part[(size_t)i*nch*2 + ch*2 + 1];
  }
  __shared__ double ls[256], lq[256];
  ls[tid]=s; lq[tid]=q; __syncthreads();
  for (int o=128;o>0;o>>=1){ if(tid<o){ls[tid]+=ls[tid+o]; lq[tid]+=lq[tid+o];} __syncthreads(); }
  if (tid==0){ stat[ch*2]=ls[0]; stat[ch*2+1]=lq[0]; }
}

// ---------------- BN_t + 1x1 conv + leaky + avgpool(1,2)  --- IN-PLACE, conflict-free ----------------
__global__ __launch_bounds__(256) void k_mix(
    float* __restrict__ feat, const double* __restrict__ stat1,
    const float* __restrict__ oxo_w, const float* __restrict__ oxo_b,
    float* __restrict__ part2)
{
  __shared__ float ft[32*122];
  __shared__ float vout[32*60];
  __shared__ float mvm[32], mvi[32];
  __shared__ float osum[32], osq[32];
  int b = blockIdx.x / cC, c = blockIdx.x % cC;
  int tid = threadIdx.x;
  int o = tid >> 3, lg = tid & 7;
  float wreg[32];
  #pragma unroll
  for (int t=0;t<32;t+=4){
    float4 w4 = *(const float4*)&oxo_w[o*32+t];
    wreg[t]=w4.x; wreg[t+1]=w4.y; wreg[t+2]=w4.z; wreg[t+3]=w4.w;
  }
  if (tid<32){
    double cnt = (double)cB*cC*cLT;
    double m = stat1[tid*2]/cnt;
    double v = stat1[tid*2+1]/cnt - m*m;
    mvm[tid] = (float)m;
    mvi[tid] = (float)(1.0/sqrt(v+1e-5));
    osum[tid]=0.f; osq[tid]=0.f;
  }
  float ob = oxo_b[o];
  float accs=0.f, accq=0.f;
  for (int ch=0; ch<6; ch++){
    __syncthreads();
    int l0 = ch*118;
    for (int i=tid;i<32*118;i+=256){
      int t = i/118, l = i-t*118;
      ft[t*122+l] = (feat[((size_t)(b*cNT+t)*cC + c)*cLT + l0 + l] - mvm[t]) * mvi[t];
    }
    __syncthreads();
    for (int l2=lg; l2<59; l2+=8){
      float m0=ob, m1=ob;
      #pragma unroll
      for (int t=0;t<32;t++){
        float2 f2 = *(const float2*)&ft[t*122 + 2*l2];
        m0 = fmaf(f2.x, wreg[t], m0);
        m1 = fmaf(f2.y, wreg[t], m1);
      }
      m0 = m0>0.f ? m0 : 0.01f*m0;
      m1 = m1>0.f ? m1 : 0.01f*m1;
      float v = 0.5f*(m0+m1);
      vout[o*60 + l2] = v;
      accs += v; accq += v*v;
    }
    __syncthreads();
    for (int i=tid;i<1888;i+=256){
      int o2 = i/59, l2 = i - o2*59;
      feat[((size_t)(b*cNT+o2)*cC + c)*cLT + ch*59 + l2] = vout[o2*60+l2];
    }
  }
  atomicAdd(&osum[o], accs);
  atomicAdd(&osq[o], accq);
  __syncthreads();
  if (tid<32){
    part2[(size_t)blockIdx.x*64 + tid*2]   = osum[tid];
    part2[(size_t)blockIdx.x*64 + tid*2+1] = osq[tid];
  }
}

// ---------------- raw gram/ow/rowsum: P = V V^T, Q = V W, r = V 1 ----------------
__global__ __launch_bounds__(256) void k_gramow(
    const float* __restrict__ featbuf, const double* __restrict__ stat2,
    const float* __restrict__ lf_w, const float* __restrict__ lf_b,
    const float* __restrict__ entry_w, const float* __restrict__ pool_w,
    float* __restrict__ P, float* __restrict__ Q, float* __restrict__ r_g)
{
  __shared__ float lt[64*68];
  __shared__ float lw[64*100];
  __shared__ float a_s[32], b_s[32];
  __shared__ float lbs[64];
  int b = blockIdx.x >> 5, ks = blockIdx.x & 31;
  int tid = threadIdx.x;
  if (tid<32){
    double cnt = (double)cB*cC*cLT2;
    double m = stat2[tid*2]/cnt;
    double v = stat2[tid*2+1]/cnt - m*m;
    float inv = (float)(1.0/sqrt(v+1e-5));
    a_s[tid] = inv;
    b_s[tid] = -(float)m * inv;
  }
  if (tid<64) lbs[tid] = (tid<62) ? lf_b[tid] : 0.f;
  float accG[4][4] = {{0.f}};
  float accO[4][6] = {{0.f}};
  float accR[4]    = {0.f,0.f,0.f,0.f};
  int n0 = (tid>>4)<<2;
  int mg = (tid&15)<<2;
  int jo = (tid&15)*6;
  int kk = tid & 63, nr = tid >> 6;
  for (int tile=ks; tile<177; tile+=32){
    int k0 = tile<<6;
    int f = k0 + kk, t = f/cLT2, l2 = f - t*cLT2;
    __syncthreads();
    for (int n=nr; n<64; n+=4){
      float v = 0.f;
      if (n<62){
        float raw = featbuf[((size_t)(b*cNT+t)*cC + n)*cLT + l2];
        float z = fmaf(raw, a_s[t], b_s[t]);
        v = fmaxf(fmaf(z, lf_w[(size_t)n*cFD + f], -lbs[n]), 0.f);
      }
      lt[kk*68 + n] = v;
    }
    for (int i=tid;i<6144;i+=256){
      int kw = i/96, j = i-kw*96;
      float wv = (j<64) ? entry_w[(size_t)(k0+kw)*64 + j] : pool_w[(size_t)(k0+kw)*32 + (j-64)];
      lw[kw*100 + j] = wv;
    }
    __syncthreads();
    #pragma unroll 4
    for (int k=0;k<64;k++){
      const float4 av = *(const float4*)&lt[k*68 + n0];
      const float4 bv = *(const float4*)&lt[k*68 + mg];
      const float2 w0 = *(const float2*)&lw[k*100+jo];
      const float2 w1 = *(const float2*)&lw[k*100+jo+2];
      const float2 w2 = *(const float2*)&lw[k*100+jo+4];
      float avv[4] = {av.x,av.y,av.z,av.w};
      float bvv[4] = {bv.x,bv.y,bv.z,bv.w};
      float wv[6]  = {w0.x,w0.y,w1.x,w1.y,w2.x,w2.y};
      #pragma unroll
      for (int i=0;i<4;i++){
        accR[i] += avv[i];
        #pragma unroll
        for (int j=0;j<4;j++) accG[i][j] = fmaf(avv[i], bvv[j], accG[i][j]);
        #pragma unroll
        for (int j=0;j<6;j++) accO[i][j] = fmaf(avv[i], wv[j], accO[i][j]);
      }
    }
  }
  for (int i=0;i<4;i++) if (n0+i<62){
    for (int j=0;j<4;j++) if (mg+j<62)
      atomicAdd(&P[((size_t)b*cC + n0+i)*cC + mg+j], accG[i][j]);
    for (int j=0;j<6;j++)
      atomicAdd(&Q[((size_t)b*cC + n0+i)*96 + jo+j], accO[i][j]);
  }
  if ((tid&15)==0)
    for (int i=0;i<4;i++) if (n0+i<62)
      atomicAdd(&r_g[(size_t)b*64 + n0+i], accR[i]);
}

// ---------------- merged: statC + adjacency + GCN1 (adj consumed from LDS) ----------------
__global__ __launch_bounds__(256) void k_adjgcn(
    const float* __restrict__ P, const float* __restrict__ r_g,
    const float* __restrict__ gadj, const float* __restrict__ Q,
    const float* __restrict__ wcol,
    const float* __restrict__ entry_b, const float* __restrict__ pool_b,
    float* __restrict__ adj, float* __restrict__ hE, float* __restrict__ hP,
    double* __restrict__ statE, double* __restrict__ statP)
{
  __shared__ float a[3844];
  __shared__ float oL[5952];
  __shared__ float dsh[62];
  __shared__ float rL[62], mL[62], iL[62], wcL[96];
  __shared__ float es[62], eq[62], ps[62], pq[62];
  int b = blockIdx.x, tid = threadIdx.x;
  if (tid<62){
    double S=0, SQ=0;
    for (int b2=0;b2<32;b2++){
      S  += (double)r_g[(size_t)b2*64 + tid];
      SQ += (double)P[((size_t)b2*cC + tid)*cC + tid];
    }
    double cnt = (double)cB*cFD;
    double m = S/cnt, var = SQ/cnt - m*m;
    mL[tid] = (float)m;
    iL[tid] = (float)(1.0/sqrt(var+1e-5));
    rL[tid] = r_g[(size_t)b*64+tid];
    es[tid]=0.f; eq[tid]=0.f; ps[tid]=0.f; pq[tid]=0.f;
  }
  if (tid>=64 && tid<160) wcL[tid-64]=wcol[tid-64];
  __syncthreads();
  for (int i=tid;i<3844;i+=256){
    int n=i/62, m=i-n*62;
    float sv = (P[(size_t)b*3844+i] - mL[n]*rL[m] - mL[m]*rL[n] + (float)cFD*mL[n]*mL[m]) * iL[n]*iL[m];
    float g = gadj[n*62+m] + gadj[m*62+n];
    float v = sv*g;
    v = v>0.f ? v : 0.f;
    if (n==m) v += 1.f;
    a[i]=v;
  }
  for (int i=tid;i<5952;i+=256){
    int m=i/96, j=i-m*96;
    oL[i] = (Q[(size_t)b*5952+i] - mL[m]*wcL[j]) * iL[m];
  }
  __syncthreads();
  if (tid<62){
    float rsum=0.f;
    for (int m=0;m<62;m++) rsum += a[tid*62+m];
    if (rsum==0.f) rsum=1.f;
    dsh[tid] = 1.0f/sqrtf(rsum);
  }
  __syncthreads();
  for (int i=tid;i<3844;i+=256){
    int n=i/62, m=i-n*62;
    float v = a[i]*dsh[n]*dsh[m];
    a[i] = v;
    adj[(size_t)b*3844+i] = v;
  }
  __syncthreads();
  for (int i=tid;i<5952;i+=256){
    int n=i/96, j=i-n*96;
    float v=0.f;
    for (int m=0;m<62;m++) v = fmaf(a[n*62+m], oL[m*96+j], v);
    if (j<64){
      v -= entry_b[j];
      hE[((size_t)b*62+n)*64 + j] = v;
      atomicAdd(&es[n],v); atomicAdd(&eq[n],v*v);
    } else {
      int j2=j-64;
      v -= pool_b[j2];
      hP[((size_t)b*62+n)*32 + j2] = v;
      atomicAdd(&ps[n],v); atomicAdd(&pq[n],v*v);
    }
  }
  __syncthreads();
  if (tid<62){
    atomicAdd(&statE[tid*2],(double)es[tid]);
    atomicAdd(&statE[tid*2+1],(double)eq[tid]);
    atomicAdd(&statP[tid*2],(double)ps[tid]);
    atomicAdd(&statP[tid*2+1],(double)pq[tid]);
  }
}

// ---------------- dense_diff_pool + in-block assign/bn + embed GCN pre + losses ----------------
__global__ __launch_bounds__(256) void k_pool(
    const float* __restrict__ adj, const float* __restrict__ hEraw,
    const float* __restrict__ hPraw,
    const double* __restrict__ statE, const double* __restrict__ statP,
    const float* __restrict__ pl_w, const float* __restrict__ pl_b,
    const float* __restrict__ embed_w, const float* __restrict__ embed_b,
    float* __restrict__ hpre, double* __restrict__ statH, double* __restrict__ accs)
{
  __shared__ float aL[3844];
  __shared__ float sL[1984];
  __shared__ float hL[3968];   // later reused as e1[32*64]
  __shared__ float t1[1984];   // later reused as sT[32*62]
  __shared__ float xp[2048];   // first used as hPL[1984]
  __shared__ float ap[1024];   // first used as plw[1024]
  __shared__ float red[256];
  __shared__ float ksum[32], ksq[32];
  __shared__ float mE[62], iE[62], mP[62], iP[62];
  float* e1 = hL;
  float* sT = t1;
  float* hPL = xp;
  float* plw = ap;
  int b = blockIdx.x, tid = threadIdx.x;
  if (tid<62){
    double cntE = (double)cB*64;
    double m = statE[tid*2]/cntE;
    double v = statE[tid*2+1]/cntE - m*m;
    mE[tid]=(float)m; iE[tid]=(float)(1.0/sqrt(v+1e-5));
    double cntP = (double)cB*32;
    double m2 = statP[tid*2]/cntP;
    double v2 = statP[tid*2+1]/cntP - m2*m2;
    mP[tid]=(float)m2; iP[tid]=(float)(1.0/sqrt(v2+1e-5));
  }
  if (tid<32){ksum[tid]=0.f;ksq[tid]=0.f;}
  for (int i=tid;i<3844;i+=256) aL[i]=adj[(size_t)b*3844+i];
  for (int i=tid;i<1984;i+=256) hPL[i]=hPraw[(size_t)b*1984+i];
  for (int i=tid;i<1024;i+=256) plw[i]=pl_w[i];
  __syncthreads();
  for (int i=tid;i<3968;i+=256){
    int n = i>>6;
    hL[i] = (hEraw[(size_t)b*3968+i]-mE[n])*iE[n];
  }
  // s_assign = softmax over k of bn(hP) @ pl_w + pl_b; ent_loss
  int r0 = tid>>5, o = tid&31;
  float entacc = 0.f;
  for (int n=r0; n<62; n+=8){
    float y = pl_b[o];
    float mm = mP[n], ii = iP[n];
    #pragma unroll 8
    for (int j=0;j<32;j++)
      y = fmaf((hPL[n*32+j]-mm)*ii, plw[j*32+o], y);
    float mx = y;
    for (int d=16;d>0;d>>=1) mx = fmaxf(mx, __shfl_xor(mx,d,32));
    float e = expf(y-mx);
    float sum = e;
    for (int d=16;d>0;d>>=1) sum += __shfl_xor(sum,d,32);
    float p = e/sum;
    sL[n*32+o] = p;
    entacc += -p*logf(p+1e-30f);
  }
  red[tid]=entacc; __syncthreads();
  for (int o2=128;o2>0;o2>>=1){ if(tid<o2) red[tid]+=red[tid+o2]; __syncthreads(); }
  if (tid==0) atomicAdd(&accs[1], (double)red[0]);
  __syncthreads();
  // x_pool[k][f] = sum_n s[n][k]*hL[n][f]   (overwrites hPL region)
  for (int i=tid;i<2048;i+=256){
    int k=i>>6, f=i&63;
    float v=0.f;
    for (int n=0;n<62;n++) v = fmaf(sL[n*32+k], hL[n*64+f], v);
    xp[i]=v;
  }
  for (int i=tid;i<1984;i+=256){
    int n=i>>5, k=i&31;
    float v=0.f;
    for (int m=0;m<62;m++) v = fmaf(aL[n*62+m], sL[m*32+k], v);
    t1[i]=v;
  }
  __syncthreads();
  for (int i=tid;i<1024;i+=256){
    int k=i>>5, l=i&31;
    float v=0.f;
    for (int n=0;n<62;n++) v = fmaf(sL[n*32+k], t1[n*32+l], v);
    ap[i]=v;
  }
  __syncthreads();
  for (int i=tid;i<1984;i+=256){
    int k=i/62, n=i-k*62;
    sT[k*62+n] = sL[n*32+k];
  }
  __syncthreads();
  float lacc=0.f;
  for (int i=tid;i<3844;i+=256){
    int n=i/62, m=i-n*62;
    float v=0.f;
    for (int k=0;k<32;k++) v = fmaf(sT[k*62+n], sT[k*62+m], v);
    float d = aL[i]-v+1e-30f;
    lacc = fmaf(d,d,lacc);
  }
  red[tid]=lacc; __syncthreads();
  for (int o2=128;o2>0;o2>>=1){ if(tid<o2) red[tid]+=red[tid+o2]; __syncthreads(); }
  if (tid==0) atomicAdd(&accs[0], (double)red[0]);
  __syncthreads();
  for (int i=tid;i<2048;i+=256){
    int k=i>>6, f=i&63;
    float v=0.f;
    for (int l=0;l<32;l++) v = fmaf(ap[k*32+l], xp[l*64+f], v);
    e1[i]=v;
  }
  __syncthreads();
  for (int i=tid;i<2048;i+=256){
    int k=i>>6, j=i&63;
    float v=0.f;
    for (int f=0;f<64;f++) v = fmaf(e1[k*64+f], embed_w[f*64+j], v);
    v -= embed_b[j];
    hpre[(size_t)b*2048 + i] = v;
    atomicAdd(&ksum[k], v);
    atomicAdd(&ksq[k], v*v);
  }
  __syncthreads();
  if (tid<32){
    atomicAdd(&statH[tid*2],   (double)ksum[tid]);
    atomicAdd(&statH[tid*2+1], (double)ksq[tid]);
  }
}

// ---------------- reps + MLP head (bn(hE) on the fly) ----------------
__global__ __launch_bounds__(128) void k_head(
    const float* __restrict__ hEraw, const float* __restrict__ hpre,
    const double* __restrict__ statE, const double* __restrict__ statH,
    const float* __restrict__ fc1_w, const float* __restrict__ fc1_b,
    const float* __restrict__ fc2_w, const float* __restrict__ fc2_b,
    const float* __restrict__ fc3_w, const float* __restrict__ fc3_b,
    float* __restrict__ o_pre)
{
  __shared__ float o1[128], y1[128], y2[64];
  __shared__ float mk[32], ik[32];
  __shared__ float mE[62], iE[62];
  int b = blockIdx.x, tid = threadIdx.x;
  if (tid<32){
    double cnt = 2048.0;
    double m = statH[tid*2]/cnt;
    double v = statH[tid*2+1]/cnt - m*m;
    mk[tid]=(float)m; ik[tid]=(float)(1.0/sqrt(v+1e-5));
  }
  if (tid>=64 && tid<126){
    int n = tid-64;
    double cnt = (double)cB*64;
    double m = statE[n*2]/cnt;
    double v = statE[n*2+1]/cnt - m*m;
    mE[n]=(float)m; iE[n]=(float)(1.0/sqrt(v+1e-5));
  }
  __syncthreads();
  if (tid<64){
    float s1=0.f;
    for (int n=0;n<62;n++)
      s1 += (hEraw[((size_t)b*62+n)*64+tid]-mE[n])*iE[n];
    o1[tid]=s1;
    float s2=0.f;
    for (int k=0;k<32;k++) s2 += (hpre[(size_t)b*2048 + k*64+tid]-mk[k])*ik[k];
    o1[64+tid]=s2;
  }
  __syncthreads();
  {
    float y = fc1_b[tid];
    for (int j=0;j<128;j++) y = fmaf(o1[j], fc1_w[j*128+tid], y);
    y1[tid] = fmaxf(y,0.f);
  }
  __syncthreads();
  if (tid<64){
    float z = fc2_b[tid];
    for (int j=0;j<128;j++) z = fmaf(y1[j], fc2_w[j*64+tid], z);
    y2[tid]=fmaxf(z,0.f);
  }
  __syncthreads();
  if (tid<4){
    float w = fc3_b[tid];
    for (int j=0;j<64;j++) w = fmaf(y2[j], fc3_w[j*4+tid], w);
    o_pre[b*4+tid]=w;
  }
}

// ---------------- final BN over batch + losses ----------------
__global__ void k_final(const float* __restrict__ o_pre, const double* __restrict__ accs,
                        float* __restrict__ out)
{
  int tid = threadIdx.x;
  if (tid<4){
    float s=0.f,q=0.f;
    for (int b=0;b<32;b++){ float v=o_pre[b*4+tid]; s+=v; q+=v*v; }
    float m = s*(1.f/32.f);
    float var = q*(1.f/32.f) - m*m;
    float inv = 1.0f/sqrtf(var+1e-5f);
    for (int b=0;b<32;b++) out[b*4+tid] = (o_pre[b*4+tid]-m)*inv;
  }
  if (tid==4) out[128] = (float)(sqrt(accs[0])/123008.0);
  if (tid==5) out[129] = (float)(accs[1]/1984.0);
}

// ---------------- workspace-too-small sentinel (diagnostic) ----------------
__global__ void k_wsfail(float* __restrict__ out, int n)
{
  int i = blockIdx.x*256 + threadIdx.x;
  if (i < n) out[i] = 12345.0f;
}

// ============================================================================
extern "C" void kernel_launch(void* const* d_in, const int* in_sizes, int n_in,
                              void* d_out, int out_size, void* d_ws, size_t ws_size,
                              hipStream_t stream)
{
  const float* x       = (const float*)d_in[0];
  const float* w1      = (const float*)d_in[1];
  const float* b1      = (const float*)d_in[2];
  const float* w2      = (const float*)d_in[3];
  const float* b2      = (const float*)d_in[4];
  const float* w3      = (const float*)d_in[5];
  const float* b3      = (const float*)d_in[6];
  const float* oxo_w   = (const float*)d_in[7];
  const float* oxo_b   = (const float*)d_in[8];
  const float* lf_w    = (const float*)d_in[9];
  const float* lf_b    = (const float*)d_in[10];
  const float* gadj    = (const float*)d_in[11];
  const float* entry_w = (const float*)d_in[12];
  const float* entry_b = (const float*)d_in[13];
  const float* pool_w  = (const float*)d_in[14];
  const float* pool_b  = (const float*)d_in[15];
  const float* pl_w    = (const float*)d_in[16];
  const float* pl_b    = (const float*)d_in[17];
  const float* embed_w = (const float*)d_in[18];
  const float* embed_b = (const float*)d_in[19];
  const float* fc1_w   = (const float*)d_in[20];
  const float* fc1_b   = (const float*)d_in[21];
  const float* fc2_w   = (const float*)d_in[22];
  const float* fc2_b   = (const float*)d_in[23];
  const float* fc3_w   = (const float*)d_in[24];
  const float* fc3_b   = (const float*)d_in[25];

  char* ws = (char*)d_ws;
  size_t off = 0;
  auto take = [&](size_t bytes){ size_t o = off; off = (off + bytes + 15) & ~(size_t)15; return o; };

  size_t feat_o = take(FEAT_N*4);          // conv logs; k_mix writes pooled rows in place
  size_t zstart = off;                     // ---- zeroed zone (atomic accumulators) ----
  size_t P_o     = take(P_N*4);
  size_t Q_o     = take(Q_N*4);
  size_t r_o     = take(R_N*4);
  size_t statE_o = take(124*8);
  size_t statP_o = take(124*8);
  size_t statH_o = take(64*8);
  size_t accs_o  = take(2*8);
  size_t zend = off;                       // ---- end zeroed zone ----
  size_t stat1_o = take(64*8);
  size_t stat2_o = take(64*8);
  size_t wcol_o  = take(96*4);
  size_t part1_o = take(PART_N*4);
  size_t part2_o = take(PART_N*4);
  size_t adj_o   = take(ADJ_N*4);
  size_t hE_o    = take(HE_N*4);
  size_t hP_o    = take(HP_N*4);
  size_t hpre_o  = take(HPRE_N*4);
  size_t opre_o  = take(128*4);
  size_t wpad_o  = take(WPAD_N*4);

  if (off > ws_size) {                     // diagnostic: ws too small
    k_wsfail<<<(out_size+255)/256, 256, 0, stream>>>((float*)d_out, out_size);
    return;
  }

  float*  feat  = (float*)(ws+feat_o);
  float*  P_g   = (float*)(ws+P_o);
  float*  Q_g   = (float*)(ws+Q_o);
  float*  r_g   = (float*)(ws+r_o);
  double* statE = (double*)(ws+statE_o);
  double* statP = (double*)(ws+statP_o);
  double* statH = (double*)(ws+statH_o);
  double* accs  = (double*)(ws+accs_o);
  double* stat1 = (double*)(ws+stat1_o);
  double* stat2 = (double*)(ws+stat2_o);
  float*  wcol  = (float*)(ws+wcol_o);
  float*  part1 = (float*)(ws+part1_o);
  float*  part2 = (float*)(ws+part2_o);
  float*  adj_g = (float*)(ws+adj_o);
  float*  hE_g  = (float*)(ws+hE_o);
  float*  hP_g  = (float*)(ws+hP_o);
  float*  hpre  = (float*)(ws+hpre_o);
  float*  opre  = (float*)(ws+opre_o);
  float*  wpad  = (float*)(ws+wpad_o);
  float*  out   = (float*)d_out;

  hipMemsetAsync(ws + zstart, 0, zend - zstart, stream);

  k_prep<<<122, 256, 0, stream>>>(w1, w2, w3, entry_w, pool_w, wpad, wcol);
  k_conv<<<cNBC, 256, 0, stream>>>(x, wpad, b1, b2, b3, feat, part1);
  k_reduce_stats<<<32, 256, 0, stream>>>(part1, stat1, cNBC, 32);
  k_mix<<<cNBC, 256, 0, stream>>>(feat, stat1, oxo_w, oxo_b, part2);
  k_reduce_stats<<<32, 256, 0, stream>>>(part2, stat2, cNBC, 32);
  k_gramow<<<cB*32, 256, 0, stream>>>(feat, stat2, lf_w, lf_b, entry_w, pool_w, P_g, Q_g, r_g);
  k_adjgcn<<<cB, 256, 0, stream>>>(P_g, r_g, gadj, Q_g, wcol, entry_b, pool_b,
                                   adj_g, hE_g, hP_g, statE, statP);
  k_pool<<<cB, 256, 0, stream>>>(adj_g, hE_g, hP_g, statE, statP, pl_w, pl_b,
                                 embed_w, embed_b, hpre, statH, accs);
  k_head<<<cB, 128, 0, stream>>>(hE_g, hpre, statE, statH, fc1_w, fc1_b, fc2_w, fc2_b, fc3_w, fc3_b, opre);
  k_final<<<1, 64, 0, stream>>>(opre, accs, out);
}

// Round 7
// 976.995 us; speedup vs baseline: 1.0378x; 1.0378x over previous
//
#include <hip/hip_runtime.h>
#include <math.h>

// ---------------- problem constants ----------------
constexpr int cB  = 32;     // batch
constexpr int cC  = 62;     // channels (graph nodes)
constexpr int cT  = 1024;   // time
constexpr int cNT = 32;     // temporal filters
constexpr int cLT = 708;    // concat conv-pool length (247+240+221)
constexpr int cLT2= 354;    // after avgpool(1,2)
constexpr int cFD = 11328;  // NT * 354
constexpr int cNBC = cB*cC; // 1984 blocks for per-(b,c) kernels

// element counts
constexpr size_t FEAT_N = (size_t)cB*cNT*cC*cLT;   // ~180 MB - conv logs, then in-place pooled mix
constexpr size_t P_N    = (size_t)cB*cC*cC;        // raw gram V V^T
constexpr size_t Q_N    = (size_t)cB*cC*96;        // raw V @ [entry_w|pool_w]
constexpr size_t R_N    = (size_t)cB*64;           // rowsums of V
constexpr size_t PART_N = (size_t)cNBC*64;
constexpr size_t ADJ_N  = P_N;
constexpr size_t HE_N   = (size_t)cB*cC*64;
constexpr size_t HP_N   = (size_t)cB*cC*32;
constexpr size_t HPRE_N = (size_t)cB*32*64;
constexpr size_t WPAD_N = 32*28 + 32*52 + 32*128;  // 6656 padded weights

// ---------------- prep: pad conv weights + wcol[j] = sum_k W[k][j] ----------------
__global__ __launch_bounds__(256) void k_prep(
    const float* __restrict__ w1, const float* __restrict__ w2,
    const float* __restrict__ w3, const float* __restrict__ entry_w,
    const float* __restrict__ pool_w, float* __restrict__ wpad,
    float* __restrict__ wcol)
{
  int blk = blockIdx.x, tid = threadIdx.x;
  if (blk < 26){
    int i = blk*256 + tid;
    if (i < 896){ int t=i/28, k=i-t*28; wpad[i] = (k<25) ? w1[t*25+k] : 0.f; }
    else if (i < 2560){ int j=i-896; int t=j/52, k=j-t*52; wpad[i] = (k<51) ? w2[t*51+k] : 0.f; }
    else if (i < 6656){ wpad[i] = w3[i-2560]; }
  } else {
    int j = blk - 26;          // 0..95
    float s = 0.f;
    if (j < 64){ for (int k=tid;k<cFD;k+=256) s += entry_w[(size_t)k*64 + j]; }
    else       { for (int k=tid;k<cFD;k+=256) s += pool_w[(size_t)k*32 + (j-64)]; }
    __shared__ float red[256];
    red[tid]=s; __syncthreads();
    for (int o=128;o>0;o>>=1){ if(tid<o) red[tid]+=red[tid+o]; __syncthreads(); }
    if (tid==0) wcol[j] = red[0];
  }
}

// ---------------- conv core: 8 filters x 4 positions per lane, x via GLOBAL (L1-hit, vmcnt) ----------------
// x-window on vmcnt, weights on lgkmcnt (s_load) -> independent counters, no drain stalls.
template<int K4, int L, int G>
__device__ __forceinline__ void conv8(
    const float* __restrict__ xg, const float* __restrict__ wg, const float* __restrict__ bg,
    float* pt, int tid)
{
  if (tid >= G) return;
  int pos = 4*tid;
  float4 c = *(const float4*)&xg[pos];
  float x0=c.x, x1=c.y, x2=c.z, x3=c.w;
  float a[8][4];
  #pragma unroll
  for (int f=0;f<8;f++){ float bv=bg[f]; a[f][0]=bv; a[f][1]=bv; a[f][2]=bv; a[f][3]=bv; }
  #pragma unroll 2
  for (int i=0;i<K4;i+=4){
    int ia = pos+4+i; ia = ia>1020 ? 1020 : ia;      // OOB-clamp: affected taps are pads or feed invalid outputs
    float4 n = *(const float4*)&xg[ia];              // coalesced 16B/lane, L1-resident row
    #pragma unroll
    for (int f=0;f<8;f++){
      const float* w = wg + f*K4 + i;                // wave-uniform -> scalar loads
      float w0=w[0], w1=w[1], w2=w[2], w3=w[3];
      a[f][0]=fmaf(x0,w0,a[f][0]); a[f][1]=fmaf(x1,w0,a[f][1]); a[f][2]=fmaf(x2,w0,a[f][2]); a[f][3]=fmaf(x3,w0,a[f][3]);
      a[f][0]=fmaf(x1,w1,a[f][0]); a[f][1]=fmaf(x2,w1,a[f][1]); a[f][2]=fmaf(x3,w1,a[f][2]); a[f][3]=fmaf(n.x,w1,a[f][3]);
      a[f][0]=fmaf(x2,w2,a[f][0]); a[f][1]=fmaf(x3,w2,a[f][1]); a[f][2]=fmaf(n.x,w2,a[f][2]); a[f][3]=fmaf(n.y,w2,a[f][3]);
      a[f][0]=fmaf(x3,w3,a[f][0]); a[f][1]=fmaf(n.x,w3,a[f][1]); a[f][2]=fmaf(n.y,w3,a[f][2]); a[f][3]=fmaf(n.z,w3,a[f][3]);
    }
    x0=n.x; x1=n.y; x2=n.z; x3=n.w;
  }
  #pragma unroll
  for (int f=0;f<8;f++){
    float p = (pos   < L ? a[f][0]*a[f][0] : 0.f)
            + (pos+1 < L ? a[f][1]*a[f][1] : 0.f)
            + (pos+2 < L ? a[f][2]*a[f][2] : 0.f)
            + (pos+3 < L ? a[f][3]*a[f][3] : 0.f);
    pt[f*256 + tid] = p;
  }
}

__global__ __launch_bounds__(256) void k_conv(
    const float* __restrict__ x,
    const float* __restrict__ wpad,
    const float* __restrict__ b1, const float* __restrict__ b2, const float* __restrict__ b3,
    float* __restrict__ feat, float* __restrict__ part1)
{
  __shared__ float pt1[2048], pt2[2048], pt3[2048];
  __shared__ float tsum[32], tsq[32];
  int b = blockIdx.x / cC, c = blockIdx.x % cC;
  int tid = threadIdx.x;
  const float* xg = x + (size_t)(b*cC+c)*cT;
  if (tid<32){ tsum[tid]=0.f; tsq[tid]=0.f; }
  for (int t0=0; t0<32; t0+=8){
    __syncthreads();
    conv8<28,1000,250>(xg, wpad + t0*28,        b1+t0, pt1, tid);
    conv8<52,974,244> (xg, wpad + 896 + t0*52,  b2+t0, pt2, tid);
    conv8<128,897,225>(xg, wpad + 2560 + t0*128,b3+t0, pt3, tid);
    __syncthreads();
    size_t base0 = ((size_t)(b*cNT+t0)*cC + c)*cLT;
    float val[8]={0,0,0,0,0,0,0,0}, vsq[8]={0,0,0,0,0,0,0,0};
    if (tid<247){
      #pragma unroll
      for (int f=0;f<8;f++){
        float p = (pt1[f*256+tid]+pt1[f*256+tid+1]+pt1[f*256+tid+2]+pt1[f*256+tid+3])*(1.f/16.f);
        float lv = __logf(p);
        feat[base0 + (size_t)f*cC*cLT + tid] = lv;
        val[f]+=lv; vsq[f]+=lv*lv;
      }
    }
    if (tid<240){
      #pragma unroll
      for (int f=0;f<8;f++){
        float p = (pt2[f*256+tid]+pt2[f*256+tid+1]+pt2[f*256+tid+2]+pt2[f*256+tid+3])*(1.f/16.f);
        float lv = __logf(p);
        feat[base0 + (size_t)f*cC*cLT + 247 + tid] = lv;
        val[f]+=lv; vsq[f]+=lv*lv;
      }
    }
    if (tid<221){
      #pragma unroll
      for (int f=0;f<8;f++){
        float p = (pt3[f*256+tid]+pt3[f*256+tid+1]+pt3[f*256+tid+2]+pt3[f*256+tid+3])*(1.f/16.f);
        float lv = __logf(p);
        feat[base0 + (size_t)f*cC*cLT + 487 + tid] = lv;
        val[f]+=lv; vsq[f]+=lv*lv;
      }
    }
    #pragma unroll
    for (int f=0;f<8;f++){
      float v=val[f], q=vsq[f];
      #pragma unroll
      for (int o=32;o>0;o>>=1){ v += __shfl_down(v,o,64); q += __shfl_down(q,o,64); }
      if ((tid&63)==0){ atomicAdd(&tsum[t0+f], v); atomicAdd(&tsq[t0+f], q); }
    }
  }
  __syncthreads();
  if (tid<32){
    part1[(size_t)blockIdx.x*64 + tid*2]   = tsum[tid];
    part1[(size_t)blockIdx.x*64 + tid*2+1] = tsq[tid];
  }
}

// ---------------- partial-stat reduction: [nblk][nch][2] f32 -> [nch][2] f64 ----------------
__global__ __launch_bounds__(256) void k_reduce_stats(
    const float* __restrict__ part, double* __restrict__ stat, int nblk, int nch)
{
  int ch = blockIdx.x, tid = threadIdx.x;
  double s=0,q=0;
  for (int i=tid;i<nblk;i+=256){
    s += (double)part[(size_t)i*nch*2 + ch*2];
    q += (double)part[(size_t)i*nch*2 + ch*2 + 1];
  }
  __shared__ double ls[256], lq[256];
  ls[tid]=s; lq[tid]=q; __syncthreads();
  for (int o=128;o>0;o>>=1){ if(tid<o){ls[tid]+=ls[tid+o]; lq[tid]+=lq[tid+o];} __syncthreads(); }
  if (tid==0){ stat[ch*2]=ls[0]; stat[ch*2+1]=lq[0]; }
}

// ---------------- fold BN1 into mix weights: W2T[t][o] = w[o][t]*inv[t], C[o] = b[o]-sum w*inv*mu ----------------
__global__ void k_foldw(const double* __restrict__ stat1,
                        const float* __restrict__ oxo_w, const float* __restrict__ oxo_b,
                        float* __restrict__ W2T, float* __restrict__ Cf)
{
  __shared__ float mu[32], inv[32];
  int tid = threadIdx.x;
  if (tid<32){
    double cnt = (double)cB*cC*cLT;
    double m = stat1[tid*2]/cnt;
    double v = stat1[tid*2+1]/cnt - m*m;
    mu[tid] = (float)m; inv[tid] = (float)(1.0/sqrt(v+1e-5));
  }
  __syncthreads();
  for (int i=tid;i<1024;i+=256){
    int t=i>>5, o=i&31;
    W2T[t*32+o] = oxo_w[o*32+t]*inv[t];
  }
  if (tid<32){
    float cacc = oxo_b[tid];
    for (int t=0;t<32;t++) cacc -= oxo_w[tid*32+t]*inv[t]*mu[t];
    Cf[tid] = cacc;
  }
}

// ---------------- mix: out[o][l2] from raw feat, BN folded; all-LDS inner loop ----------------
// wave -> 8 filters (o); lane -> 4 raw l (1 ds_read_b128 per t feeds 32 FMA). IN-PLACE.
__global__ __launch_bounds__(256) void k_mix(
    float* __restrict__ feat, const float* __restrict__ W2T,
    const float* __restrict__ Cf, float* __restrict__ part2)
{
  __shared__ float ft[32*240];    // raw tile 32 t x 236 l, stride 240
  __shared__ float wL[1024];
  __shared__ float cL[32];
  int b = blockIdx.x / cC, c = blockIdx.x % cC;
  int tid = threadIdx.x;
  int lane = tid & 63, oset = (tid>>6)*8;
  for (int i=tid;i<1024;i+=256) wL[i] = W2T[i];
  if (tid<32) cL[tid] = Cf[tid];
  float sacc[8]={0,0,0,0,0,0,0,0}, qacc[8]={0,0,0,0,0,0,0,0};
  for (int ch=0; ch<3; ch++){
    int l0 = ch*236;
    __syncthreads();   // wL/cL ready (ch0); ft reusable afterwards
    for (int g=tid; g<32*59; g+=256){
      int t = g/59, l4 = (g - t*59)*4;
      *(float4*)&ft[t*240+l4] = *(const float4*)&feat[((size_t)(b*cNT+t)*cC + c)*cLT + l0 + l4];
    }
    __syncthreads();
    if (lane < 59){
      float m[8][4];
      #pragma unroll
      for (int f=0;f<8;f++){ float cv=cL[oset+f]; m[f][0]=cv;m[f][1]=cv;m[f][2]=cv;m[f][3]=cv; }
      #pragma unroll 4
      for (int t=0;t<32;t++){
        float4 z = *(const float4*)&ft[t*240 + 4*lane];
        float4 wa = *(const float4*)&wL[t*32+oset];      // broadcast
        float4 wb = *(const float4*)&wL[t*32+oset+4];    // broadcast
        float w8a[8] = {wa.x,wa.y,wa.z,wa.w, wb.x,wb.y,wb.z,wb.w};
        #pragma unroll
        for (int f=0;f<8;f++){
          m[f][0]=fmaf(z.x,w8a[f],m[f][0]);
          m[f][1]=fmaf(z.y,w8a[f],m[f][1]);
          m[f][2]=fmaf(z.z,w8a[f],m[f][2]);
          m[f][3]=fmaf(z.w,w8a[f],m[f][3]);
        }
      }
      #pragma unroll
      for (int f=0;f<8;f++){
        float a0 = m[f][0]>0.f ? m[f][0] : 0.01f*m[f][0];
        float a1 = m[f][1]>0.f ? m[f][1] : 0.01f*m[f][1];
        float a2 = m[f][2]>0.f ? m[f][2] : 0.01f*m[f][2];
        float a3 = m[f][3]>0.f ? m[f][3] : 0.01f*m[f][3];
        float v0 = 0.5f*(a0+a1), v1 = 0.5f*(a2+a3);
        float2 st; st.x=v0; st.y=v1;
        *(float2*)&feat[((size_t)(b*cNT+oset+f)*cC + c)*cLT + 118*ch + 2*lane] = st;
        sacc[f] += v0+v1; qacc[f] += v0*v0+v1*v1;
      }
    }
  }
  #pragma unroll
  for (int f=0;f<8;f++){
    float s = sacc[f], q = qacc[f];
    #pragma unroll
    for (int o=32;o>0;o>>=1){ s += __shfl_down(s,o,64); q += __shfl_down(q,o,64); }
    if (lane==0){
      part2[(size_t)blockIdx.x*64 + (oset+f)*2]   = s;
      part2[(size_t)blockIdx.x*64 + (oset+f)*2+1] = q;
    }
  }
}

// ---------------- raw gram/ow/rowsum: P = V V^T, Q = V W, r = V 1 ----------------
__global__ __launch_bounds__(256) void k_gramow(
    const float* __restrict__ featbuf, const double* __restrict__ stat2,
    const float* __restrict__ lf_w, const float* __restrict__ lf_b,
    const float* __restrict__ entry_w, const float* __restrict__ pool_w,
    float* __restrict__ P, float* __restrict__ Q, float* __restrict__ r_g)
{
  __shared__ float lt[64*68];
  __shared__ float lw[64*100];
  __shared__ float a_s[32], b_s[32];
  __shared__ float lbs[64];
  int b = blockIdx.x >> 5, ks = blockIdx.x & 31;
  int tid = threadIdx.x;
  if (tid<32){
    double cnt = (double)cB*cC*cLT2;
    double m = stat2[tid*2]/cnt;
    double v = stat2[tid*2+1]/cnt - m*m;
    float inv = (float)(1.0/sqrt(v+1e-5));
    a_s[tid] = inv;
    b_s[tid] = -(float)m * inv;
  }
  if (tid<64) lbs[tid] = (tid<62) ? lf_b[tid] : 0.f;
  float accG[4][4] = {{0.f}};
  float accO[4][6] = {{0.f}};
  float accR[4]    = {0.f,0.f,0.f,0.f};
  int n0 = (tid>>4)<<2;
  int mg = (tid&15)<<2;
  int jo = (tid&15)*6;
  int kk = tid & 63, nr = tid >> 6;
  for (int tile=ks; tile<177; tile+=32){
    int k0 = tile<<6;
    int f = k0 + kk, t = f/cLT2, l2 = f - t*cLT2;
    __syncthreads();
    for (int n=nr; n<64; n+=4){
      float v = 0.f;
      if (n<62){
        float raw = featbuf[((size_t)(b*cNT+t)*cC + n)*cLT + l2];
        float z = fmaf(raw, a_s[t], b_s[t]);
        v = fmaxf(fmaf(z, lf_w[(size_t)n*cFD + f], -lbs[n]), 0.f);
      }
      lt[kk*68 + n] = v;
    }
    for (int i=tid;i<6144;i+=256){
      int kw = i/96, j = i-kw*96;
      float wv = (j<64) ? entry_w[(size_t)(k0+kw)*64 + j] : pool_w[(size_t)(k0+kw)*32 + (j-64)];
      lw[kw*100 + j] = wv;
    }
    __syncthreads();
    #pragma unroll 4
    for (int k=0;k<64;k++){
      const float4 av = *(const float4*)&lt[k*68 + n0];
      const float4 bv = *(const float4*)&lt[k*68 + mg];
      const float2 w0 = *(const float2*)&lw[k*100+jo];
      const float2 w1 = *(const float2*)&lw[k*100+jo+2];
      const float2 w2 = *(const float2*)&lw[k*100+jo+4];
      float avv[4] = {av.x,av.y,av.z,av.w};
      float bvv[4] = {bv.x,bv.y,bv.z,bv.w};
      float wv[6]  = {w0.x,w0.y,w1.x,w1.y,w2.x,w2.y};
      #pragma unroll
      for (int i=0;i<4;i++){
        accR[i] += avv[i];
        #pragma unroll
        for (int j=0;j<4;j++) accG[i][j] = fmaf(avv[i], bvv[j], accG[i][j]);
        #pragma unroll
        for (int j=0;j<6;j++) accO[i][j] = fmaf(avv[i], wv[j], accO[i][j]);
      }
    }
  }
  for (int i=0;i<4;i++) if (n0+i<62){
    for (int j=0;j<4;j++) if (mg+j<62)
      atomicAdd(&P[((size_t)b*cC + n0+i)*cC + mg+j], accG[i][j]);
    for (int j=0;j<6;j++)
      atomicAdd(&Q[((size_t)b*cC + n0+i)*96 + jo+j], accO[i][j]);
  }
  if ((tid&15)==0)
    for (int i=0;i<4;i++) if (n0+i<62)
      atomicAdd(&r_g[(size_t)b*64 + n0+i], accR[i]);
}

// ---------------- merged: statC + adjacency + GCN1 (adj consumed from LDS) ----------------
__global__ __launch_bounds__(256) void k_adjgcn(
    const float* __restrict__ P, const float* __restrict__ r_g,
    const float* __restrict__ gadj, const float* __restrict__ Q,
    const float* __restrict__ wcol,
    const float* __restrict__ entry_b, const float* __restrict__ pool_b,
    float* __restrict__ adj, float* __restrict__ hE, float* __restrict__ hP,
    double* __restrict__ statE, double* __restrict__ statP)
{
  __shared__ float a[3844];
  __shared__ float oL[5952];
  __shared__ float dsh[62];
  __shared__ float rL[62], mL[62], iL[62], wcL[96];
  __shared__ float es[62], eq[62], ps[62], pq[62];
  int b = blockIdx.x, tid = threadIdx.x;
  if (tid<62){
    double S=0, SQ=0;
    for (int b2=0;b2<32;b2++){
      S  += (double)r_g[(size_t)b2*64 + tid];
      SQ += (double)P[((size_t)b2*cC + tid)*cC + tid];
    }
    double cnt = (double)cB*cFD;
    double m = S/cnt, var = SQ/cnt - m*m;
    mL[tid] = (float)m;
    iL[tid] = (float)(1.0/sqrt(var+1e-5));
    rL[tid] = r_g[(size_t)b*64+tid];
    es[tid]=0.f; eq[tid]=0.f; ps[tid]=0.f; pq[tid]=0.f;
  }
  if (tid>=64 && tid<160) wcL[tid-64]=wcol[tid-64];
  __syncthreads();
  for (int i=tid;i<3844;i+=256){
    int n=i/62, m=i-n*62;
    float sv = (P[(size_t)b*3844+i] - mL[n]*rL[m] - mL[m]*rL[n] + (float)cFD*mL[n]*mL[m]) * iL[n]*iL[m];
    float g = gadj[n*62+m] + gadj[m*62+n];
    float v = sv*g;
    v = v>0.f ? v : 0.f;
    if (n==m) v += 1.f;
    a[i]=v;
  }
  for (int i=tid;i<5952;i+=256){
    int m=i/96, j=i-m*96;
    oL[i] = (Q[(size_t)b*5952+i] - mL[m]*wcL[j]) * iL[m];
  }
  __syncthreads();
  if (tid<62){
    float rsum=0.f;
    for (int m=0;m<62;m++) rsum += a[tid*62+m];
    if (rsum==0.f) rsum=1.f;
    dsh[tid] = 1.0f/sqrtf(rsum);
  }
  __syncthreads();
  for (int i=tid;i<3844;i+=256){
    int n=i/62, m=i-n*62;
    float v = a[i]*dsh[n]*dsh[m];
    a[i] = v;
    adj[(size_t)b*3844+i] = v;
  }
  __syncthreads();
  for (int i=tid;i<5952;i+=256){
    int n=i/96, j=i-n*96;
    float v=0.f;
    for (int m=0;m<62;m++) v = fmaf(a[n*62+m], oL[m*96+j], v);
    if (j<64){
      v -= entry_b[j];
      hE[((size_t)b*62+n)*64 + j] = v;
      atomicAdd(&es[n],v); atomicAdd(&eq[n],v*v);
    } else {
      int j2=j-64;
      v -= pool_b[j2];
      hP[((size_t)b*62+n)*32 + j2] = v;
      atomicAdd(&ps[n],v); atomicAdd(&pq[n],v*v);
    }
  }
  __syncthreads();
  if (tid<62){
    atomicAdd(&statE[tid*2],(double)es[tid]);
    atomicAdd(&statE[tid*2+1],(double)eq[tid]);
    atomicAdd(&statP[tid*2],(double)ps[tid]);
    atomicAdd(&statP[tid*2+1],(double)pq[tid]);
  }
}

// ---------------- dense_diff_pool + in-block assign/bn + embed GCN pre + losses ----------------
__global__ __launch_bounds__(256) void k_pool(
    const float* __restrict__ adj, const float* __restrict__ hEraw,
    const float* __restrict__ hPraw,
    const double* __restrict__ statE, const double* __restrict__ statP,
    const float* __restrict__ pl_w, const float* __restrict__ pl_b,
    const float* __restrict__ embed_w, const float* __restrict__ embed_b,
    float* __restrict__ hpre, double* __restrict__ statH, double* __restrict__ accs)
{
  __shared__ float aL[3844];
  __shared__ float sL[1984];
  __shared__ float hL[3968];   // later reused as e1[32*64]
  __shared__ float t1[1984];   // later reused as sT[32*62]
  __shared__ float xp[2048];   // first used as hPL[1984]
  __shared__ float ap[1024];   // first used as plw[1024]
  __shared__ float red[256];
  __shared__ float ksum[32], ksq[32];
  __shared__ float mE[62], iE[62], mP[62], iP[62];
  float* e1 = hL;
  float* sT = t1;
  float* hPL = xp;
  float* plw = ap;
  int b = blockIdx.x, tid = threadIdx.x;
  if (tid<62){
    double cntE = (double)cB*64;
    double m = statE[tid*2]/cntE;
    double v = statE[tid*2+1]/cntE - m*m;
    mE[tid]=(float)m; iE[tid]=(float)(1.0/sqrt(v+1e-5));
    double cntP = (double)cB*32;
    double m2 = statP[tid*2]/cntP;
    double v2 = statP[tid*2+1]/cntP - m2*m2;
    mP[tid]=(float)m2; iP[tid]=(float)(1.0/sqrt(v2+1e-5));
  }
  if (tid<32){ksum[tid]=0.f;ksq[tid]=0.f;}
  for (int i=tid;i<3844;i+=256) aL[i]=adj[(size_t)b*3844+i];
  for (int i=tid;i<1984;i+=256) hPL[i]=hPraw[(size_t)b*1984+i];
  for (int i=tid;i<1024;i+=256) plw[i]=pl_w[i];
  __syncthreads();
  for (int i=tid;i<3968;i+=256){
    int n = i>>6;
    hL[i] = (hEraw[(size_t)b*3968+i]-mE[n])*iE[n];
  }
  int r0 = tid>>5, o = tid&31;
  float entacc = 0.f;
  for (int n=r0; n<62; n+=8){
    float y = pl_b[o];
    float mm = mP[n], ii = iP[n];
    #pragma unroll 8
    for (int j=0;j<32;j++)
      y = fmaf((hPL[n*32+j]-mm)*ii, plw[j*32+o], y);
    float mx = y;
    for (int d=16;d>0;d>>=1) mx = fmaxf(mx, __shfl_xor(mx,d,32));
    float e = expf(y-mx);
    float sum = e;
    for (int d=16;d>0;d>>=1) sum += __shfl_xor(sum,d,32);
    float p = e/sum;
    sL[n*32+o] = p;
    entacc += -p*logf(p+1e-30f);
  }
  red[tid]=entacc; __syncthreads();
  for (int o2=128;o2>0;o2>>=1){ if(tid<o2) red[tid]+=red[tid+o2]; __syncthreads(); }
  if (tid==0) atomicAdd(&accs[1], (double)red[0]);
  __syncthreads();
  for (int i=tid;i<2048;i+=256){
    int k=i>>6, f=i&63;
    float v=0.f;
    for (int n=0;n<62;n++) v = fmaf(sL[n*32+k], hL[n*64+f], v);
    xp[i]=v;
  }
  for (int i=tid;i<1984;i+=256){
    int n=i>>5, k=i&31;
    float v=0.f;
    for (int m=0;m<62;m++) v = fmaf(aL[n*62+m], sL[m*32+k], v);
    t1[i]=v;
  }
  __syncthreads();
  for (int i=tid;i<1024;i+=256){
    int k=i>>5, l=i&31;
    float v=0.f;
    for (int n=0;n<62;n++) v = fmaf(sL[n*32+k], t1[n*32+l], v);
    ap[i]=v;
  }
  __syncthreads();
  for (int i=tid;i<1984;i+=256){
    int k=i/62, n=i-k*62;
    sT[k*62+n] = sL[n*32+k];
  }
  __syncthreads();
  float lacc=0.f;
  for (int i=tid;i<3844;i+=256){
    int n=i/62, m=i-n*62;
    float v=0.f;
    for (int k=0;k<32;k++) v = fmaf(sT[k*62+n], sT[k*62+m], v);
    float d = aL[i]-v+1e-30f;
    lacc = fmaf(d,d,lacc);
  }
  red[tid]=lacc; __syncthreads();
  for (int o2=128;o2>0;o2>>=1){ if(tid<o2) red[tid]+=red[tid+o2]; __syncthreads(); }
  if (tid==0) atomicAdd(&accs[0], (double)red[0]);
  __syncthreads();
  for (int i=tid;i<2048;i+=256){
    int k=i>>6, f=i&63;
    float v=0.f;
    for (int l=0;l<32;l++) v = fmaf(ap[k*32+l], xp[l*64+f], v);
    e1[i]=v;
  }
  __syncthreads();
  for (int i=tid;i<2048;i+=256){
    int k=i>>6, j=i&63;
    float v=0.f;
    for (int f=0;f<64;f++) v = fmaf(e1[k*64+f], embed_w[f*64+j], v);
    v -= embed_b[j];
    hpre[(size_t)b*2048 + i] = v;
    atomicAdd(&ksum[k], v);
    atomicAdd(&ksq[k], v*v);
  }
  __syncthreads();
  if (tid<32){
    atomicAdd(&statH[tid*2],   (double)ksum[tid]);
    atomicAdd(&statH[tid*2+1], (double)ksq[tid]);
  }
}

// ---------------- reps + MLP head (bn(hE) on the fly) ----------------
__global__ __launch_bounds__(128) void k_head(
    const float* __restrict__ hEraw, const float* __restrict__ hpre,
    const double* __restrict__ statE, const double* __restrict__ statH,
    const float* __restrict__ fc1_w, const float* __restrict__ fc1_b,
    const float* __restrict__ fc2_w, const float* __restrict__ fc2_b,
    const float* __restrict__ fc3_w, const float* __restrict__ fc3_b,
    float* __restrict__ o_pre)
{
  __shared__ float o1[128], y1[128], y2[64];
  __shared__ float mk[32], ik[32];
  __shared__ float mE[62], iE[62];
  int b = blockIdx.x, tid = threadIdx.x;
  if (tid<32){
    double cnt = 2048.0;
    double m = statH[tid*2]/cnt;
    double v = statH[tid*2+1]/cnt - m*m;
    mk[tid]=(float)m; ik[tid]=(float)(1.0/sqrt(v+1e-5));
  }
  if (tid>=64 && tid<126){
    int n = tid-64;
    double cnt = (double)cB*64;
    double m = statE[n*2]/cnt;
    double v = statE[n*2+1]/cnt - m*m;
    mE[n]=(float)m; iE[n]=(float)(1.0/sqrt(v+1e-5));
  }
  __syncthreads();
  if (tid<64){
    float s1=0.f;
    for (int n=0;n<62;n++)
      s1 += (hEraw[((size_t)b*62+n)*64+tid]-mE[n])*iE[n];
    o1[tid]=s1;
    float s2=0.f;
    for (int k=0;k<32;k++) s2 += (hpre[(size_t)b*2048 + k*64+tid]-mk[k])*ik[k];
    o1[64+tid]=s2;
  }
  __syncthreads();
  {
    float y = fc1_b[tid];
    for (int j=0;j<128;j++) y = fmaf(o1[j], fc1_w[j*128+tid], y);
    y1[tid] = fmaxf(y,0.f);
  }
  __syncthreads();
  if (tid<64){
    float z = fc2_b[tid];
    for (int j=0;j<128;j++) z = fmaf(y1[j], fc2_w[j*64+tid], z);
    y2[tid]=fmaxf(z,0.f);
  }
  __syncthreads();
  if (tid<4){
    float w = fc3_b[tid];
    for (int j=0;j<64;j++) w = fmaf(y2[j], fc3_w[j*4+tid], w);
    o_pre[b*4+tid]=w;
  }
}

// ---------------- final BN over batch + losses ----------------
__global__ void k_final(const float* __restrict__ o_pre, const double* __restrict__ accs,
                        float* __restrict__ out)
{
  int tid = threadIdx.x;
  if (tid<4){
    float s=0.f,q=0.f;
    for (int b=0;b<32;b++){ float v=o_pre[b*4+tid]; s+=v; q+=v*v; }
    float m = s*(1.f/32.f);
    float var = q*(1.f/32.f) - m*m;
    float inv = 1.0f/sqrtf(var+1e-5f);
    for (int b=0;b<32;b++) out[b*4+tid] = (o_pre[b*4+tid]-m)*inv;
  }
  if (tid==4) out[128] = (float)(sqrt(accs[0])/123008.0);
  if (tid==5) out[129] = (float)(accs[1]/1984.0);
}

// ---------------- workspace-too-small sentinel (diagnostic) ----------------
__global__ void k_wsfail(float* __restrict__ out, int n)
{
  int i = blockIdx.x*256 + threadIdx.x;
  if (i < n) out[i] = 12345.0f;
}

// ============================================================================
extern "C" void kernel_launch(void* const* d_in, const int* in_sizes, int n_in,
                              void* d_out, int out_size, void* d_ws, size_t ws_size,
                              hipStream_t stream)
{
  const float* x       = (const float*)d_in[0];
  const float* w1      = (const float*)d_in[1];
  const float* b1      = (const float*)d_in[2];
  const float* w2      = (const float*)d_in[3];
  const float* b2      = (const float*)d_in[4];
  const float* w3      = (const float*)d_in[5];
  const float* b3      = (const float*)d_in[6];
  const float* oxo_w   = (const float*)d_in[7];
  const float* oxo_b   = (const float*)d_in[8];
  const float* lf_w    = (const float*)d_in[9];
  const float* lf_b    = (const float*)d_in[10];
  const float* gadj    = (const float*)d_in[11];
  const float* entry_w = (const float*)d_in[12];
  const float* entry_b = (const float*)d_in[13];
  const float* pool_w  = (const float*)d_in[14];
  const float* pool_b  = (const float*)d_in[15];
  const float* pl_w    = (const float*)d_in[16];
  const float* pl_b    = (const float*)d_in[17];
  const float* embed_w = (const float*)d_in[18];
  const float* embed_b = (const float*)d_in[19];
  const float* fc1_w   = (const float*)d_in[20];
  const float* fc1_b   = (const float*)d_in[21];
  const float* fc2_w   = (const float*)d_in[22];
  const float* fc2_b   = (const float*)d_in[23];
  const float* fc3_w   = (const float*)d_in[24];
  const float* fc3_b   = (const float*)d_in[25];

  char* ws = (char*)d_ws;
  size_t off = 0;
  auto take = [&](size_t bytes){ size_t o = off; off = (off + bytes + 15) & ~(size_t)15; return o; };

  size_t feat_o = take(FEAT_N*4);          // conv logs; k_mix writes pooled rows in place
  size_t zstart = off;                     // ---- zeroed zone (atomic accumulators) ----
  size_t P_o     = take(P_N*4);
  size_t Q_o     = take(Q_N*4);
  size_t r_o     = take(R_N*4);
  size_t statE_o = take(124*8);
  size_t statP_o = take(124*8);
  size_t statH_o = take(64*8);
  size_t accs_o  = take(2*8);
  size_t zend = off;                       // ---- end zeroed zone ----
  size_t stat1_o = take(64*8);
  size_t stat2_o = take(64*8);
  size_t wcol_o  = take(96*4);
  size_t w2t_o   = take(1024*4);
  size_t cf_o    = take(32*4);
  size_t part1_o = take(PART_N*4);
  size_t part2_o = take(PART_N*4);
  size_t adj_o   = take(ADJ_N*4);
  size_t hE_o    = take(HE_N*4);
  size_t hP_o    = take(HP_N*4);
  size_t hpre_o  = take(HPRE_N*4);
  size_t opre_o  = take(128*4);
  size_t wpad_o  = take(WPAD_N*4);

  if (off > ws_size) {                     // diagnostic: ws too small
    k_wsfail<<<(out_size+255)/256, 256, 0, stream>>>((float*)d_out, out_size);
    return;
  }

  float*  feat  = (float*)(ws+feat_o);
  float*  P_g   = (float*)(ws+P_o);
  float*  Q_g   = (float*)(ws+Q_o);
  float*  r_g   = (float*)(ws+r_o);
  double* statE = (double*)(ws+statE_o);
  double* statP = (double*)(ws+statP_o);
  double* statH = (double*)(ws+statH_o);
  double* accs  = (double*)(ws+accs_o);
  double* stat1 = (double*)(ws+stat1_o);
  double* stat2 = (double*)(ws+stat2_o);
  float*  wcol  = (float*)(ws+wcol_o);
  float*  W2T   = (float*)(ws+w2t_o);
  float*  Cf    = (float*)(ws+cf_o);
  float*  part1 = (float*)(ws+part1_o);
  float*  part2 = (float*)(ws+part2_o);
  float*  adj_g = (float*)(ws+adj_o);
  float*  hE_g  = (float*)(ws+hE_o);
  float*  hP_g  = (float*)(ws+hP_o);
  float*  hpre  = (float*)(ws+hpre_o);
  float*  opre  = (float*)(ws+opre_o);
  float*  wpad  = (float*)(ws+wpad_o);
  float*  out   = (float*)d_out;

  hipMemsetAsync(ws + zstart, 0, zend - zstart, stream);

  k_prep<<<122, 256, 0, stream>>>(w1, w2, w3, entry_w, pool_w, wpad, wcol);
  k_conv<<<cNBC, 256, 0, stream>>>(x, wpad, b1, b2, b3, feat, part1);
  k_reduce_stats<<<32, 256, 0, stream>>>(part1, stat1, cNBC, 32);
  k_foldw<<<1, 256, 0, stream>>>(stat1, oxo_w, oxo_b, W2T, Cf);
  k_mix<<<cNBC, 256, 0, stream>>>(feat, W2T, Cf, part2);
  k_reduce_stats<<<32, 256, 0, stream>>>(part2, stat2, cNBC, 32);
  k_gramow<<<cB*32, 256, 0, stream>>>(feat, stat2, lf_w, lf_b, entry_w, pool_w, P_g, Q_g, r_g);
  k_adjgcn<<<cB, 256, 0, stream>>>(P_g, r_g, gadj, Q_g, wcol, entry_b, pool_b,
                                   adj_g, hE_g, hP_g, statE, statP);
  k_pool<<<cB, 256, 0, stream>>>(adj_g, hE_g, hP_g, statE, statP, pl_w, pl_b,
                                 embed_w, embed_b, hpre, statH, accs);
  k_head<<<cB, 128, 0, stream>>>(hE_g, hpre, statE, statH, fc1_w, fc1_b, fc2_w, fc2_b, fc3_w, fc3_b, opre);
  k_final<<<1, 64, 0, stream>>>(opre, accs, out);
}

// Round 8
// 896.669 us; speedup vs baseline: 1.1308x; 1.0896x over previous
//
#include <hip/hip_runtime.h>
#include <math.h>

// ---------------- problem constants ----------------
constexpr int cB  = 32;     // batch
constexpr int cC  = 62;     // channels (graph nodes)
constexpr int cT  = 1024;   // time
constexpr int cNT = 32;     // temporal filters
constexpr int cLT = 708;    // concat conv-pool length (247+240+221)
constexpr int cLT2= 354;    // after avgpool(1,2)
constexpr int cFD = 11328;  // NT * 354
constexpr int cNBC = cB*cC; // 1984 blocks for per-(b,c) kernels

// element counts
constexpr size_t FEAT_N = (size_t)cB*cNT*cC*cLT;   // ~180 MB - conv logs, then in-place pooled mix
constexpr size_t P_N    = (size_t)cB*cC*cC;        // raw gram V V^T
constexpr size_t Q_N    = (size_t)cB*cC*96;        // raw V @ [entry_w|pool_w]
constexpr size_t R_N    = (size_t)cB*64;           // rowsums of V
constexpr size_t PART_N = (size_t)cNBC*64;
constexpr size_t ADJ_N  = P_N;
constexpr size_t HE_N   = (size_t)cB*cC*64;
constexpr size_t HP_N   = (size_t)cB*cC*32;
constexpr size_t HPRE_N = (size_t)cB*32*64;
constexpr size_t WPAD_N = 32*28 + 32*52 + 32*128;  // 6656 padded weights

// ---------------- prep: pad conv weights + wcol[j] = sum_k W[k][j] ----------------
__global__ __launch_bounds__(256) void k_prep(
    const float* __restrict__ w1, const float* __restrict__ w2,
    const float* __restrict__ w3, const float* __restrict__ entry_w,
    const float* __restrict__ pool_w, float* __restrict__ wpad,
    float* __restrict__ wcol)
{
  int blk = blockIdx.x, tid = threadIdx.x;
  if (blk < 26){
    int i = blk*256 + tid;
    if (i < 896){ int t=i/28, k=i-t*28; wpad[i] = (k<25) ? w1[t*25+k] : 0.f; }
    else if (i < 2560){ int j=i-896; int t=j/52, k=j-t*52; wpad[i] = (k<51) ? w2[t*51+k] : 0.f; }
    else if (i < 6656){ wpad[i] = w3[i-2560]; }
  } else {
    int j = blk - 26;          // 0..95
    float s = 0.f;
    if (j < 64){ for (int k=tid;k<cFD;k+=256) s += entry_w[(size_t)k*64 + j]; }
    else       { for (int k=tid;k<cFD;k+=256) s += pool_w[(size_t)k*32 + (j-64)]; }
    __shared__ float red[256];
    red[tid]=s; __syncthreads();
    for (int o=128;o>0;o>>=1){ if(tid<o) red[tid]+=red[tid+o]; __syncthreads(); }
    if (tid==0) wcol[j] = red[0];
  }
}

// ---------------- conv core: 8 filters x 4 positions per lane, LDS x-window ----------------
// one ds_read_b128 feeds 128 FMA; weights via wave-uniform scalar loads.
template<int K4, int L, int G>
__device__ __forceinline__ void conv8(
    const float* xs, const float* __restrict__ wg, const float* __restrict__ bg,
    float* pt, int tid)
{
  if (tid >= G) return;
  int pos = 4*tid;
  float4 c = *(const float4*)&xs[pos];
  float x0=c.x, x1=c.y, x2=c.z, x3=c.w;
  float a[8][4];
  #pragma unroll
  for (int f=0;f<8;f++){ float bv=bg[f]; a[f][0]=bv; a[f][1]=bv; a[f][2]=bv; a[f][3]=bv; }
  #pragma unroll 2
  for (int i=0;i<K4;i+=4){
    float4 n = *(const float4*)&xs[pos+4+i];    // 16B-aligned, 16B/lane stride (conflict-free)
    #pragma unroll
    for (int f=0;f<8;f++){
      const float* w = wg + f*K4 + i;           // wave-uniform -> scalar loads
      float w0=w[0], w1=w[1], w2=w[2], w3=w[3];
      a[f][0]=fmaf(x0,w0,a[f][0]); a[f][1]=fmaf(x1,w0,a[f][1]); a[f][2]=fmaf(x2,w0,a[f][2]); a[f][3]=fmaf(x3,w0,a[f][3]);
      a[f][0]=fmaf(x1,w1,a[f][0]); a[f][1]=fmaf(x2,w1,a[f][1]); a[f][2]=fmaf(x3,w1,a[f][2]); a[f][3]=fmaf(n.x,w1,a[f][3]);
      a[f][0]=fmaf(x2,w2,a[f][0]); a[f][1]=fmaf(x3,w2,a[f][1]); a[f][2]=fmaf(n.x,w2,a[f][2]); a[f][3]=fmaf(n.y,w2,a[f][3]);
      a[f][0]=fmaf(x3,w3,a[f][0]); a[f][1]=fmaf(n.x,w3,a[f][1]); a[f][2]=fmaf(n.y,w3,a[f][2]); a[f][3]=fmaf(n.z,w3,a[f][3]);
    }
    x0=n.x; x1=n.y; x2=n.z; x3=n.w;
  }
  #pragma unroll
  for (int f=0;f<8;f++){
    float p = (pos   < L ? a[f][0]*a[f][0] : 0.f)
            + (pos+1 < L ? a[f][1]*a[f][1] : 0.f)
            + (pos+2 < L ? a[f][2]*a[f][2] : 0.f)
            + (pos+3 < L ? a[f][3]*a[f][3] : 0.f);
    pt[f*256 + tid] = p;
  }
}

// ---------------- pool pair: 3 aligned ds_read_b64 per 2 outputs (vs 8 b32) ----------------
template<int P>
__device__ __forceinline__ void pool2(
    const float* pt, float* featp, size_t fstride, int tid,
    float* val, float* vsq)
{
  if (tid >= (P+1)/2) return;
  int u2 = 2*tid;
  #pragma unroll
  for (int f=0;f<8;f++){
    const float* q = pt + f*256 + u2;            // 8B-aligned (u2 even)
    float2 r0 = *(const float2*)&q[0];
    float2 r1 = *(const float2*)&q[2];
    float s23 = r1.x + r1.y;
    float p0 = (r0.x + r0.y + s23)*(1.f/16.f);
    float lv0 = __logf(p0);
    featp[(size_t)f*fstride + u2] = lv0;
    val[f]+=lv0; vsq[f]+=lv0*lv0;
    if (u2+1 < P){
      float2 r2 = *(const float2*)&q[4];
      float p1 = (r0.y + s23 + r2.x)*(1.f/16.f);
      float lv1 = __logf(p1);
      featp[(size_t)f*fstride + u2 + 1] = lv1;
      val[f]+=lv1; vsq[f]+=lv1*lv1;
    }
  }
}

__global__ __launch_bounds__(256) void k_conv(
    const float* __restrict__ x,
    const float* __restrict__ wpad,
    const float* __restrict__ b1, const float* __restrict__ b2, const float* __restrict__ b3,
    float* __restrict__ feat, float* __restrict__ part1)
{
  __shared__ float xs[1152];
  __shared__ float pt1[2048], pt2[2048], pt3[2048];
  __shared__ float tsum[32], tsq[32];
  int b = blockIdx.x / cC, c = blockIdx.x % cC;
  int tid = threadIdx.x;
  for (int i=tid;i<1152;i+=256) xs[i] = (i<1024) ? x[(size_t)(b*cC+c)*cT + i] : 0.f;
  if (tid<32){ tsum[tid]=0.f; tsq[tid]=0.f; }
  for (int t0=0; t0<32; t0+=8){
    __syncthreads();
    conv8<28,1000,250>(xs, wpad + t0*28,        b1+t0, pt1, tid);
    conv8<52,974,244> (xs, wpad + 896 + t0*52,  b2+t0, pt2, tid);
    conv8<128,897,225>(xs, wpad + 2560 + t0*128,b3+t0, pt3, tid);
    __syncthreads();
    size_t base0 = ((size_t)(b*cNT+t0)*cC + c)*cLT;
    size_t fstr  = (size_t)cC*cLT;
    float val[8]={0,0,0,0,0,0,0,0}, vsq[8]={0,0,0,0,0,0,0,0};
    pool2<247>(pt1, feat+base0,     fstr, tid, val, vsq);
    pool2<240>(pt2, feat+base0+247, fstr, tid, val, vsq);
    pool2<221>(pt3, feat+base0+487, fstr, tid, val, vsq);
    #pragma unroll
    for (int f=0;f<8;f++){
      float v=val[f], q=vsq[f];
      #pragma unroll
      for (int o=32;o>0;o>>=1){ v += __shfl_down(v,o,64); q += __shfl_down(q,o,64); }
      if ((tid&63)==0){ atomicAdd(&tsum[t0+f], v); atomicAdd(&tsq[t0+f], q); }
    }
  }
  __syncthreads();
  if (tid<32){
    part1[(size_t)blockIdx.x*64 + tid*2]   = tsum[tid];
    part1[(size_t)blockIdx.x*64 + tid*2+1] = tsq[tid];
  }
}

// ---------------- partial-stat reduction: [nblk][nch][2] f32 -> [nch][2] f64 ----------------
__global__ __launch_bounds__(256) void k_reduce_stats(
    const float* __restrict__ part, double* __restrict__ stat, int nblk, int nch)
{
  int ch = blockIdx.x, tid = threadIdx.x;
  double s=0,q=0;
  for (int i=tid;i<nblk;i+=256){
    s += (double)part[(size_t)i*nch*2 + ch*2];
    q += (double)part[(size_t)i*nch*2 + ch*2 + 1];
  }
  __shared__ double ls[256], lq[256];
  ls[tid]=s; lq[tid]=q; __syncthreads();
  for (int o=128;o>0;o>>=1){ if(tid<o){ls[tid]+=ls[tid+o]; lq[tid]+=lq[tid+o];} __syncthreads(); }
  if (tid==0){ stat[ch*2]=ls[0]; stat[ch*2+1]=lq[0]; }
}

// ---------------- fold BN1 into mix weights: W2T[t][o] = w[o][t]*inv[t], C[o] = b[o]-sum w*inv*mu ----------------
__global__ void k_foldw(const double* __restrict__ stat1,
                        const float* __restrict__ oxo_w, const float* __restrict__ oxo_b,
                        float* __restrict__ W2T, float* __restrict__ Cf)
{
  __shared__ float mu[32], inv[32];
  int tid = threadIdx.x;
  if (tid<32){
    double cnt = (double)cB*cC*cLT;
    double m = stat1[tid*2]/cnt;
    double v = stat1[tid*2+1]/cnt - m*m;
    mu[tid] = (float)m; inv[tid] = (float)(1.0/sqrt(v+1e-5));
  }
  __syncthreads();
  for (int i=tid;i<1024;i+=256){
    int t=i>>5, o=i&31;
    W2T[t*32+o] = oxo_w[o*32+t]*inv[t];
  }
  if (tid<32){
    float cacc = oxo_b[tid];
    for (int t=0;t<32;t++) cacc -= oxo_w[tid*32+t]*inv[t]*mu[t];
    Cf[tid] = cacc;
  }
}

// ---------------- mix: out[o][l2] from raw feat, BN folded; all-LDS inner loop ----------------
__global__ __launch_bounds__(256) void k_mix(
    float* __restrict__ feat, const float* __restrict__ W2T,
    const float* __restrict__ Cf, float* __restrict__ part2)
{
  __shared__ float ft[32*240];    // raw tile 32 t x 236 l, stride 240
  __shared__ float wL[1024];
  __shared__ float cL[32];
  int b = blockIdx.x / cC, c = blockIdx.x % cC;
  int tid = threadIdx.x;
  int lane = tid & 63, oset = (tid>>6)*8;
  for (int i=tid;i<1024;i+=256) wL[i] = W2T[i];
  if (tid<32) cL[tid] = Cf[tid];
  float sacc[8]={0,0,0,0,0,0,0,0}, qacc[8]={0,0,0,0,0,0,0,0};
  for (int ch=0; ch<3; ch++){
    int l0 = ch*236;
    __syncthreads();
    for (int g=tid; g<32*59; g+=256){
      int t = g/59, l4 = (g - t*59)*4;
      *(float4*)&ft[t*240+l4] = *(const float4*)&feat[((size_t)(b*cNT+t)*cC + c)*cLT + l0 + l4];
    }
    __syncthreads();
    if (lane < 59){
      float m[8][4];
      #pragma unroll
      for (int f=0;f<8;f++){ float cv=cL[oset+f]; m[f][0]=cv;m[f][1]=cv;m[f][2]=cv;m[f][3]=cv; }
      #pragma unroll 4
      for (int t=0;t<32;t++){
        float4 z = *(const float4*)&ft[t*240 + 4*lane];
        float4 wa = *(const float4*)&wL[t*32+oset];
        float4 wb = *(const float4*)&wL[t*32+oset+4];
        float w8a[8] = {wa.x,wa.y,wa.z,wa.w, wb.x,wb.y,wb.z,wb.w};
        #pragma unroll
        for (int f=0;f<8;f++){
          m[f][0]=fmaf(z.x,w8a[f],m[f][0]);
          m[f][1]=fmaf(z.y,w8a[f],m[f][1]);
          m[f][2]=fmaf(z.z,w8a[f],m[f][2]);
          m[f][3]=fmaf(z.w,w8a[f],m[f][3]);
        }
      }
      #pragma unroll
      for (int f=0;f<8;f++){
        float a0 = m[f][0]>0.f ? m[f][0] : 0.01f*m[f][0];
        float a1 = m[f][1]>0.f ? m[f][1] : 0.01f*m[f][1];
        float a2 = m[f][2]>0.f ? m[f][2] : 0.01f*m[f][2];
        float a3 = m[f][3]>0.f ? m[f][3] : 0.01f*m[f][3];
        float v0 = 0.5f*(a0+a1), v1 = 0.5f*(a2+a3);
        float2 st; st.x=v0; st.y=v1;
        *(float2*)&feat[((size_t)(b*cNT+oset+f)*cC + c)*cLT + 118*ch + 2*lane] = st;
        sacc[f] += v0+v1; qacc[f] += v0*v0+v1*v1;
      }
    }
  }
  #pragma unroll
  for (int f=0;f<8;f++){
    float s = sacc[f], q = qacc[f];
    #pragma unroll
    for (int o=32;o>0;o>>=1){ s += __shfl_down(s,o,64); q += __shfl_down(q,o,64); }
    if (lane==0){
      part2[(size_t)blockIdx.x*64 + (oset+f)*2]   = s;
      part2[(size_t)blockIdx.x*64 + (oset+f)*2+1] = q;
    }
  }
}

// ---------------- raw gram/ow/rowsum: P = V V^T, Q = V W, r = V 1 ----------------
__global__ __launch_bounds__(256) void k_gramow(
    const float* __restrict__ featbuf, const double* __restrict__ stat2,
    const float* __restrict__ lf_w, const float* __restrict__ lf_b,
    const float* __restrict__ entry_w, const float* __restrict__ pool_w,
    float* __restrict__ P, float* __restrict__ Q, float* __restrict__ r_g)
{
  __shared__ float lt[64*68];
  __shared__ float lw[64*100];
  __shared__ float a_s[32], b_s[32];
  __shared__ float lbs[64];
  int b = blockIdx.x >> 4, ks = blockIdx.x & 15;
  int tid = threadIdx.x;
  if (tid<32){
    double cnt = (double)cB*cC*cLT2;
    double m = stat2[tid*2]/cnt;
    double v = stat2[tid*2+1]/cnt - m*m;
    float inv = (float)(1.0/sqrt(v+1e-5));
    a_s[tid] = inv;
    b_s[tid] = -(float)m * inv;
  }
  if (tid<64) lbs[tid] = (tid<62) ? lf_b[tid] : 0.f;
  float accG[4][4] = {{0.f}};
  float accO[4][6] = {{0.f}};
  float accR[4]    = {0.f,0.f,0.f,0.f};
  int n0 = (tid>>4)<<2;
  int mg = (tid&15)<<2;
  int jo = (tid&15)*6;
  int kk = tid & 63, nr = tid >> 6;
  for (int tile=ks; tile<177; tile+=16){
    int k0 = tile<<6;
    int f = k0 + kk, t = f/cLT2, l2 = f - t*cLT2;
    __syncthreads();
    for (int n=nr; n<64; n+=4){
      float v = 0.f;
      if (n<62){
        float raw = featbuf[((size_t)(b*cNT+t)*cC + n)*cLT + l2];
        float z = fmaf(raw, a_s[t], b_s[t]);
        v = fmaxf(fmaf(z, lf_w[(size_t)n*cFD + f], -lbs[n]), 0.f);
      }
      lt[kk*68 + n] = v;
    }
    for (int i=tid;i<6144;i+=256){
      int kw = i/96, j = i-kw*96;
      float wv = (j<64) ? entry_w[(size_t)(k0+kw)*64 + j] : pool_w[(size_t)(k0+kw)*32 + (j-64)];
      lw[kw*100 + j] = wv;
    }
    __syncthreads();
    #pragma unroll 4
    for (int k=0;k<64;k++){
      const float4 av = *(const float4*)&lt[k*68 + n0];
      const float4 bv = *(const float4*)&lt[k*68 + mg];
      const float2 w0 = *(const float2*)&lw[k*100+jo];
      const float2 w1 = *(const float2*)&lw[k*100+jo+2];
      const float2 w2 = *(const float2*)&lw[k*100+jo+4];
      float avv[4] = {av.x,av.y,av.z,av.w};
      float bvv[4] = {bv.x,bv.y,bv.z,bv.w};
      float wv[6]  = {w0.x,w0.y,w1.x,w1.y,w2.x,w2.y};
      #pragma unroll
      for (int i=0;i<4;i++){
        accR[i] += avv[i];
        #pragma unroll
        for (int j=0;j<4;j++) accG[i][j] = fmaf(avv[i], bvv[j], accG[i][j]);
        #pragma unroll
        for (int j=0;j<6;j++) accO[i][j] = fmaf(avv[i], wv[j], accO[i][j]);
      }
    }
  }
  for (int i=0;i<4;i++) if (n0+i<62){
    for (int j=0;j<4;j++) if (mg+j<62)
      atomicAdd(&P[((size_t)b*cC + n0+i)*cC + mg+j], accG[i][j]);
    for (int j=0;j<6;j++)
      atomicAdd(&Q[((size_t)b*cC + n0+i)*96 + jo+j], accO[i][j]);
  }
  if ((tid&15)==0)
    for (int i=0;i<4;i++) if (n0+i<62)
      atomicAdd(&r_g[(size_t)b*64 + n0+i], accR[i]);
}

// ---------------- merged: statC + adjacency + GCN1 (adj consumed from LDS) ----------------
__global__ __launch_bounds__(256) void k_adjgcn(
    const float* __restrict__ P, const float* __restrict__ r_g,
    const float* __restrict__ gadj, const float* __restrict__ Q,
    const float* __restrict__ wcol,
    const float* __restrict__ entry_b, const float* __restrict__ pool_b,
    float* __restrict__ adj, float* __restrict__ hE, float* __restrict__ hP,
    double* __restrict__ statE, double* __restrict__ statP)
{
  __shared__ float a[3844];
  __shared__ float oL[5952];
  __shared__ float dsh[62];
  __shared__ float rL[62], mL[62], iL[62], wcL[96];
  __shared__ float es[62], eq[62], ps[62], pq[62];
  int b = blockIdx.x, tid = threadIdx.x;
  if (tid<62){
    double S=0, SQ=0;
    for (int b2=0;b2<32;b2++){
      S  += (double)r_g[(size_t)b2*64 + tid];
      SQ += (double)P[((size_t)b2*cC + tid)*cC + tid];
    }
    double cnt = (double)cB*cFD;
    double m = S/cnt, var = SQ/cnt - m*m;
    mL[tid] = (float)m;
    iL[tid] = (float)(1.0/sqrt(var+1e-5));
    rL[tid] = r_g[(size_t)b*64+tid];
    es[tid]=0.f; eq[tid]=0.f; ps[tid]=0.f; pq[tid]=0.f;
  }
  if (tid>=64 && tid<160) wcL[tid-64]=wcol[tid-64];
  __syncthreads();
  for (int i=tid;i<3844;i+=256){
    int n=i/62, m=i-n*62;
    float sv = (P[(size_t)b*3844+i] - mL[n]*rL[m] - mL[m]*rL[n] + (float)cFD*mL[n]*mL[m]) * iL[n]*iL[m];
    float g = gadj[n*62+m] + gadj[m*62+n];
    float v = sv*g;
    v = v>0.f ? v : 0.f;
    if (n==m) v += 1.f;
    a[i]=v;
  }
  for (int i=tid;i<5952;i+=256){
    int m=i/96, j=i-m*96;
    oL[i] = (Q[(size_t)b*5952+i] - mL[m]*wcL[j]) * iL[m];
  }
  __syncthreads();
  if (tid<62){
    float rsum=0.f;
    for (int m=0;m<62;m++) rsum += a[tid*62+m];
    if (rsum==0.f) rsum=1.f;
    dsh[tid] = 1.0f/sqrtf(rsum);
  }
  __syncthreads();
  for (int i=tid;i<3844;i+=256){
    int n=i/62, m=i-n*62;
    float v = a[i]*dsh[n]*dsh[m];
    a[i] = v;
    adj[(size_t)b*3844+i] = v;
  }
  __syncthreads();
  for (int i=tid;i<5952;i+=256){
    int n=i/96, j=i-n*96;
    float v=0.f;
    for (int m=0;m<62;m++) v = fmaf(a[n*62+m], oL[m*96+j], v);
    if (j<64){
      v -= entry_b[j];
      hE[((size_t)b*62+n)*64 + j] = v;
      atomicAdd(&es[n],v); atomicAdd(&eq[n],v*v);
    } else {
      int j2=j-64;
      v -= pool_b[j2];
      hP[((size_t)b*62+n)*32 + j2] = v;
      atomicAdd(&ps[n],v); atomicAdd(&pq[n],v*v);
    }
  }
  __syncthreads();
  if (tid<62){
    atomicAdd(&statE[tid*2],(double)es[tid]);
    atomicAdd(&statE[tid*2+1],(double)eq[tid]);
    atomicAdd(&statP[tid*2],(double)ps[tid]);
    atomicAdd(&statP[tid*2+1],(double)pq[tid]);
  }
}

// ---------------- dense_diff_pool + in-block assign/bn + embed GCN pre + losses ----------------
__global__ __launch_bounds__(256) void k_pool(
    const float* __restrict__ adj, const float* __restrict__ hEraw,
    const float* __restrict__ hPraw,
    const double* __restrict__ statE, const double* __restrict__ statP,
    const float* __restrict__ pl_w, const float* __restrict__ pl_b,
    const float* __restrict__ embed_w, const float* __restrict__ embed_b,
    float* __restrict__ hpre, double* __restrict__ statH, double* __restrict__ accs)
{
  __shared__ float aL[3844];
  __shared__ float sL[1984];
  __shared__ float hL[3968];   // later reused as e1[32*64]
  __shared__ float t1[1984];   // later reused as sT[32*62]
  __shared__ float xp[2048];   // first used as hPL[1984]
  __shared__ float ap[1024];   // first used as plw[1024]
  __shared__ float red[256];
  __shared__ float ksum[32], ksq[32];
  __shared__ float mE[62], iE[62], mP[62], iP[62];
  float* e1 = hL;
  float* sT = t1;
  float* hPL = xp;
  float* plw = ap;
  int b = blockIdx.x, tid = threadIdx.x;
  if (tid<62){
    double cntE = (double)cB*64;
    double m = statE[tid*2]/cntE;
    double v = statE[tid*2+1]/cntE - m*m;
    mE[tid]=(float)m; iE[tid]=(float)(1.0/sqrt(v+1e-5));
    double cntP = (double)cB*32;
    double m2 = statP[tid*2]/cntP;
    double v2 = statP[tid*2+1]/cntP - m2*m2;
    mP[tid]=(float)m2; iP[tid]=(float)(1.0/sqrt(v2+1e-5));
  }
  if (tid<32){ksum[tid]=0.f;ksq[tid]=0.f;}
  for (int i=tid;i<3844;i+=256) aL[i]=adj[(size_t)b*3844+i];
  for (int i=tid;i<1984;i+=256) hPL[i]=hPraw[(size_t)b*1984+i];
  for (int i=tid;i<1024;i+=256) plw[i]=pl_w[i];
  __syncthreads();
  for (int i=tid;i<3968;i+=256){
    int n = i>>6;
    hL[i] = (hEraw[(size_t)b*3968+i]-mE[n])*iE[n];
  }
  int r0 = tid>>5, o = tid&31;
  float entacc = 0.f;
  for (int n=r0; n<62; n+=8){
    float y = pl_b[o];
    float mm = mP[n], ii = iP[n];
    #pragma unroll 8
    for (int j=0;j<32;j++)
      y = fmaf((hPL[n*32+j]-mm)*ii, plw[j*32+o], y);
    float mx = y;
    for (int d=16;d>0;d>>=1) mx = fmaxf(mx, __shfl_xor(mx,d,32));
    float e = expf(y-mx);
    float sum = e;
    for (int d=16;d>0;d>>=1) sum += __shfl_xor(sum,d,32);
    float p = e/sum;
    sL[n*32+o] = p;
    entacc += -p*logf(p+1e-30f);
  }
  red[tid]=entacc; __syncthreads();
  for (int o2=128;o2>0;o2>>=1){ if(tid<o2) red[tid]+=red[tid+o2]; __syncthreads(); }
  if (tid==0) atomicAdd(&accs[1], (double)red[0]);
  __syncthreads();
  for (int i=tid;i<2048;i+=256){
    int k=i>>6, f=i&63;
    float v=0.f;
    for (int n=0;n<62;n++) v = fmaf(sL[n*32+k], hL[n*64+f], v);
    xp[i]=v;
  }
  for (int i=tid;i<1984;i+=256){
    int n=i>>5, k=i&31;
    float v=0.f;
    for (int m=0;m<62;m++) v = fmaf(aL[n*62+m], sL[m*32+k], v);
    t1[i]=v;
  }
  __syncthreads();
  for (int i=tid;i<1024;i+=256){
    int k=i>>5, l=i&31;
    float v=0.f;
    for (int n=0;n<62;n++) v = fmaf(sL[n*32+k], t1[n*32+l], v);
    ap[i]=v;
  }
  __syncthreads();
  for (int i=tid;i<1984;i+=256){
    int k=i/62, n=i-k*62;
    sT[k*62+n] = sL[n*32+k];
  }
  __syncthreads();
  float lacc=0.f;
  for (int i=tid;i<3844;i+=256){
    int n=i/62, m=i-n*62;
    float v=0.f;
    for (int k=0;k<32;k++) v = fmaf(sT[k*62+n], sT[k*62+m], v);
    float d = aL[i]-v+1e-30f;
    lacc = fmaf(d,d,lacc);
  }
  red[tid]=lacc; __syncthreads();
  for (int o2=128;o2>0;o2>>=1){ if(tid<o2) red[tid]+=red[tid+o2]; __syncthreads(); }
  if (tid==0) atomicAdd(&accs[0], (double)red[0]);
  __syncthreads();
  for (int i=tid;i<2048;i+=256){
    int k=i>>6, f=i&63;
    float v=0.f;
    for (int l=0;l<32;l++) v = fmaf(ap[k*32+l], xp[l*64+f], v);
    e1[i]=v;
  }
  __syncthreads();
  for (int i=tid;i<2048;i+=256){
    int k=i>>6, j=i&63;
    float v=0.f;
    for (int f=0;f<64;f++) v = fmaf(e1[k*64+f], embed_w[f*64+j], v);
    v -= embed_b[j];
    hpre[(size_t)b*2048 + i] = v;
    atomicAdd(&ksum[k], v);
    atomicAdd(&ksq[k], v*v);
  }
  __syncthreads();
  if (tid<32){
    atomicAdd(&statH[tid*2],   (double)ksum[tid]);
    atomicAdd(&statH[tid*2+1], (double)ksq[tid]);
  }
}

// ---------------- reps + MLP head (bn(hE) on the fly) ----------------
__global__ __launch_bounds__(128) void k_head(
    const float* __restrict__ hEraw, const float* __restrict__ hpre,
    const double* __restrict__ statE, const double* __restrict__ statH,
    const float* __restrict__ fc1_w, const float* __restrict__ fc1_b,
    const float* __restrict__ fc2_w, const float* __restrict__ fc2_b,
    const float* __restrict__ fc3_w, const float* __restrict__ fc3_b,
    float* __restrict__ o_pre)
{
  __shared__ float o1[128], y1[128], y2[64];
  __shared__ float mk[32], ik[32];
  __shared__ float mE[62], iE[62];
  int b = blockIdx.x, tid = threadIdx.x;
  if (tid<32){
    double cnt = 2048.0;
    double m = statH[tid*2]/cnt;
    double v = statH[tid*2+1]/cnt - m*m;
    mk[tid]=(float)m; ik[tid]=(float)(1.0/sqrt(v+1e-5));
  }
  if (tid>=64 && tid<126){
    int n = tid-64;
    double cnt = (double)cB*64;
    double m = statE[n*2]/cnt;
    double v = statE[n*2+1]/cnt - m*m;
    mE[n]=(float)m; iE[n]=(float)(1.0/sqrt(v+1e-5));
  }
  __syncthreads();
  if (tid<64){
    float s1=0.f;
    for (int n=0;n<62;n++)
      s1 += (hEraw[((size_t)b*62+n)*64+tid]-mE[n])*iE[n];
    o1[tid]=s1;
    float s2=0.f;
    for (int k=0;k<32;k++) s2 += (hpre[(size_t)b*2048 + k*64+tid]-mk[k])*ik[k];
    o1[64+tid]=s2;
  }
  __syncthreads();
  {
    float y = fc1_b[tid];
    for (int j=0;j<128;j++) y = fmaf(o1[j], fc1_w[j*128+tid], y);
    y1[tid] = fmaxf(y,0.f);
  }
  __syncthreads();
  if (tid<64){
    float z = fc2_b[tid];
    for (int j=0;j<128;j++) z = fmaf(y1[j], fc2_w[j*64+tid], z);
    y2[tid]=fmaxf(z,0.f);
  }
  __syncthreads();
  if (tid<4){
    float w = fc3_b[tid];
    for (int j=0;j<64;j++) w = fmaf(y2[j], fc3_w[j*4+tid], w);
    o_pre[b*4+tid]=w;
  }
}

// ---------------- final BN over batch + losses ----------------
__global__ void k_final(const float* __restrict__ o_pre, const double* __restrict__ accs,
                        float* __restrict__ out)
{
  int tid = threadIdx.x;
  if (tid<4){
    float s=0.f,q=0.f;
    for (int b=0;b<32;b++){ float v=o_pre[b*4+tid]; s+=v; q+=v*v; }
    float m = s*(1.f/32.f);
    float var = q*(1.f/32.f) - m*m;
    float inv = 1.0f/sqrtf(var+1e-5f);
    for (int b=0;b<32;b++) out[b*4+tid] = (o_pre[b*4+tid]-m)*inv;
  }
  if (tid==4) out[128] = (float)(sqrt(accs[0])/123008.0);
  if (tid==5) out[129] = (float)(accs[1]/1984.0);
}

// ---------------- workspace-too-small sentinel (diagnostic) ----------------
__global__ void k_wsfail(float* __restrict__ out, int n)
{
  int i = blockIdx.x*256 + threadIdx.x;
  if (i < n) out[i] = 12345.0f;
}

// ============================================================================
extern "C" void kernel_launch(void* const* d_in, const int* in_sizes, int n_in,
                              void* d_out, int out_size, void* d_ws, size_t ws_size,
                              hipStream_t stream)
{
  const float* x       = (const float*)d_in[0];
  const float* w1      = (const float*)d_in[1];
  const float* b1      = (const float*)d_in[2];
  const float* w2      = (const float*)d_in[3];
  const float* b2      = (const float*)d_in[4];
  const float* w3      = (const float*)d_in[5];
  const float* b3      = (const float*)d_in[6];
  const float* oxo_w   = (const float*)d_in[7];
  const float* oxo_b   = (const float*)d_in[8];
  const float* lf_w    = (const float*)d_in[9];
  const float* lf_b    = (const float*)d_in[10];
  const float* gadj    = (const float*)d_in[11];
  const float* entry_w = (const float*)d_in[12];
  const float* entry_b = (const float*)d_in[13];
  const float* pool_w  = (const float*)d_in[14];
  const float* pool_b  = (const float*)d_in[15];
  const float* pl_w    = (const float*)d_in[16];
  const float* pl_b    = (const float*)d_in[17];
  const float* embed_w = (const float*)d_in[18];
  const float* embed_b = (const float*)d_in[19];
  const float* fc1_w   = (const float*)d_in[20];
  const float* fc1_b   = (const float*)d_in[21];
  const float* fc2_w   = (const float*)d_in[22];
  const float* fc2_b   = (const float*)d_in[23];
  const float* fc3_w   = (const float*)d_in[24];
  const float* fc3_b   = (const float*)d_in[25];

  char* ws = (char*)d_ws;
  size_t off = 0;
  auto take = [&](size_t bytes){ size_t o = off; off = (off + bytes + 15) & ~(size_t)15; return o; };

  size_t feat_o = take(FEAT_N*4);          // conv logs; k_mix writes pooled rows in place
  size_t zstart = off;                     // ---- zeroed zone (atomic accumulators) ----
  size_t P_o     = take(P_N*4);
  size_t Q_o     = take(Q_N*4);
  size_t r_o     = take(R_N*4);
  size_t statE_o = take(124*8);
  size_t statP_o = take(124*8);
  size_t statH_o = take(64*8);
  size_t accs_o  = take(2*8);
  size_t zend = off;                       // ---- end zeroed zone ----
  size_t stat1_o = take(64*8);
  size_t stat2_o = take(64*8);
  size_t wcol_o  = take(96*4);
  size_t w2t_o   = take(1024*4);
  size_t cf_o    = take(32*4);
  size_t part1_o = take(PART_N*4);
  size_t part2_o = take(PART_N*4);
  size_t adj_o   = take(ADJ_N*4);
  size_t hE_o    = take(HE_N*4);
  size_t hP_o    = take(HP_N*4);
  size_t hpre_o  = take(HPRE_N*4);
  size_t opre_o  = take(128*4);
  size_t wpad_o  = take(WPAD_N*4);

  if (off > ws_size) {                     // diagnostic: ws too small
    k_wsfail<<<(out_size+255)/256, 256, 0, stream>>>((float*)d_out, out_size);
    return;
  }

  float*  feat  = (float*)(ws+feat_o);
  float*  P_g   = (float*)(ws+P_o);
  float*  Q_g   = (float*)(ws+Q_o);
  float*  r_g   = (float*)(ws+r_o);
  double* statE = (double*)(ws+statE_o);
  double* statP = (double*)(ws+statP_o);
  double* statH = (double*)(ws+statH_o);
  double* accs  = (double*)(ws+accs_o);
  double* stat1 = (double*)(ws+stat1_o);
  double* stat2 = (double*)(ws+stat2_o);
  float*  wcol  = (float*)(ws+wcol_o);
  float*  W2T   = (float*)(ws+w2t_o);
  float*  Cf    = (float*)(ws+cf_o);
  float*  part1 = (float*)(ws+part1_o);
  float*  part2 = (float*)(ws+part2_o);
  float*  adj_g = (float*)(ws+adj_o);
  float*  hE_g  = (float*)(ws+hE_o);
  float*  hP_g  = (float*)(ws+hP_o);
  float*  hpre  = (float*)(ws+hpre_o);
  float*  opre  = (float*)(ws+opre_o);
  float*  wpad  = (float*)(ws+wpad_o);
  float*  out   = (float*)d_out;

  hipMemsetAsync(ws + zstart, 0, zend - zstart, stream);

  k_prep<<<122, 256, 0, stream>>>(w1, w2, w3, entry_w, pool_w, wpad, wcol);
  k_conv<<<cNBC, 256, 0, stream>>>(x, wpad, b1, b2, b3, feat, part1);
  k_reduce_stats<<<32, 256, 0, stream>>>(part1, stat1, cNBC, 32);
  k_foldw<<<1, 256, 0, stream>>>(stat1, oxo_w, oxo_b, W2T, Cf);
  k_mix<<<cNBC, 256, 0, stream>>>(feat, W2T, Cf, part2);
  k_reduce_stats<<<32, 256, 0, stream>>>(part2, stat2, cNBC, 32);
  k_gramow<<<cB*16, 256, 0, stream>>>(feat, stat2, lf_w, lf_b, entry_w, pool_w, P_g, Q_g, r_g);
  k_adjgcn<<<cB, 256, 0, stream>>>(P_g, r_g, gadj, Q_g, wcol, entry_b, pool_b,
                                   adj_g, hE_g, hP_g, statE, statP);
  k_pool<<<cB, 256, 0, stream>>>(adj_g, hE_g, hP_g, statE, statP, pl_w, pl_b,
                                 embed_w, embed_b, hpre, statH, accs);
  k_head<<<cB, 128, 0, stream>>>(hE_g, hpre, statE, statH, fc1_w, fc1_b, fc2_w, fc2_b, fc3_w, fc3_b, opre);
  k_final<<<1, 64, 0, stream>>>(opre, accs, out);
}

// Round 9
// 780.604 us; speedup vs baseline: 1.2989x; 1.1487x over previous
//
#include <hip/hip_runtime.h>
#include <math.h>

typedef float  f32x4 __attribute__((ext_vector_type(4)));
typedef short  s16x4 __attribute__((ext_vector_type(4)));
typedef short  s16x8 __attribute__((ext_vector_type(8)));

// ---------------- problem constants ----------------
constexpr int cB  = 32;
constexpr int cC  = 62;
constexpr int cT  = 1024;
constexpr int cNT = 32;
constexpr int cLT = 708;    // 247+240+221
constexpr int cLT2= 354;
constexpr int cFD = 11328;
constexpr int cNBC = cB*cC;

constexpr size_t FEAT_N = (size_t)cB*cNT*cC*cLT;
constexpr size_t P_N    = (size_t)cB*cC*cC;
constexpr size_t Q_N    = (size_t)cB*cC*96;
constexpr size_t R_N    = (size_t)cB*64;
constexpr size_t PART_N = (size_t)cNBC*64;
constexpr size_t ADJ_N  = P_N;
constexpr size_t HE_N   = (size_t)cB*cC*64;
constexpr size_t HP_N   = (size_t)cB*cC*32;
constexpr size_t HPRE_N = (size_t)cB*32*64;
constexpr int WBF_N = 32*32 + 32*64 + 32*128;   // 7168 bf16 padded weights (K->32/64/128)

__device__ __forceinline__ unsigned short bf16rne(float v){
  unsigned int u = __float_as_uint(v);
  unsigned int r = (u + 0x7fffu + ((u>>16)&1u)) >> 16;
  return (unsigned short)r;
}

// ---------------- prep: split-bf16 padded conv weights + wcol ----------------
__global__ __launch_bounds__(256) void k_prep(
    const float* __restrict__ w1, const float* __restrict__ w2,
    const float* __restrict__ w3, const float* __restrict__ entry_w,
    const float* __restrict__ pool_w,
    unsigned short* __restrict__ wH, unsigned short* __restrict__ wL,
    float* __restrict__ wcol)
{
  int blk = blockIdx.x, tid = threadIdx.x;
  if (blk < 28){
    int i = blk*256 + tid;   // 0..7167
    float v;
    if (i < 1024){ int f=i>>5, k=i&31; v = (k<25) ? w1[f*25+k] : 0.f; }
    else if (i < 3072){ int j=i-1024; int f=j>>6, k=j&63; v = (k<51) ? w2[f*51+k] : 0.f; }
    else { v = w3[i-3072]; }
    unsigned short h = bf16rne(v);
    float hf = __uint_as_float(((unsigned int)h)<<16);
    wH[i] = h;
    wL[i] = bf16rne(v - hf);
  } else {
    int j = blk - 28;          // 0..95
    float s = 0.f;
    if (j < 64){ for (int k=tid;k<cFD;k+=256) s += entry_w[(size_t)k*64 + j]; }
    else       { for (int k=tid;k<cFD;k+=256) s += pool_w[(size_t)k*32 + (j-64)]; }
    __shared__ float red[256];
    red[tid]=s; __syncthreads();
    for (int o=128;o>0;o>>=1){ if(tid<o) red[tid]+=red[tid+o]; __syncthreads(); }
    if (tid==0) wcol[j] = red[0];
  }
}

// ---------------- MFMA conv branch: D[pos16 x filt16], split-bf16 (hh+hl+lh) ----------------
// A[m=lane&15][k=quad*8+j] = x[P0+m+k] via 4 shift-copies (aligned ds_read_b64 pairs).
// B[k][n=lane&15] = w[filter n][k], global loads (L1/L2-hot).
// D row=(lane>>4)*4+r -> 4 consecutive positions -> in-lane 4-square sum -> 1 pt write.
template<int KS, int MT, int WOFF>
__device__ __forceinline__ void mfma_branch(
    const unsigned short* xH, const unsigned short* xL,
    const unsigned short* __restrict__ wHg, const unsigned short* __restrict__ wLg,
    const float* __restrict__ biasg, float* pt, int tid)
{
  int lane = tid & 63, wv = tid >> 6;
  int f = lane & 15, q = lane >> 4;
  int s = lane & 3;
  int a12 = lane & 12;
  s16x8 BH[2][KS], BL[2][KS];
  #pragma unroll
  for (int nt=0; nt<2; nt++)
    #pragma unroll
    for (int ks=0; ks<KS; ks++){
      size_t wo = (size_t)WOFF + (size_t)(nt*16+f)*(KS*32) + ks*32 + q*8;
      BH[nt][ks] = *(const s16x8*)&wHg[wo];
      BL[nt][ks] = *(const s16x8*)&wLg[wo];
    }
  float bv0 = biasg[f], bv1 = biasg[16+f];
  for (int mt = wv; mt < MT; mt += 4){
    f32x4 acc0 = {0.f,0.f,0.f,0.f};
    f32x4 acc1 = {0.f,0.f,0.f,0.f};
    int e0 = mt*16 + a12;
    #pragma unroll
    for (int ks=0; ks<KS; ks++){
      int e = e0 + q*8 + ks*32;
      const unsigned short* ph = xH + s*1160 + e;
      const unsigned short* pl = xL + s*1160 + e;
      s16x4 h0 = *(const s16x4*)ph;
      s16x4 h1 = *(const s16x4*)(ph+4);
      s16x4 l0 = *(const s16x4*)pl;
      s16x4 l1 = *(const s16x4*)(pl+4);
      s16x8 Ah = __builtin_shufflevector(h0,h1,0,1,2,3,4,5,6,7);
      s16x8 Al = __builtin_shufflevector(l0,l1,0,1,2,3,4,5,6,7);
      acc0 = __builtin_amdgcn_mfma_f32_16x16x32_bf16(Ah, BH[0][ks], acc0, 0,0,0);
      acc0 = __builtin_amdgcn_mfma_f32_16x16x32_bf16(Ah, BL[0][ks], acc0, 0,0,0);
      acc0 = __builtin_amdgcn_mfma_f32_16x16x32_bf16(Al, BH[0][ks], acc0, 0,0,0);
      acc1 = __builtin_amdgcn_mfma_f32_16x16x32_bf16(Ah, BH[1][ks], acc1, 0,0,0);
      acc1 = __builtin_amdgcn_mfma_f32_16x16x32_bf16(Ah, BL[1][ks], acc1, 0,0,0);
      acc1 = __builtin_amdgcn_mfma_f32_16x16x32_bf16(Al, BH[1][ks], acc1, 0,0,0);
    }
    float p0=0.f, p1=0.f;
    #pragma unroll
    for (int r=0;r<4;r++){
      float t0 = acc0[r]+bv0; p0 = fmaf(t0,t0,p0);
      float t1 = acc1[r]+bv1; p1 = fmaf(t1,t1,p1);
    }
    pt[(size_t)f*261      + mt*4 + q] = p0;
    pt[(size_t)(16+f)*261 + mt*4 + q] = p1;
  }
}

// ---------------- pool: u = tid (coalesced feat writes), wave-reduce stats ----------------
template<int P, int OFF>
__device__ __forceinline__ void pool_phase(
    const float* pt, float* __restrict__ feat, size_t rstr, size_t base_bc,
    float* tsum, float* tsq, int tid)
{
  bool act = tid < P;
  for (int fi=0; fi<32; fi++){
    float lv = 0.f;
    if (act){
      const float* pp = &pt[(size_t)fi*261 + tid];
      float pooled = (pp[0]+pp[1]+pp[2]+pp[3])*(1.f/16.f);
      lv = __logf(pooled);
      feat[base_bc + (size_t)fi*rstr + OFF + tid] = lv;
    }
    float v = lv, qq = lv*lv;
    #pragma unroll
    for (int o=32;o>0;o>>=1){ v += __shfl_down(v,o,64); qq += __shfl_down(qq,o,64); }
    if ((tid&63)==0){ atomicAdd(&tsum[fi], v); atomicAdd(&tsq[fi], qq); }
  }
}

__global__ __launch_bounds__(256) void k_conv(
    const float* __restrict__ x,
    const unsigned short* __restrict__ wH, const unsigned short* __restrict__ wL,
    const float* __restrict__ b1, const float* __restrict__ b2, const float* __restrict__ b3,
    float* __restrict__ feat, float* __restrict__ part1)
{
  __shared__ unsigned short xH[4*1160];
  __shared__ unsigned short xL[4*1160];
  __shared__ float pt[32*261];
  __shared__ float tsum[32], tsq[32];
  int b = blockIdx.x / cC, c = blockIdx.x % cC;
  int tid = threadIdx.x;
  const float* xg = x + (size_t)(b*cC+c)*cT;
  if (tid<32){ tsum[tid]=0.f; tsq[tid]=0.f; }
  for (int i=tid; i<4*1160; i+=256){
    int s = i / 1160, idx = i - s*1160;
    int src = idx + s;
    float v = (src < 1024) ? xg[src] : 0.f;
    unsigned short h = bf16rne(v);
    float hf = __uint_as_float(((unsigned int)h)<<16);
    xH[i] = h;
    xL[i] = bf16rne(v - hf);
  }
  size_t base_bc = ((size_t)(b*cNT)*cC + c)*cLT;
  size_t rstr = (size_t)cC*cLT;
  __syncthreads();
  mfma_branch<1,63,0>(xH,xL,wH,wL,b1,pt,tid);
  __syncthreads();
  pool_phase<247,0>(pt,feat,rstr,base_bc,tsum,tsq,tid);
  __syncthreads();
  mfma_branch<2,61,1024>(xH,xL,wH,wL,b2,pt,tid);
  __syncthreads();
  pool_phase<240,247>(pt,feat,rstr,base_bc,tsum,tsq,tid);
  __syncthreads();
  mfma_branch<4,57,3072>(xH,xL,wH,wL,b3,pt,tid);
  __syncthreads();
  pool_phase<221,487>(pt,feat,rstr,base_bc,tsum,tsq,tid);
  __syncthreads();
  if (tid<32){
    part1[(size_t)blockIdx.x*64 + tid*2]   = tsum[tid];
    part1[(size_t)blockIdx.x*64 + tid*2+1] = tsq[tid];
  }
}

// ---------------- partial-stat reduction ----------------
__global__ __launch_bounds__(256) void k_reduce_stats(
    const float* __restrict__ part, double* __restrict__ stat, int nblk, int nch)
{
  int ch = blockIdx.x, tid = threadIdx.x;
  double s=0,q=0;
  for (int i=tid;i<nblk;i+=256){
    s += (double)part[(size_t)i*nch*2 + ch*2];
    q += (double)part[(size_t)i*nch*2 + ch*2 + 1];
  }
  __shared__ double ls[256], lq[256];
  ls[tid]=s; lq[tid]=q; __syncthreads();
  for (int o=128;o>0;o>>=1){ if(tid<o){ls[tid]+=ls[tid+o]; lq[tid]+=lq[tid+o];} __syncthreads(); }
  if (tid==0){ stat[ch*2]=ls[0]; stat[ch*2+1]=lq[0]; }
}

// ---------------- fold BN1 into mix weights ----------------
__global__ void k_foldw(const double* __restrict__ stat1,
                        const float* __restrict__ oxo_w, const float* __restrict__ oxo_b,
                        float* __restrict__ W2T, float* __restrict__ Cf)
{
  __shared__ float mu[32], inv[32];
  int tid = threadIdx.x;
  if (tid<32){
    double cnt = (double)cB*cC*cLT;
    double m = stat1[tid*2]/cnt;
    double v = stat1[tid*2+1]/cnt - m*m;
    mu[tid] = (float)m; inv[tid] = (float)(1.0/sqrt(v+1e-5));
  }
  __syncthreads();
  for (int i=tid;i<1024;i+=256){
    int t=i>>5, o=i&31;
    W2T[t*32+o] = oxo_w[o*32+t]*inv[t];
  }
  if (tid<32){
    float cacc = oxo_b[tid];
    for (int t=0;t<32;t++) cacc -= oxo_w[tid*32+t]*inv[t]*mu[t];
    Cf[tid] = cacc;
  }
}

// ---------------- mix: BN folded, all-LDS inner, IN-PLACE ----------------
__global__ __launch_bounds__(256) void k_mix(
    float* __restrict__ feat, const float* __restrict__ W2T,
    const float* __restrict__ Cf, float* __restrict__ part2)
{
  __shared__ float ft[32*240];
  __shared__ float wLh[1024];
  __shared__ float cL[32];
  int b = blockIdx.x / cC, c = blockIdx.x % cC;
  int tid = threadIdx.x;
  int lane = tid & 63, oset = (tid>>6)*8;
  for (int i=tid;i<1024;i+=256) wLh[i] = W2T[i];
  if (tid<32) cL[tid] = Cf[tid];
  float sacc[8]={0,0,0,0,0,0,0,0}, qacc[8]={0,0,0,0,0,0,0,0};
  for (int ch=0; ch<3; ch++){
    int l0 = ch*236;
    __syncthreads();
    for (int g=tid; g<32*59; g+=256){
      int t = g/59, l4 = (g - t*59)*4;
      *(float4*)&ft[t*240+l4] = *(const float4*)&feat[((size_t)(b*cNT+t)*cC + c)*cLT + l0 + l4];
    }
    __syncthreads();
    if (lane < 59){
      float m[8][4];
      #pragma unroll
      for (int f=0;f<8;f++){ float cv=cL[oset+f]; m[f][0]=cv;m[f][1]=cv;m[f][2]=cv;m[f][3]=cv; }
      #pragma unroll 4
      for (int t=0;t<32;t++){
        float4 z = *(const float4*)&ft[t*240 + 4*lane];
        float4 wa = *(const float4*)&wLh[t*32+oset];
        float4 wb = *(const float4*)&wLh[t*32+oset+4];
        float w8a[8] = {wa.x,wa.y,wa.z,wa.w, wb.x,wb.y,wb.z,wb.w};
        #pragma unroll
        for (int f=0;f<8;f++){
          m[f][0]=fmaf(z.x,w8a[f],m[f][0]);
          m[f][1]=fmaf(z.y,w8a[f],m[f][1]);
          m[f][2]=fmaf(z.z,w8a[f],m[f][2]);
          m[f][3]=fmaf(z.w,w8a[f],m[f][3]);
        }
      }
      #pragma unroll
      for (int f=0;f<8;f++){
        float a0 = m[f][0]>0.f ? m[f][0] : 0.01f*m[f][0];
        float a1 = m[f][1]>0.f ? m[f][1] : 0.01f*m[f][1];
        float a2 = m[f][2]>0.f ? m[f][2] : 0.01f*m[f][2];
        float a3 = m[f][3]>0.f ? m[f][3] : 0.01f*m[f][3];
        float v0 = 0.5f*(a0+a1), v1 = 0.5f*(a2+a3);
        float2 st; st.x=v0; st.y=v1;
        *(float2*)&feat[((size_t)(b*cNT+oset+f)*cC + c)*cLT + 118*ch + 2*lane] = st;
        sacc[f] += v0+v1; qacc[f] += v0*v0+v1*v1;
      }
    }
  }
  #pragma unroll
  for (int f=0;f<8;f++){
    float s = sacc[f], q = qacc[f];
    #pragma unroll
    for (int o=32;o>0;o>>=1){ s += __shfl_down(s,o,64); q += __shfl_down(q,o,64); }
    if (lane==0){
      part2[(size_t)blockIdx.x*64 + (oset+f)*2]   = s;
      part2[(size_t)blockIdx.x*64 + (oset+f)*2+1] = q;
    }
  }
}

// ---------------- raw gram/ow/rowsum: P = V V^T, Q = V W, r = V 1 ----------------
__global__ __launch_bounds__(256) void k_gramow(
    const float* __restrict__ featbuf, const double* __restrict__ stat2,
    const float* __restrict__ lf_w, const float* __restrict__ lf_b,
    const float* __restrict__ entry_w, const float* __restrict__ pool_w,
    float* __restrict__ P, float* __restrict__ Q, float* __restrict__ r_g)
{
  __shared__ float lt[64*68];
  __shared__ float lw[64*100];
  __shared__ float a_s[32], b_s[32];
  __shared__ float lbs[64];
  int b = blockIdx.x >> 4, ks = blockIdx.x & 15;
  int tid = threadIdx.x;
  if (tid<32){
    double cnt = (double)cB*cC*cLT2;
    double m = stat2[tid*2]/cnt;
    double v = stat2[tid*2+1]/cnt - m*m;
    float inv = (float)(1.0/sqrt(v+1e-5));
    a_s[tid] = inv;
    b_s[tid] = -(float)m * inv;
  }
  if (tid<64) lbs[tid] = (tid<62) ? lf_b[tid] : 0.f;
  float accG[4][4] = {{0.f}};
  float accO[4][6] = {{0.f}};
  float accR[4]    = {0.f,0.f,0.f,0.f};
  int n0 = (tid>>4)<<2;
  int mg = (tid&15)<<2;
  int jo = (tid&15)*6;
  int kk = tid & 63, nr = tid >> 6;
  for (int tile=ks; tile<177; tile+=16){
    int k0 = tile<<6;
    int f = k0 + kk, t = f/cLT2, l2 = f - t*cLT2;
    __syncthreads();
    for (int n=nr; n<64; n+=4){
      float v = 0.f;
      if (n<62){
        float raw = featbuf[((size_t)(b*cNT+t)*cC + n)*cLT + l2];
        float z = fmaf(raw, a_s[t], b_s[t]);
        v = fmaxf(fmaf(z, lf_w[(size_t)n*cFD + f], -lbs[n]), 0.f);
      }
      lt[kk*68 + n] = v;
    }
    for (int i=tid;i<6144;i+=256){
      int kw = i/96, j = i-kw*96;
      float wv = (j<64) ? entry_w[(size_t)(k0+kw)*64 + j] : pool_w[(size_t)(k0+kw)*32 + (j-64)];
      lw[kw*100 + j] = wv;
    }
    __syncthreads();
    #pragma unroll 4
    for (int k=0;k<64;k++){
      const float4 av = *(const float4*)&lt[k*68 + n0];
      const float4 bv = *(const float4*)&lt[k*68 + mg];
      const float2 w0 = *(const float2*)&lw[k*100+jo];
      const float2 w1 = *(const float2*)&lw[k*100+jo+2];
      const float2 w2 = *(const float2*)&lw[k*100+jo+4];
      float avv[4] = {av.x,av.y,av.z,av.w};
      float bvv[4] = {bv.x,bv.y,bv.z,bv.w};
      float wv[6]  = {w0.x,w0.y,w1.x,w1.y,w2.x,w2.y};
      #pragma unroll
      for (int i=0;i<4;i++){
        accR[i] += avv[i];
        #pragma unroll
        for (int j=0;j<4;j++) accG[i][j] = fmaf(avv[i], bvv[j], accG[i][j]);
        #pragma unroll
        for (int j=0;j<6;j++) accO[i][j] = fmaf(avv[i], wv[j], accO[i][j]);
      }
    }
  }
  for (int i=0;i<4;i++) if (n0+i<62){
    for (int j=0;j<4;j++) if (mg+j<62)
      atomicAdd(&P[((size_t)b*cC + n0+i)*cC + mg+j], accG[i][j]);
    for (int j=0;j<6;j++)
      atomicAdd(&Q[((size_t)b*cC + n0+i)*96 + jo+j], accO[i][j]);
  }
  if ((tid&15)==0)
    for (int i=0;i<4;i++) if (n0+i<62)
      atomicAdd(&r_g[(size_t)b*64 + n0+i], accR[i]);
}

// ---------------- merged: statC + adjacency + GCN1 ----------------
__global__ __launch_bounds__(256) void k_adjgcn(
    const float* __restrict__ P, const float* __restrict__ r_g,
    const float* __restrict__ gadj, const float* __restrict__ Q,
    const float* __restrict__ wcol,
    const float* __restrict__ entry_b, const float* __restrict__ pool_b,
    float* __restrict__ adj, float* __restrict__ hE, float* __restrict__ hP,
    double* __restrict__ statE, double* __restrict__ statP)
{
  __shared__ float a[3844];
  __shared__ float oL[5952];
  __shared__ float dsh[62];
  __shared__ float rL[62], mL[62], iL[62], wcL[96];
  __shared__ float es[62], eq[62], ps[62], pq[62];
  int b = blockIdx.x, tid = threadIdx.x;
  if (tid<62){
    double S=0, SQ=0;
    for (int b2=0;b2<32;b2++){
      S  += (double)r_g[(size_t)b2*64 + tid];
      SQ += (double)P[((size_t)b2*cC + tid)*cC + tid];
    }
    double cnt = (double)cB*cFD;
    double m = S/cnt, var = SQ/cnt - m*m;
    mL[tid] = (float)m;
    iL[tid] = (float)(1.0/sqrt(var+1e-5));
    rL[tid] = r_g[(size_t)b*64+tid];
    es[tid]=0.f; eq[tid]=0.f; ps[tid]=0.f; pq[tid]=0.f;
  }
  if (tid>=64 && tid<160) wcL[tid-64]=wcol[tid-64];
  __syncthreads();
  for (int i=tid;i<3844;i+=256){
    int n=i/62, m=i-n*62;
    float sv = (P[(size_t)b*3844+i] - mL[n]*rL[m] - mL[m]*rL[n] + (float)cFD*mL[n]*mL[m]) * iL[n]*iL[m];
    float g = gadj[n*62+m] + gadj[m*62+n];
    float v = sv*g;
    v = v>0.f ? v : 0.f;
    if (n==m) v += 1.f;
    a[i]=v;
  }
  for (int i=tid;i<5952;i+=256){
    int m=i/96, j=i-m*96;
    oL[i] = (Q[(size_t)b*5952+i] - mL[m]*wcL[j]) * iL[m];
  }
  __syncthreads();
  if (tid<62){
    float rsum=0.f;
    for (int m=0;m<62;m++) rsum += a[tid*62+m];
    if (rsum==0.f) rsum=1.f;
    dsh[tid] = 1.0f/sqrtf(rsum);
  }
  __syncthreads();
  for (int i=tid;i<3844;i+=256){
    int n=i/62, m=i-n*62;
    float v = a[i]*dsh[n]*dsh[m];
    a[i] = v;
    adj[(size_t)b*3844+i] = v;
  }
  __syncthreads();
  for (int i=tid;i<5952;i+=256){
    int n=i/96, j=i-n*96;
    float v=0.f;
    for (int m=0;m<62;m++) v = fmaf(a[n*62+m], oL[m*96+j], v);
    if (j<64){
      v -= entry_b[j];
      hE[((size_t)b*62+n)*64 + j] = v;
      atomicAdd(&es[n],v); atomicAdd(&eq[n],v*v);
    } else {
      int j2=j-64;
      v -= pool_b[j2];
      hP[((size_t)b*62+n)*32 + j2] = v;
      atomicAdd(&ps[n],v); atomicAdd(&pq[n],v*v);
    }
  }
  __syncthreads();
  if (tid<62){
    atomicAdd(&statE[tid*2],(double)es[tid]);
    atomicAdd(&statE[tid*2+1],(double)eq[tid]);
    atomicAdd(&statP[tid*2],(double)ps[tid]);
    atomicAdd(&statP[tid*2+1],(double)pq[tid]);
  }
}

// ---------------- dense_diff_pool + in-block assign/bn + embed GCN pre + losses ----------------
__global__ __launch_bounds__(256) void k_pool(
    const float* __restrict__ adj, const float* __restrict__ hEraw,
    const float* __restrict__ hPraw,
    const double* __restrict__ statE, const double* __restrict__ statP,
    const float* __restrict__ pl_w, const float* __restrict__ pl_b,
    const float* __restrict__ embed_w, const float* __restrict__ embed_b,
    float* __restrict__ hpre, double* __restrict__ statH, double* __restrict__ accs)
{
  __shared__ float aL[3844];
  __shared__ float sL[1984];
  __shared__ float hL[3968];
  __shared__ float t1[1984];
  __shared__ float xp[2048];
  __shared__ float ap[1024];
  __shared__ float red[256];
  __shared__ float ksum[32], ksq[32];
  __shared__ float mE[62], iE[62], mP[62], iP[62];
  float* e1 = hL;
  float* sT = t1;
  float* hPL = xp;
  float* plw = ap;
  int b = blockIdx.x, tid = threadIdx.x;
  if (tid<62){
    double cntE = (double)cB*64;
    double m = statE[tid*2]/cntE;
    double v = statE[tid*2+1]/cntE - m*m;
    mE[tid]=(float)m; iE[tid]=(float)(1.0/sqrt(v+1e-5));
    double cntP = (double)cB*32;
    double m2 = statP[tid*2]/cntP;
    double v2 = statP[tid*2+1]/cntP - m2*m2;
    mP[tid]=(float)m2; iP[tid]=(float)(1.0/sqrt(v2+1e-5));
  }
  if (tid<32){ksum[tid]=0.f;ksq[tid]=0.f;}
  for (int i=tid;i<3844;i+=256) aL[i]=adj[(size_t)b*3844+i];
  for (int i=tid;i<1984;i+=256) hPL[i]=hPraw[(size_t)b*1984+i];
  for (int i=tid;i<1024;i+=256) plw[i]=pl_w[i];
  __syncthreads();
  for (int i=tid;i<3968;i+=256){
    int n = i>>6;
    hL[i] = (hEraw[(size_t)b*3968+i]-mE[n])*iE[n];
  }
  int r0 = tid>>5, o = tid&31;
  float entacc = 0.f;
  for (int n=r0; n<62; n+=8){
    float y = pl_b[o];
    float mm = mP[n], ii = iP[n];
    #pragma unroll 8
    for (int j=0;j<32;j++)
      y = fmaf((hPL[n*32+j]-mm)*ii, plw[j*32+o], y);
    float mx = y;
    for (int d=16;d>0;d>>=1) mx = fmaxf(mx, __shfl_xor(mx,d,32));
    float e = expf(y-mx);
    float sum = e;
    for (int d=16;d>0;d>>=1) sum += __shfl_xor(sum,d,32);
    float p = e/sum;
    sL[n*32+o] = p;
    entacc += -p*logf(p+1e-30f);
  }
  red[tid]=entacc; __syncthreads();
  for (int o2=128;o2>0;o2>>=1){ if(tid<o2) red[tid]+=red[tid+o2]; __syncthreads(); }
  if (tid==0) atomicAdd(&accs[1], (double)red[0]);
  __syncthreads();
  for (int i=tid;i<2048;i+=256){
    int k=i>>6, f=i&63;
    float v=0.f;
    for (int n=0;n<62;n++) v = fmaf(sL[n*32+k], hL[n*64+f], v);
    xp[i]=v;
  }
  for (int i=tid;i<1984;i+=256){
    int n=i>>5, k=i&31;
    float v=0.f;
    for (int m=0;m<62;m++) v = fmaf(aL[n*62+m], sL[m*32+k], v);
    t1[i]=v;
  }
  __syncthreads();
  for (int i=tid;i<1024;i+=256){
    int k=i>>5, l=i&31;
    float v=0.f;
    for (int n=0;n<62;n++) v = fmaf(sL[n*32+k], t1[n*32+l], v);
    ap[i]=v;
  }
  __syncthreads();
  for (int i=tid;i<1984;i+=256){
    int k=i/62, n=i-k*62;
    sT[k*62+n] = sL[n*32+k];
  }
  __syncthreads();
  float lacc=0.f;
  for (int i=tid;i<3844;i+=256){
    int n=i/62, m=i-n*62;
    float v=0.f;
    for (int k=0;k<32;k++) v = fmaf(sT[k*62+n], sT[k*62+m], v);
    float d = aL[i]-v+1e-30f;
    lacc = fmaf(d,d,lacc);
  }
  red[tid]=lacc; __syncthreads();
  for (int o2=128;o2>0;o2>>=1){ if(tid<o2) red[tid]+=red[tid+o2]; __syncthreads(); }
  if (tid==0) atomicAdd(&accs[0], (double)red[0]);
  __syncthreads();
  for (int i=tid;i<2048;i+=256){
    int k=i>>6, f=i&63;
    float v=0.f;
    for (int l=0;l<32;l++) v = fmaf(ap[k*32+l], xp[l*64+f], v);
    e1[i]=v;
  }
  __syncthreads();
  for (int i=tid;i<2048;i+=256){
    int k=i>>6, j=i&63;
    float v=0.f;
    for (int f=0;f<64;f++) v = fmaf(e1[k*64+f], embed_w[f*64+j], v);
    v -= embed_b[j];
    hpre[(size_t)b*2048 + i] = v;
    atomicAdd(&ksum[k], v);
    atomicAdd(&ksq[k], v*v);
  }
  __syncthreads();
  if (tid<32){
    atomicAdd(&statH[tid*2],   (double)ksum[tid]);
    atomicAdd(&statH[tid*2+1], (double)ksq[tid]);
  }
}

// ---------------- reps + MLP head ----------------
__global__ __launch_bounds__(128) void k_head(
    const float* __restrict__ hEraw, const float* __restrict__ hpre,
    const double* __restrict__ statE, const double* __restrict__ statH,
    const float* __restrict__ fc1_w, const float* __restrict__ fc1_b,
    const float* __restrict__ fc2_w, const float* __restrict__ fc2_b,
    const float* __restrict__ fc3_w, const float* __restrict__ fc3_b,
    float* __restrict__ o_pre)
{
  __shared__ float o1[128], y1[128], y2[64];
  __shared__ float mk[32], ik[32];
  __shared__ float mE[62], iE[62];
  int b = blockIdx.x, tid = threadIdx.x;
  if (tid<32){
    double cnt = 2048.0;
    double m = statH[tid*2]/cnt;
    double v = statH[tid*2+1]/cnt - m*m;
    mk[tid]=(float)m; ik[tid]=(float)(1.0/sqrt(v+1e-5));
  }
  if (tid>=64 && tid<126){
    int n = tid-64;
    double cnt = (double)cB*64;
    double m = statE[n*2]/cnt;
    double v = statE[n*2+1]/cnt - m*m;
    mE[n]=(float)m; iE[n]=(float)(1.0/sqrt(v+1e-5));
  }
  __syncthreads();
  if (tid<64){
    float s1=0.f;
    for (int n=0;n<62;n++)
      s1 += (hEraw[((size_t)b*62+n)*64+tid]-mE[n])*iE[n];
    o1[tid]=s1;
    float s2=0.f;
    for (int k=0;k<32;k++) s2 += (hpre[(size_t)b*2048 + k*64+tid]-mk[k])*ik[k];
    o1[64+tid]=s2;
  }
  __syncthreads();
  {
    float y = fc1_b[tid];
    for (int j=0;j<128;j++) y = fmaf(o1[j], fc1_w[j*128+tid], y);
    y1[tid] = fmaxf(y,0.f);
  }
  __syncthreads();
  if (tid<64){
    float z = fc2_b[tid];
    for (int j=0;j<128;j++) z = fmaf(y1[j], fc2_w[j*64+tid], z);
    y2[tid]=fmaxf(z,0.f);
  }
  __syncthreads();
  if (tid<4){
    float w = fc3_b[tid];
    for (int j=0;j<64;j++) w = fmaf(y2[j], fc3_w[j*4+tid], w);
    o_pre[b*4+tid]=w;
  }
}

// ---------------- final BN + losses ----------------
__global__ void k_final(const float* __restrict__ o_pre, const double* __restrict__ accs,
                        float* __restrict__ out)
{
  int tid = threadIdx.x;
  if (tid<4){
    float s=0.f,q=0.f;
    for (int b=0;b<32;b++){ float v=o_pre[b*4+tid]; s+=v; q+=v*v; }
    float m = s*(1.f/32.f);
    float var = q*(1.f/32.f) - m*m;
    float inv = 1.0f/sqrtf(var+1e-5f);
    for (int b=0;b<32;b++) out[b*4+tid] = (o_pre[b*4+tid]-m)*inv;
  }
  if (tid==4) out[128] = (float)(sqrt(accs[0])/123008.0);
  if (tid==5) out[129] = (float)(accs[1]/1984.0);
}

__global__ void k_wsfail(float* __restrict__ out, int n)
{
  int i = blockIdx.x*256 + threadIdx.x;
  if (i < n) out[i] = 12345.0f;
}

// ============================================================================
extern "C" void kernel_launch(void* const* d_in, const int* in_sizes, int n_in,
                              void* d_out, int out_size, void* d_ws, size_t ws_size,
                              hipStream_t stream)
{
  const float* x       = (const float*)d_in[0];
  const float* w1      = (const float*)d_in[1];
  const float* b1      = (const float*)d_in[2];
  const float* w2      = (const float*)d_in[3];
  const float* b2      = (const float*)d_in[4];
  const float* w3      = (const float*)d_in[5];
  const float* b3      = (const float*)d_in[6];
  const float* oxo_w   = (const float*)d_in[7];
  const float* oxo_b   = (const float*)d_in[8];
  const float* lf_w    = (const float*)d_in[9];
  const float* lf_b    = (const float*)d_in[10];
  const float* gadj    = (const float*)d_in[11];
  const float* entry_w = (const float*)d_in[12];
  const float* entry_b = (const float*)d_in[13];
  const float* pool_w  = (const float*)d_in[14];
  const float* pool_b  = (const float*)d_in[15];
  const float* pl_w    = (const float*)d_in[16];
  const float* pl_b    = (const float*)d_in[17];
  const float* embed_w = (const float*)d_in[18];
  const float* embed_b = (const float*)d_in[19];
  const float* fc1_w   = (const float*)d_in[20];
  const float* fc1_b   = (const float*)d_in[21];
  const float* fc2_w   = (const float*)d_in[22];
  const float* fc2_b   = (const float*)d_in[23];
  const float* fc3_w   = (const float*)d_in[24];
  const float* fc3_b   = (const float*)d_in[25];

  char* ws = (char*)d_ws;
  size_t off = 0;
  auto take = [&](size_t bytes){ size_t o = off; off = (off + bytes + 15) & ~(size_t)15; return o; };

  size_t feat_o = take(FEAT_N*4);
  size_t zstart = off;
  size_t P_o     = take(P_N*4);
  size_t Q_o     = take(Q_N*4);
  size_t r_o     = take(R_N*4);
  size_t statE_o = take(124*8);
  size_t statP_o = take(124*8);
  size_t statH_o = take(64*8);
  size_t accs_o  = take(2*8);
  size_t zend = off;
  size_t stat1_o = take(64*8);
  size_t stat2_o = take(64*8);
  size_t wcol_o  = take(96*4);
  size_t w2t_o   = take(1024*4);
  size_t cf_o    = take(32*4);
  size_t part1_o = take(PART_N*4);
  size_t part2_o = take(PART_N*4);
  size_t adj_o   = take(ADJ_N*4);
  size_t hE_o    = take(HE_N*4);
  size_t hP_o    = take(HP_N*4);
  size_t hpre_o  = take(HPRE_N*4);
  size_t opre_o  = take(128*4);
  size_t wbfH_o  = take(WBF_N*2);
  size_t wbfL_o  = take(WBF_N*2);

  if (off > ws_size) {
    k_wsfail<<<(out_size+255)/256, 256, 0, stream>>>((float*)d_out, out_size);
    return;
  }

  float*  feat  = (float*)(ws+feat_o);
  float*  P_g   = (float*)(ws+P_o);
  float*  Q_g   = (float*)(ws+Q_o);
  float*  r_g   = (float*)(ws+r_o);
  double* statE = (double*)(ws+statE_o);
  double* statP = (double*)(ws+statP_o);
  double* statH = (double*)(ws+statH_o);
  double* accs  = (double*)(ws+accs_o);
  double* stat1 = (double*)(ws+stat1_o);
  double* stat2 = (double*)(ws+stat2_o);
  float*  wcol  = (float*)(ws+wcol_o);
  float*  W2T   = (float*)(ws+w2t_o);
  float*  Cf    = (float*)(ws+cf_o);
  float*  part1 = (float*)(ws+part1_o);
  float*  part2 = (float*)(ws+part2_o);
  float*  adj_g = (float*)(ws+adj_o);
  float*  hE_g  = (float*)(ws+hE_o);
  float*  hP_g  = (float*)(ws+hP_o);
  float*  hpre  = (float*)(ws+hpre_o);
  float*  opre  = (float*)(ws+opre_o);
  unsigned short* wbfH = (unsigned short*)(ws+wbfH_o);
  unsigned short* wbfL = (unsigned short*)(ws+wbfL_o);
  float*  out   = (float*)d_out;

  hipMemsetAsync(ws + zstart, 0, zend - zstart, stream);

  k_prep<<<124, 256, 0, stream>>>(w1, w2, w3, entry_w, pool_w, wbfH, wbfL, wcol);
  k_conv<<<cNBC, 256, 0, stream>>>(x, wbfH, wbfL, b1, b2, b3, feat, part1);
  k_reduce_stats<<<32, 256, 0, stream>>>(part1, stat1, cNBC, 32);
  k_foldw<<<1, 256, 0, stream>>>(stat1, oxo_w, oxo_b, W2T, Cf);
  k_mix<<<cNBC, 256, 0, stream>>>(feat, W2T, Cf, part2);
  k_reduce_stats<<<32, 256, 0, stream>>>(part2, stat2, cNBC, 32);
  k_gramow<<<cB*16, 256, 0, stream>>>(feat, stat2, lf_w, lf_b, entry_w, pool_w, P_g, Q_g, r_g);
  k_adjgcn<<<cB, 256, 0, stream>>>(P_g, r_g, gadj, Q_g, wcol, entry_b, pool_b,
                                   adj_g, hE_g, hP_g, statE, statP);
  k_pool<<<cB, 256, 0, stream>>>(adj_g, hE_g, hP_g, statE, statP, pl_w, pl_b,
                                 embed_w, embed_b, hpre, statH, accs);
  k_head<<<cB, 128, 0, stream>>>(hE_g, hpre, statE, statH, fc1_w, fc1_b, fc2_w, fc2_b, fc3_w, fc3_b, opre);
  k_final<<<1, 64, 0, stream>>>(opre, accs, out);
}

// Round 10
// 757.354 us; speedup vs baseline: 1.3388x; 1.0307x over previous
//
#include <hip/hip_runtime.h>
#include <math.h>

typedef float  f32x4 __attribute__((ext_vector_type(4)));
typedef short  s16x4 __attribute__((ext_vector_type(4)));
typedef short  s16x8 __attribute__((ext_vector_type(8)));

// ---------------- problem constants ----------------
constexpr int cB  = 32;
constexpr int cC  = 62;
constexpr int cT  = 1024;
constexpr int cNT = 32;
constexpr int cLT = 708;    // 247+240+221
constexpr int cLT2= 354;
constexpr int cFD = 11328;
constexpr int cNBC = cB*cC;

constexpr size_t FEAT_N = (size_t)cB*cNT*cC*cLT;
constexpr size_t P_N    = (size_t)cB*cC*cC;
constexpr size_t Q_N    = (size_t)cB*cC*96;
constexpr size_t R_N    = (size_t)cB*64;
constexpr size_t PART_N = (size_t)cNBC*64;
constexpr size_t ADJ_N  = P_N;
constexpr size_t HE_N   = (size_t)cB*cC*64;
constexpr size_t HP_N   = (size_t)cB*cC*32;
constexpr size_t HPRE_N = (size_t)cB*32*64;
constexpr int WBF_N = 32*32 + 32*64 + 32*128;   // 7168 bf16 padded conv weights
constexpr size_t WT_N = (size_t)96*cFD;         // entry|pool transposed, bf16 split

__device__ __forceinline__ unsigned short bf16rne(float v){
  unsigned int u = __float_as_uint(v);
  unsigned int r = (u + 0x7fffu + ((u>>16)&1u)) >> 16;
  return (unsigned short)r;
}

// ---------------- prep: conv weights split-bf16 + WT split-bf16 + wcol ----------------
__global__ __launch_bounds__(256) void k_prep(
    const float* __restrict__ w1, const float* __restrict__ w2,
    const float* __restrict__ w3, const float* __restrict__ entry_w,
    const float* __restrict__ pool_w,
    unsigned short* __restrict__ wH, unsigned short* __restrict__ wL,
    float* __restrict__ wcol,
    unsigned short* __restrict__ WTH, unsigned short* __restrict__ WTL)
{
  int blk = blockIdx.x, tid = threadIdx.x;
  if (blk < 28){
    int i = blk*256 + tid;   // 0..7167
    float v;
    if (i < 1024){ int f=i>>5, k=i&31; v = (k<25) ? w1[f*25+k] : 0.f; }
    else if (i < 3072){ int j=i-1024; int f=j>>6, k=j&63; v = (k<51) ? w2[f*51+k] : 0.f; }
    else { v = w3[i-3072]; }
    unsigned short h = bf16rne(v);
    float hf = __uint_as_float(((unsigned int)h)<<16);
    wH[i] = h;
    wL[i] = bf16rne(v - hf);
  } else {
    int j = blk - 28;          // 0..95
    float s = 0.f;
    for (int k=tid;k<cFD;k+=256){
      float v = (j<64) ? entry_w[(size_t)k*64 + j] : pool_w[(size_t)k*32 + (j-64)];
      s += v;
      unsigned short h = bf16rne(v);
      float hf = __uint_as_float(((unsigned int)h)<<16);
      WTH[(size_t)j*cFD + k] = h;
      WTL[(size_t)j*cFD + k] = bf16rne(v - hf);
    }
    __shared__ float red[256];
    red[tid]=s; __syncthreads();
    for (int o=128;o>0;o>>=1){ if(tid<o) red[tid]+=red[tid+o]; __syncthreads(); }
    if (tid==0) wcol[j] = red[0];
  }
}

// ---------------- MFMA conv branch (r9, verified) ----------------
template<int KS, int MT, int WOFF>
__device__ __forceinline__ void mfma_branch(
    const unsigned short* xH, const unsigned short* xL,
    const unsigned short* __restrict__ wHg, const unsigned short* __restrict__ wLg,
    const float* __restrict__ biasg, float* pt, int tid)
{
  int lane = tid & 63, wv = tid >> 6;
  int f = lane & 15, q = lane >> 4;
  int s = lane & 3;
  int a12 = lane & 12;
  s16x8 BH[2][KS], BL[2][KS];
  #pragma unroll
  for (int nt=0; nt<2; nt++)
    #pragma unroll
    for (int ks=0; ks<KS; ks++){
      size_t wo = (size_t)WOFF + (size_t)(nt*16+f)*(KS*32) + ks*32 + q*8;
      BH[nt][ks] = *(const s16x8*)&wHg[wo];
      BL[nt][ks] = *(const s16x8*)&wLg[wo];
    }
  float bv0 = biasg[f], bv1 = biasg[16+f];
  for (int mt = wv; mt < MT; mt += 4){
    f32x4 acc0 = {0.f,0.f,0.f,0.f};
    f32x4 acc1 = {0.f,0.f,0.f,0.f};
    int e0 = mt*16 + a12;
    #pragma unroll
    for (int ks=0; ks<KS; ks++){
      int e = e0 + q*8 + ks*32;
      const unsigned short* ph = xH + s*1160 + e;
      const unsigned short* pl = xL + s*1160 + e;
      s16x4 h0 = *(const s16x4*)ph;
      s16x4 h1 = *(const s16x4*)(ph+4);
      s16x4 l0 = *(const s16x4*)pl;
      s16x4 l1 = *(const s16x4*)(pl+4);
      s16x8 Ah = __builtin_shufflevector(h0,h1,0,1,2,3,4,5,6,7);
      s16x8 Al = __builtin_shufflevector(l0,l1,0,1,2,3,4,5,6,7);
      acc0 = __builtin_amdgcn_mfma_f32_16x16x32_bf16(Ah, BH[0][ks], acc0, 0,0,0);
      acc0 = __builtin_amdgcn_mfma_f32_16x16x32_bf16(Ah, BL[0][ks], acc0, 0,0,0);
      acc0 = __builtin_amdgcn_mfma_f32_16x16x32_bf16(Al, BH[0][ks], acc0, 0,0,0);
      acc1 = __builtin_amdgcn_mfma_f32_16x16x32_bf16(Ah, BH[1][ks], acc1, 0,0,0);
      acc1 = __builtin_amdgcn_mfma_f32_16x16x32_bf16(Ah, BL[1][ks], acc1, 0,0,0);
      acc1 = __builtin_amdgcn_mfma_f32_16x16x32_bf16(Al, BH[1][ks], acc1, 0,0,0);
    }
    float p0=0.f, p1=0.f;
    #pragma unroll
    for (int r=0;r<4;r++){
      float t0 = acc0[r]+bv0; p0 = fmaf(t0,t0,p0);
      float t1 = acc1[r]+bv1; p1 = fmaf(t1,t1,p1);
    }
    pt[(size_t)f*261      + mt*4 + q] = p0;
    pt[(size_t)(16+f)*261 + mt*4 + q] = p1;
  }
}

template<int P, int OFF>
__device__ __forceinline__ void pool_phase(
    const float* pt, float* __restrict__ feat, size_t rstr, size_t base_bc,
    float* tsum, float* tsq, int tid)
{
  bool act = tid < P;
  for (int fi=0; fi<32; fi++){
    float lv = 0.f;
    if (act){
      const float* pp = &pt[(size_t)fi*261 + tid];
      float pooled = (pp[0]+pp[1]+pp[2]+pp[3])*(1.f/16.f);
      lv = __logf(pooled);
      feat[base_bc + (size_t)fi*rstr + OFF + tid] = lv;
    }
    float v = lv, qq = lv*lv;
    #pragma unroll
    for (int o=32;o>0;o>>=1){ v += __shfl_down(v,o,64); qq += __shfl_down(qq,o,64); }
    if ((tid&63)==0){ atomicAdd(&tsum[fi], v); atomicAdd(&tsq[fi], qq); }
  }
}

__global__ __launch_bounds__(256) void k_conv(
    const float* __restrict__ x,
    const unsigned short* __restrict__ wH, const unsigned short* __restrict__ wL,
    const float* __restrict__ b1, const float* __restrict__ b2, const float* __restrict__ b3,
    float* __restrict__ feat, float* __restrict__ part1)
{
  __shared__ unsigned short xH[4*1160];
  __shared__ unsigned short xL[4*1160];
  __shared__ float pt[32*261];
  __shared__ float tsum[32], tsq[32];
  int b = blockIdx.x / cC, c = blockIdx.x % cC;
  int tid = threadIdx.x;
  const float* xg = x + (size_t)(b*cC+c)*cT;
  if (tid<32){ tsum[tid]=0.f; tsq[tid]=0.f; }
  for (int i=tid; i<4*1160; i+=256){
    int s = i / 1160, idx = i - s*1160;
    int src = idx + s;
    float v = (src < 1024) ? xg[src] : 0.f;
    unsigned short h = bf16rne(v);
    float hf = __uint_as_float(((unsigned int)h)<<16);
    xH[i] = h;
    xL[i] = bf16rne(v - hf);
  }
  size_t base_bc = ((size_t)(b*cNT)*cC + c)*cLT;
  size_t rstr = (size_t)cC*cLT;
  __syncthreads();
  mfma_branch<1,63,0>(xH,xL,wH,wL,b1,pt,tid);
  __syncthreads();
  pool_phase<247,0>(pt,feat,rstr,base_bc,tsum,tsq,tid);
  __syncthreads();
  mfma_branch<2,61,1024>(xH,xL,wH,wL,b2,pt,tid);
  __syncthreads();
  pool_phase<240,247>(pt,feat,rstr,base_bc,tsum,tsq,tid);
  __syncthreads();
  mfma_branch<4,57,3072>(xH,xL,wH,wL,b3,pt,tid);
  __syncthreads();
  pool_phase<221,487>(pt,feat,rstr,base_bc,tsum,tsq,tid);
  __syncthreads();
  if (tid<32){
    part1[(size_t)blockIdx.x*64 + tid*2]   = tsum[tid];
    part1[(size_t)blockIdx.x*64 + tid*2+1] = tsq[tid];
  }
}

// ---------------- partial-stat reduction ----------------
__global__ __launch_bounds__(256) void k_reduce_stats(
    const float* __restrict__ part, double* __restrict__ stat, int nblk, int nch)
{
  int ch = blockIdx.x, tid = threadIdx.x;
  double s=0,q=0;
  for (int i=tid;i<nblk;i+=256){
    s += (double)part[(size_t)i*nch*2 + ch*2];
    q += (double)part[(size_t)i*nch*2 + ch*2 + 1];
  }
  __shared__ double ls[256], lq[256];
  ls[tid]=s; lq[tid]=q; __syncthreads();
  for (int o=128;o>0;o>>=1){ if(tid<o){ls[tid]+=ls[tid+o]; lq[tid]+=lq[tid+o];} __syncthreads(); }
  if (tid==0){ stat[ch*2]=ls[0]; stat[ch*2+1]=lq[0]; }
}

// ---------------- fold BN1 into mix weights ----------------
__global__ void k_foldw(const double* __restrict__ stat1,
                        const float* __restrict__ oxo_w, const float* __restrict__ oxo_b,
                        float* __restrict__ W2T, float* __restrict__ Cf)
{
  __shared__ float mu[32], inv[32];
  int tid = threadIdx.x;
  if (tid<32){
    double cnt = (double)cB*cC*cLT;
    double m = stat1[tid*2]/cnt;
    double v = stat1[tid*2+1]/cnt - m*m;
    mu[tid] = (float)m; inv[tid] = (float)(1.0/sqrt(v+1e-5));
  }
  __syncthreads();
  for (int i=tid;i<1024;i+=256){
    int t=i>>5, o=i&31;
    W2T[t*32+o] = oxo_w[o*32+t]*inv[t];
  }
  if (tid<32){
    float cacc = oxo_b[tid];
    for (int t=0;t<32;t++) cacc -= oxo_w[tid*32+t]*inv[t]*mu[t];
    Cf[tid] = cacc;
  }
}

// ---------------- mix: BN folded, all-LDS inner, IN-PLACE ----------------
__global__ __launch_bounds__(256) void k_mix(
    float* __restrict__ feat, const float* __restrict__ W2T,
    const float* __restrict__ Cf, float* __restrict__ part2)
{
  __shared__ float ft[32*240];
  __shared__ float wLh[1024];
  __shared__ float cL[32];
  int b = blockIdx.x / cC, c = blockIdx.x % cC;
  int tid = threadIdx.x;
  int lane = tid & 63, oset = (tid>>6)*8;
  for (int i=tid;i<1024;i+=256) wLh[i] = W2T[i];
  if (tid<32) cL[tid] = Cf[tid];
  float sacc[8]={0,0,0,0,0,0,0,0}, qacc[8]={0,0,0,0,0,0,0,0};
  for (int ch=0; ch<3; ch++){
    int l0 = ch*236;
    __syncthreads();
    for (int g=tid; g<32*59; g+=256){
      int t = g/59, l4 = (g - t*59)*4;
      *(float4*)&ft[t*240+l4] = *(const float4*)&feat[((size_t)(b*cNT+t)*cC + c)*cLT + l0 + l4];
    }
    __syncthreads();
    if (lane < 59){
      float m[8][4];
      #pragma unroll
      for (int f=0;f<8;f++){ float cv=cL[oset+f]; m[f][0]=cv;m[f][1]=cv;m[f][2]=cv;m[f][3]=cv; }
      #pragma unroll 4
      for (int t=0;t<32;t++){
        float4 z = *(const float4*)&ft[t*240 + 4*lane];
        float4 wa = *(const float4*)&wLh[t*32+oset];
        float4 wb = *(const float4*)&wLh[t*32+oset+4];
        float w8a[8] = {wa.x,wa.y,wa.z,wa.w, wb.x,wb.y,wb.z,wb.w};
        #pragma unroll
        for (int f=0;f<8;f++){
          m[f][0]=fmaf(z.x,w8a[f],m[f][0]);
          m[f][1]=fmaf(z.y,w8a[f],m[f][1]);
          m[f][2]=fmaf(z.z,w8a[f],m[f][2]);
          m[f][3]=fmaf(z.w,w8a[f],m[f][3]);
        }
      }
      #pragma unroll
      for (int f=0;f<8;f++){
        float a0 = m[f][0]>0.f ? m[f][0] : 0.01f*m[f][0];
        float a1 = m[f][1]>0.f ? m[f][1] : 0.01f*m[f][1];
        float a2 = m[f][2]>0.f ? m[f][2] : 0.01f*m[f][2];
        float a3 = m[f][3]>0.f ? m[f][3] : 0.01f*m[f][3];
        float v0 = 0.5f*(a0+a1), v1 = 0.5f*(a2+a3);
        float2 st; st.x=v0; st.y=v1;
        *(float2*)&feat[((size_t)(b*cNT+oset+f)*cC + c)*cLT + 118*ch + 2*lane] = st;
        sacc[f] += v0+v1; qacc[f] += v0*v0+v1*v1;
      }
    }
  }
  #pragma unroll
  for (int f=0;f<8;f++){
    float s = sacc[f], q = qacc[f];
    #pragma unroll
    for (int o=32;o>0;o>>=1){ s += __shfl_down(s,o,64); q += __shfl_down(q,o,64); }
    if (lane==0){
      part2[(size_t)blockIdx.x*64 + (oset+f)*2]   = s;
      part2[(size_t)blockIdx.x*64 + (oset+f)*2+1] = q;
    }
  }
}

// ---------------- vprep: V = relu(bn2(raw)*lf_w - lf_b); pack split-bf16 IN PLACE; exact stats ----------------
__global__ __launch_bounds__(256) void k_vprep(
    float* __restrict__ feat, const double* __restrict__ stat2,
    const float* __restrict__ lf_w, const float* __restrict__ lf_b,
    float* __restrict__ r_g, float* __restrict__ SQb)
{
  __shared__ float a_s[32], b_s[32];
  __shared__ float red[256], red2[256];
  int b = blockIdx.x / cC, c = blockIdx.x % cC;
  int tid = threadIdx.x;
  if (tid<32){
    double cnt = (double)cB*cC*cLT2;
    double m = stat2[tid*2]/cnt;
    double v = stat2[tid*2+1]/cnt - m*m;
    float inv = (float)(1.0/sqrt(v+1e-5));
    a_s[tid] = inv;
    b_s[tid] = -(float)m*inv;
  }
  __syncthreads();
  float lb = lf_b[c];
  float S=0.f, SQ=0.f;
  unsigned* featU = (unsigned*)feat;
  for (int i=tid;i<cFD;i+=256){
    int t = i/cLT2, l2 = i - t*cLT2;
    size_t ad = ((size_t)(b*cNT+t)*cC + c)*cLT + l2;
    float raw = feat[ad];
    float z = fmaf(raw, a_s[t], b_s[t]);
    float v = fmaxf(fmaf(z, lf_w[(size_t)c*cFD + i], -lb), 0.f);
    S += v; SQ = fmaf(v,v,SQ);
    unsigned short h = bf16rne(v);
    float hf = __uint_as_float(((unsigned int)h)<<16);
    unsigned short lo = bf16rne(v - hf);
    featU[ad] = (((unsigned)h)<<16) | (unsigned)lo;
  }
  red[tid]=S; red2[tid]=SQ; __syncthreads();
  for (int o=128;o>0;o>>=1){ if(tid<o){red[tid]+=red[tid+o]; red2[tid]+=red2[tid+o];} __syncthreads(); }
  if (tid==0){ r_g[b*64+c]=red[0]; SQb[b*64+c]=red2[0]; }
}

// ---------------- MFMA gram/ow: P = V V^T (62x62), Q = V W (62x96), split-bf16 ----------------
// grid: b(32) x ksplit(16). Stages 64-k chunks of packed V + WT into LDS (stride-72 shorts).
__global__ __launch_bounds__(256) void k_gram(
    const unsigned* __restrict__ featP,
    const unsigned short* __restrict__ WTH, const unsigned short* __restrict__ WTL,
    float* __restrict__ P, float* __restrict__ Q)
{
  __shared__ unsigned short VH[64*72];
  __shared__ unsigned short VL[64*72];
  __shared__ unsigned short WH[96*72];
  __shared__ unsigned short WL[96*72];
  int b = blockIdx.x >> 4, ks = blockIdx.x & 15;
  int tid = threadIdx.x;
  int lane = tid & 63, wv = tid >> 6;
  int cn = lane & 15, q = lane >> 4;
  int nts[3]; int nnt = 0;
  for (int t = wv; t < 10; t += 4) nts[nnt++] = t;
  f32x4 acc[4][3];
  #pragma unroll
  for (int mt=0;mt<4;mt++)
    #pragma unroll
    for (int j=0;j<3;j++) acc[mt][j] = (f32x4){0.f,0.f,0.f,0.f};

  int t0 = (ks*64)/cLT2;
  int l20 = ks*64 - t0*cLT2;
  for (int chunk = ks; chunk < 177; chunk += 16){
    __syncthreads();
    for (int i=tid; i<62*64; i+=256){
      int n = i>>6, k = i&63;
      int fl = l20 + k;
      int cross = (fl >= cLT2);
      int t = t0 + cross;
      int l2 = fl - (cross ? cLT2 : 0);
      unsigned w = featP[((size_t)(b*cNT+t)*cC + n)*cLT + l2];
      VH[n*72+k] = (unsigned short)(w>>16);
      VL[n*72+k] = (unsigned short)(w & 0xffffu);
    }
    {
      int k0 = chunk*64;
      for (int i=tid; i<96*64; i+=256){
        int n = i>>6, k = i&63;
        WH[n*72+k] = WTH[(size_t)n*cFD + k0 + k];
        WL[n*72+k] = WTL[(size_t)n*cFD + k0 + k];
      }
    }
    __syncthreads();
    #pragma unroll
    for (int kst=0;kst<2;kst++){
      s16x8 AH[4], AL[4];
      #pragma unroll
      for (int mt=0;mt<4;mt++){
        AH[mt] = *(const s16x8*)&VH[(mt*16+cn)*72 + kst*32 + q*8];
        AL[mt] = *(const s16x8*)&VL[(mt*16+cn)*72 + kst*32 + q*8];
      }
      for (int j=0;j<nnt;j++){
        int nt = nts[j];
        s16x8 BH, BL;
        if (nt < 4){
          BH = *(const s16x8*)&VH[(nt*16+cn)*72 + kst*32 + q*8];
          BL = *(const s16x8*)&VL[(nt*16+cn)*72 + kst*32 + q*8];
        } else {
          BH = *(const s16x8*)&WH[((nt-4)*16+cn)*72 + kst*32 + q*8];
          BL = *(const s16x8*)&WL[((nt-4)*16+cn)*72 + kst*32 + q*8];
        }
        #pragma unroll
        for (int mt=0;mt<4;mt++){
          acc[mt][j] = __builtin_amdgcn_mfma_f32_16x16x32_bf16(AH[mt], BH, acc[mt][j],0,0,0);
          acc[mt][j] = __builtin_amdgcn_mfma_f32_16x16x32_bf16(AH[mt], BL, acc[mt][j],0,0,0);
          acc[mt][j] = __builtin_amdgcn_mfma_f32_16x16x32_bf16(AL[mt], BH, acc[mt][j],0,0,0);
        }
      }
    }
    l20 += 1024;
    while (l20 >= cLT2){ l20 -= cLT2; t0++; }
  }
  for (int j=0;j<nnt;j++){
    int nt = nts[j];
    for (int mt=0;mt<4;mt++){
      #pragma unroll
      for (int r=0;r<4;r++){
        int m = mt*16 + q*4 + r;
        if (m >= 62) continue;
        float v = acc[mt][j][r];
        if (nt < 4){
          int n = nt*16 + cn;
          if (n < 62) atomicAdd(&P[((size_t)b*cC+m)*cC + n], v);
        } else {
          int jn = (nt-4)*16 + cn;
          atomicAdd(&Q[((size_t)b*cC+m)*96 + jn], v);
        }
      }
    }
  }
}

// ---------------- merged: statC + adjacency + GCN1 ----------------
__global__ __launch_bounds__(256) void k_adjgcn(
    const float* __restrict__ P, const float* __restrict__ r_g,
    const float* __restrict__ SQb,
    const float* __restrict__ gadj, const float* __restrict__ Q,
    const float* __restrict__ wcol,
    const float* __restrict__ entry_b, const float* __restrict__ pool_b,
    float* __restrict__ adj, float* __restrict__ hE, float* __restrict__ hP,
    double* __restrict__ statE, double* __restrict__ statP)
{
  __shared__ float a[3844];
  __shared__ float oL[5952];
  __shared__ float dsh[62];
  __shared__ float rL[62], mL[62], iL[62], wcL[96];
  __shared__ float es[62], eq[62], ps[62], pq[62];
  int b = blockIdx.x, tid = threadIdx.x;
  if (tid<62){
    double S=0, SQ=0;
    for (int b2=0;b2<32;b2++){
      S  += (double)r_g[(size_t)b2*64 + tid];
      SQ += (double)SQb[(size_t)b2*64 + tid];
    }
    double cnt = (double)cB*cFD;
    double m = S/cnt, var = SQ/cnt - m*m;
    mL[tid] = (float)m;
    iL[tid] = (float)(1.0/sqrt(var+1e-5));
    rL[tid] = r_g[(size_t)b*64+tid];
    es[tid]=0.f; eq[tid]=0.f; ps[tid]=0.f; pq[tid]=0.f;
  }
  if (tid>=64 && tid<160) wcL[tid-64]=wcol[tid-64];
  __syncthreads();
  for (int i=tid;i<3844;i+=256){
    int n=i/62, m=i-n*62;
    float sv = (P[(size_t)b*3844+i] - mL[n]*rL[m] - mL[m]*rL[n] + (float)cFD*mL[n]*mL[m]) * iL[n]*iL[m];
    float g = gadj[n*62+m] + gadj[m*62+n];
    float v = sv*g;
    v = v>0.f ? v : 0.f;
    if (n==m) v += 1.f;
    a[i]=v;
  }
  for (int i=tid;i<5952;i+=256){
    int m=i/96, j=i-m*96;
    oL[i] = (Q[(size_t)b*5952+i] - mL[m]*wcL[j]) * iL[m];
  }
  __syncthreads();
  if (tid<62){
    float rsum=0.f;
    for (int m=0;m<62;m++) rsum += a[tid*62+m];
    if (rsum==0.f) rsum=1.f;
    dsh[tid] = 1.0f/sqrtf(rsum);
  }
  __syncthreads();
  for (int i=tid;i<3844;i+=256){
    int n=i/62, m=i-n*62;
    float v = a[i]*dsh[n]*dsh[m];
    a[i] = v;
    adj[(size_t)b*3844+i] = v;
  }
  __syncthreads();
  for (int i=tid;i<5952;i+=256){
    int n=i/96, j=i-n*96;
    float v=0.f;
    for (int m=0;m<62;m++) v = fmaf(a[n*62+m], oL[m*96+j], v);
    if (j<64){
      v -= entry_b[j];
      hE[((size_t)b*62+n)*64 + j] = v;
      atomicAdd(&es[n],v); atomicAdd(&eq[n],v*v);
    } else {
      int j2=j-64;
      v -= pool_b[j2];
      hP[((size_t)b*62+n)*32 + j2] = v;
      atomicAdd(&ps[n],v); atomicAdd(&pq[n],v*v);
    }
  }
  __syncthreads();
  if (tid<62){
    atomicAdd(&statE[tid*2],(double)es[tid]);
    atomicAdd(&statE[tid*2+1],(double)eq[tid]);
    atomicAdd(&statP[tid*2],(double)ps[tid]);
    atomicAdd(&statP[tid*2+1],(double)pq[tid]);
  }
}

// ---------------- dense_diff_pool + in-block assign/bn + embed GCN pre + losses ----------------
__global__ __launch_bounds__(256) void k_pool(
    const float* __restrict__ adj, const float* __restrict__ hEraw,
    const float* __restrict__ hPraw,
    const double* __restrict__ statE, const double* __restrict__ statP,
    const float* __restrict__ pl_w, const float* __restrict__ pl_b,
    const float* __restrict__ embed_w, const float* __restrict__ embed_b,
    float* __restrict__ hpre, double* __restrict__ statH, double* __restrict__ accs)
{
  __shared__ float aL[3844];
  __shared__ float sL[1984];
  __shared__ float hL[3968];
  __shared__ float t1[1984];
  __shared__ float xp[2048];
  __shared__ float ap[1024];
  __shared__ float red[256];
  __shared__ float ksum[32], ksq[32];
  __shared__ float mE[62], iE[62], mP[62], iP[62];
  float* e1 = hL;
  float* sT = t1;
  float* hPL = xp;
  float* plw = ap;
  int b = blockIdx.x, tid = threadIdx.x;
  if (tid<62){
    double cntE = (double)cB*64;
    double m = statE[tid*2]/cntE;
    double v = statE[tid*2+1]/cntE - m*m;
    mE[tid]=(float)m; iE[tid]=(float)(1.0/sqrt(v+1e-5));
    double cntP = (double)cB*32;
    double m2 = statP[tid*2]/cntP;
    double v2 = statP[tid*2+1]/cntP - m2*m2;
    mP[tid]=(float)m2; iP[tid]=(float)(1.0/sqrt(v2+1e-5));
  }
  if (tid<32){ksum[tid]=0.f;ksq[tid]=0.f;}
  for (int i=tid;i<3844;i+=256) aL[i]=adj[(size_t)b*3844+i];
  for (int i=tid;i<1984;i+=256) hPL[i]=hPraw[(size_t)b*1984+i];
  for (int i=tid;i<1024;i+=256) plw[i]=pl_w[i];
  __syncthreads();
  for (int i=tid;i<3968;i+=256){
    int n = i>>6;
    hL[i] = (hEraw[(size_t)b*3968+i]-mE[n])*iE[n];
  }
  int r0 = tid>>5, o = tid&31;
  float entacc = 0.f;
  for (int n=r0; n<62; n+=8){
    float y = pl_b[o];
    float mm = mP[n], ii = iP[n];
    #pragma unroll 8
    for (int j=0;j<32;j++)
      y = fmaf((hPL[n*32+j]-mm)*ii, plw[j*32+o], y);
    float mx = y;
    for (int d=16;d>0;d>>=1) mx = fmaxf(mx, __shfl_xor(mx,d,32));
    float e = expf(y-mx);
    float sum = e;
    for (int d=16;d>0;d>>=1) sum += __shfl_xor(sum,d,32);
    float p = e/sum;
    sL[n*32+o] = p;
    entacc += -p*logf(p+1e-30f);
  }
  red[tid]=entacc; __syncthreads();
  for (int o2=128;o2>0;o2>>=1){ if(tid<o2) red[tid]+=red[tid+o2]; __syncthreads(); }
  if (tid==0) atomicAdd(&accs[1], (double)red[0]);
  __syncthreads();
  for (int i=tid;i<2048;i+=256){
    int k=i>>6, f=i&63;
    float v=0.f;
    for (int n=0;n<62;n++) v = fmaf(sL[n*32+k], hL[n*64+f], v);
    xp[i]=v;
  }
  for (int i=tid;i<1984;i+=256){
    int n=i>>5, k=i&31;
    float v=0.f;
    for (int m=0;m<62;m++) v = fmaf(aL[n*62+m], sL[m*32+k], v);
    t1[i]=v;
  }
  __syncthreads();
  for (int i=tid;i<1024;i+=256){
    int k=i>>5, l=i&31;
    float v=0.f;
    for (int n=0;n<62;n++) v = fmaf(sL[n*32+k], t1[n*32+l], v);
    ap[i]=v;
  }
  __syncthreads();
  for (int i=tid;i<1984;i+=256){
    int k=i/62, n=i-k*62;
    sT[k*62+n] = sL[n*32+k];
  }
  __syncthreads();
  float lacc=0.f;
  for (int i=tid;i<3844;i+=256){
    int n=i/62, m=i-n*62;
    float v=0.f;
    for (int k=0;k<32;k++) v = fmaf(sT[k*62+n], sT[k*62+m], v);
    float d = aL[i]-v+1e-30f;
    lacc = fmaf(d,d,lacc);
  }
  red[tid]=lacc; __syncthreads();
  for (int o2=128;o2>0;o2>>=1){ if(tid<o2) red[tid]+=red[tid+o2]; __syncthreads(); }
  if (tid==0) atomicAdd(&accs[0], (double)red[0]);
  __syncthreads();
  for (int i=tid;i<2048;i+=256){
    int k=i>>6, f=i&63;
    float v=0.f;
    for (int l=0;l<32;l++) v = fmaf(ap[k*32+l], xp[l*64+f], v);
    e1[i]=v;
  }
  __syncthreads();
  for (int i=tid;i<2048;i+=256){
    int k=i>>6, j=i&63;
    float v=0.f;
    for (int f=0;f<64;f++) v = fmaf(e1[k*64+f], embed_w[f*64+j], v);
    v -= embed_b[j];
    hpre[(size_t)b*2048 + i] = v;
    atomicAdd(&ksum[k], v);
    atomicAdd(&ksq[k], v*v);
  }
  __syncthreads();
  if (tid<32){
    atomicAdd(&statH[tid*2],   (double)ksum[tid]);
    atomicAdd(&statH[tid*2+1], (double)ksq[tid]);
  }
}

// ---------------- reps + MLP head ----------------
__global__ __launch_bounds__(128) void k_head(
    const float* __restrict__ hEraw, const float* __restrict__ hpre,
    const double* __restrict__ statE, const double* __restrict__ statH,
    const float* __restrict__ fc1_w, const float* __restrict__ fc1_b,
    const float* __restrict__ fc2_w, const float* __restrict__ fc2_b,
    const float* __restrict__ fc3_w, const float* __restrict__ fc3_b,
    float* __restrict__ o_pre)
{
  __shared__ float o1[128], y1[128], y2[64];
  __shared__ float mk[32], ik[32];
  __shared__ float mE[62], iE[62];
  int b = blockIdx.x, tid = threadIdx.x;
  if (tid<32){
    double cnt = 2048.0;
    double m = statH[tid*2]/cnt;
    double v = statH[tid*2+1]/cnt - m*m;
    mk[tid]=(float)m; ik[tid]=(float)(1.0/sqrt(v+1e-5));
  }
  if (tid>=64 && tid<126){
    int n = tid-64;
    double cnt = (double)cB*64;
    double m = statE[n*2]/cnt;
    double v = statE[n*2+1]/cnt - m*m;
    mE[n]=(float)m; iE[n]=(float)(1.0/sqrt(v+1e-5));
  }
  __syncthreads();
  if (tid<64){
    float s1=0.f;
    for (int n=0;n<62;n++)
      s1 += (hEraw[((size_t)b*62+n)*64+tid]-mE[n])*iE[n];
    o1[tid]=s1;
    float s2=0.f;
    for (int k=0;k<32;k++) s2 += (hpre[(size_t)b*2048 + k*64+tid]-mk[k])*ik[k];
    o1[64+tid]=s2;
  }
  __syncthreads();
  {
    float y = fc1_b[tid];
    for (int j=0;j<128;j++) y = fmaf(o1[j], fc1_w[j*128+tid], y);
    y1[tid] = fmaxf(y,0.f);
  }
  __syncthreads();
  if (tid<64){
    float z = fc2_b[tid];
    for (int j=0;j<128;j++) z = fmaf(y1[j], fc2_w[j*64+tid], z);
    y2[tid]=fmaxf(z,0.f);
  }
  __syncthreads();
  if (tid<4){
    float w = fc3_b[tid];
    for (int j=0;j<64;j++) w = fmaf(y2[j], fc3_w[j*4+tid], w);
    o_pre[b*4+tid]=w;
  }
}

// ---------------- final BN + losses ----------------
__global__ void k_final(const float* __restrict__ o_pre, const double* __restrict__ accs,
                        float* __restrict__ out)
{
  int tid = threadIdx.x;
  if (tid<4){
    float s=0.f,q=0.f;
    for (int b=0;b<32;b++){ float v=o_pre[b*4+tid]; s+=v; q+=v*v; }
    float m = s*(1.f/32.f);
    float var = q*(1.f/32.f) - m*m;
    float inv = 1.0f/sqrtf(var+1e-5f);
    for (int b=0;b<32;b++) out[b*4+tid] = (o_pre[b*4+tid]-m)*inv;
  }
  if (tid==4) out[128] = (float)(sqrt(accs[0])/123008.0);
  if (tid==5) out[129] = (float)(accs[1]/1984.0);
}

__global__ void k_wsfail(float* __restrict__ out, int n)
{
  int i = blockIdx.x*256 + threadIdx.x;
  if (i < n) out[i] = 12345.0f;
}

// ============================================================================
extern "C" void kernel_launch(void* const* d_in, const int* in_sizes, int n_in,
                              void* d_out, int out_size, void* d_ws, size_t ws_size,
                              hipStream_t stream)
{
  const float* x       = (const float*)d_in[0];
  const float* w1      = (const float*)d_in[1];
  const float* b1      = (const float*)d_in[2];
  const float* w2      = (const float*)d_in[3];
  const float* b2      = (const float*)d_in[4];
  const float* w3      = (const float*)d_in[5];
  const float* b3      = (const float*)d_in[6];
  const float* oxo_w   = (const float*)d_in[7];
  const float* oxo_b   = (const float*)d_in[8];
  const float* lf_w    = (const float*)d_in[9];
  const float* lf_b    = (const float*)d_in[10];
  const float* gadj    = (const float*)d_in[11];
  const float* entry_w = (const float*)d_in[12];
  const float* entry_b = (const float*)d_in[13];
  const float* pool_w  = (const float*)d_in[14];
  const float* pool_b  = (const float*)d_in[15];
  const float* pl_w    = (const float*)d_in[16];
  const float* pl_b    = (const float*)d_in[17];
  const float* embed_w = (const float*)d_in[18];
  const float* embed_b = (const float*)d_in[19];
  const float* fc1_w   = (const float*)d_in[20];
  const float* fc1_b   = (const float*)d_in[21];
  const float* fc2_w   = (const float*)d_in[22];
  const float* fc2_b   = (const float*)d_in[23];
  const float* fc3_w   = (const float*)d_in[24];
  const float* fc3_b   = (const float*)d_in[25];

  char* ws = (char*)d_ws;
  size_t off = 0;
  auto take = [&](size_t bytes){ size_t o = off; off = (off + bytes + 15) & ~(size_t)15; return o; };

  size_t feat_o = take(FEAT_N*4);
  size_t zstart = off;
  size_t P_o     = take(P_N*4);
  size_t Q_o     = take(Q_N*4);
  size_t r_o     = take(R_N*4);
  size_t sqb_o   = take(R_N*4);
  size_t statE_o = take(124*8);
  size_t statP_o = take(124*8);
  size_t statH_o = take(64*8);
  size_t accs_o  = take(2*8);
  size_t zend = off;
  size_t stat1_o = take(64*8);
  size_t stat2_o = take(64*8);
  size_t wcol_o  = take(96*4);
  size_t w2t_o   = take(1024*4);
  size_t cf_o    = take(32*4);
  size_t part1_o = take(PART_N*4);
  size_t part2_o = take(PART_N*4);
  size_t adj_o   = take(ADJ_N*4);
  size_t hE_o    = take(HE_N*4);
  size_t hP_o    = take(HP_N*4);
  size_t hpre_o  = take(HPRE_N*4);
  size_t opre_o  = take(128*4);
  size_t wbfH_o  = take(WBF_N*2);
  size_t wbfL_o  = take(WBF_N*2);
  size_t wtH_o   = take(WT_N*2);
  size_t wtL_o   = take(WT_N*2);

  if (off > ws_size) {
    k_wsfail<<<(out_size+255)/256, 256, 0, stream>>>((float*)d_out, out_size);
    return;
  }

  float*  feat  = (float*)(ws+feat_o);
  float*  P_g   = (float*)(ws+P_o);
  float*  Q_g   = (float*)(ws+Q_o);
  float*  r_g   = (float*)(ws+r_o);
  float*  SQb   = (float*)(ws+sqb_o);
  double* statE = (double*)(ws+statE_o);
  double* statP = (double*)(ws+statP_o);
  double* statH = (double*)(ws+statH_o);
  double* accs  = (double*)(ws+accs_o);
  double* stat1 = (double*)(ws+stat1_o);
  double* stat2 = (double*)(ws+stat2_o);
  float*  wcol  = (float*)(ws+wcol_o);
  float*  W2T   = (float*)(ws+w2t_o);
  float*  Cf    = (float*)(ws+cf_o);
  float*  part1 = (float*)(ws+part1_o);
  float*  part2 = (float*)(ws+part2_o);
  float*  adj_g = (float*)(ws+adj_o);
  float*  hE_g  = (float*)(ws+hE_o);
  float*  hP_g  = (float*)(ws+hP_o);
  float*  hpre  = (float*)(ws+hpre_o);
  float*  opre  = (float*)(ws+opre_o);
  unsigned short* wbfH = (unsigned short*)(ws+wbfH_o);
  unsigned short* wbfL = (unsigned short*)(ws+wbfL_o);
  unsigned short* WTH  = (unsigned short*)(ws+wtH_o);
  unsigned short* WTL  = (unsigned short*)(ws+wtL_o);
  float*  out   = (float*)d_out;

  hipMemsetAsync(ws + zstart, 0, zend - zstart, stream);

  k_prep<<<124, 256, 0, stream>>>(w1, w2, w3, entry_w, pool_w, wbfH, wbfL, wcol, WTH, WTL);
  k_conv<<<cNBC, 256, 0, stream>>>(x, wbfH, wbfL, b1, b2, b3, feat, part1);
  k_reduce_stats<<<32, 256, 0, stream>>>(part1, stat1, cNBC, 32);
  k_foldw<<<1, 256, 0, stream>>>(stat1, oxo_w, oxo_b, W2T, Cf);
  k_mix<<<cNBC, 256, 0, stream>>>(feat, W2T, Cf, part2);
  k_reduce_stats<<<32, 256, 0, stream>>>(part2, stat2, cNBC, 32);
  k_vprep<<<cNBC, 256, 0, stream>>>(feat, stat2, lf_w, lf_b, r_g, SQb);
  k_gram<<<cB*16, 256, 0, stream>>>((const unsigned*)feat, WTH, WTL, P_g, Q_g);
  k_adjgcn<<<cB, 256, 0, stream>>>(P_g, r_g, SQb, gadj, Q_g, wcol, entry_b, pool_b,
                                   adj_g, hE_g, hP_g, statE, statP);
  k_pool<<<cB, 256, 0, stream>>>(adj_g, hE_g, hP_g, statE, statP, pl_w, pl_b,
                                 embed_w, embed_b, hpre, statH, accs);
  k_head<<<cB, 128, 0, stream>>>(hE_g, hpre, statE, statH, fc1_w, fc1_b, fc2_w, fc2_b, fc3_w, fc3_b, opre);
  k_final<<<1, 64, 0, stream>>>(opre, accs, out);
}

// Round 11
// 653.507 us; speedup vs baseline: 1.5515x; 1.1589x over previous
//
#include <hip/hip_runtime.h>
#include <math.h>

typedef float  f32x4 __attribute__((ext_vector_type(4)));
typedef short  s16x4 __attribute__((ext_vector_type(4)));
typedef short  s16x8 __attribute__((ext_vector_type(8)));

// ---------------- problem constants ----------------
constexpr int cB  = 32;
constexpr int cC  = 62;
constexpr int cT  = 1024;
constexpr int cNT = 32;
constexpr int cLT = 708;    // 247+240+221
constexpr int cLT2= 354;
constexpr int cFD = 11328;
constexpr int cNBC = cB*cC;

constexpr size_t FEAT_N = (size_t)cB*cNT*cC*cLT;
constexpr size_t P_N    = (size_t)cB*cC*cC;
constexpr size_t Q_N    = (size_t)cB*cC*96;
constexpr size_t R_N    = (size_t)cB*64;
constexpr size_t PART_N = (size_t)cNBC*64;
constexpr size_t ADJ_N  = P_N;
constexpr size_t HE_N   = (size_t)cB*cC*64;
constexpr size_t HP_N   = (size_t)cB*cC*32;
constexpr size_t HPRE_N = (size_t)cB*32*64;
constexpr int WBF_N = 32*32 + 32*64 + 32*128;   // 7168 bf16 padded conv weights
constexpr size_t WT_N = (size_t)96*cFD;         // entry|pool transposed, bf16 split

__device__ __forceinline__ unsigned short bf16rne(float v){
  unsigned int u = __float_as_uint(v);
  unsigned int r = (u + 0x7fffu + ((u>>16)&1u)) >> 16;
  return (unsigned short)r;
}

// ---------------- prep: conv weights split-bf16 + WT split-bf16 + wcol ----------------
__global__ __launch_bounds__(256) void k_prep(
    const float* __restrict__ w1, const float* __restrict__ w2,
    const float* __restrict__ w3, const float* __restrict__ entry_w,
    const float* __restrict__ pool_w,
    unsigned short* __restrict__ wH, unsigned short* __restrict__ wL,
    float* __restrict__ wcol,
    unsigned short* __restrict__ WTH, unsigned short* __restrict__ WTL)
{
  int blk = blockIdx.x, tid = threadIdx.x;
  if (blk < 28){
    int i = blk*256 + tid;   // 0..7167
    float v;
    if (i < 1024){ int f=i>>5, k=i&31; v = (k<25) ? w1[f*25+k] : 0.f; }
    else if (i < 3072){ int j=i-1024; int f=j>>6, k=j&63; v = (k<51) ? w2[f*51+k] : 0.f; }
    else { v = w3[i-3072]; }
    unsigned short h = bf16rne(v);
    float hf = __uint_as_float(((unsigned int)h)<<16);
    wH[i] = h;
    wL[i] = bf16rne(v - hf);
  } else {
    int j = blk - 28;          // 0..95
    float s = 0.f;
    for (int k=tid;k<cFD;k+=256){
      float v = (j<64) ? entry_w[(size_t)k*64 + j] : pool_w[(size_t)k*32 + (j-64)];
      s += v;
      unsigned short h = bf16rne(v);
      float hf = __uint_as_float(((unsigned int)h)<<16);
      WTH[(size_t)j*cFD + k] = h;
      WTL[(size_t)j*cFD + k] = bf16rne(v - hf);
    }
    __shared__ float red[256];
    red[tid]=s; __syncthreads();
    for (int o=128;o>0;o>>=1){ if(tid<o) red[tid]+=red[tid+o]; __syncthreads(); }
    if (tid==0) wcol[j] = red[0];
  }
}

// ---------------- MFMA conv branch (r9, verified) ----------------
template<int KS, int MT, int WOFF>
__device__ __forceinline__ void mfma_branch(
    const unsigned short* xH, const unsigned short* xL,
    const unsigned short* __restrict__ wHg, const unsigned short* __restrict__ wLg,
    const float* __restrict__ biasg, float* pt, int tid)
{
  int lane = tid & 63, wv = tid >> 6;
  int f = lane & 15, q = lane >> 4;
  int s = lane & 3;
  int a12 = lane & 12;
  s16x8 BH[2][KS], BL[2][KS];
  #pragma unroll
  for (int nt=0; nt<2; nt++)
    #pragma unroll
    for (int ks=0; ks<KS; ks++){
      size_t wo = (size_t)WOFF + (size_t)(nt*16+f)*(KS*32) + ks*32 + q*8;
      BH[nt][ks] = *(const s16x8*)&wHg[wo];
      BL[nt][ks] = *(const s16x8*)&wLg[wo];
    }
  float bv0 = biasg[f], bv1 = biasg[16+f];
  for (int mt = wv; mt < MT; mt += 4){
    f32x4 acc0 = {0.f,0.f,0.f,0.f};
    f32x4 acc1 = {0.f,0.f,0.f,0.f};
    int e0 = mt*16 + a12;
    #pragma unroll
    for (int ks=0; ks<KS; ks++){
      int e = e0 + q*8 + ks*32;
      const unsigned short* ph = xH + s*1160 + e;
      const unsigned short* pl = xL + s*1160 + e;
      s16x4 h0 = *(const s16x4*)ph;
      s16x4 h1 = *(const s16x4*)(ph+4);
      s16x4 l0 = *(const s16x4*)pl;
      s16x4 l1 = *(const s16x4*)(pl+4);
      s16x8 Ah = __builtin_shufflevector(h0,h1,0,1,2,3,4,5,6,7);
      s16x8 Al = __builtin_shufflevector(l0,l1,0,1,2,3,4,5,6,7);
      acc0 = __builtin_amdgcn_mfma_f32_16x16x32_bf16(Ah, BH[0][ks], acc0, 0,0,0);
      acc0 = __builtin_amdgcn_mfma_f32_16x16x32_bf16(Ah, BL[0][ks], acc0, 0,0,0);
      acc0 = __builtin_amdgcn_mfma_f32_16x16x32_bf16(Al, BH[0][ks], acc0, 0,0,0);
      acc1 = __builtin_amdgcn_mfma_f32_16x16x32_bf16(Ah, BH[1][ks], acc1, 0,0,0);
      acc1 = __builtin_amdgcn_mfma_f32_16x16x32_bf16(Ah, BL[1][ks], acc1, 0,0,0);
      acc1 = __builtin_amdgcn_mfma_f32_16x16x32_bf16(Al, BH[1][ks], acc1, 0,0,0);
    }
    float p0=0.f, p1=0.f;
    #pragma unroll
    for (int r=0;r<4;r++){
      float t0 = acc0[r]+bv0; p0 = fmaf(t0,t0,p0);
      float t1 = acc1[r]+bv1; p1 = fmaf(t1,t1,p1);
    }
    pt[(size_t)f*261      + mt*4 + q] = p0;
    pt[(size_t)(16+f)*261 + mt*4 + q] = p1;
  }
}

// ---------------- pool: wave owns 8 filters; 64-position chunks; wave-private stats ----------------
template<int P, int OFF>
__device__ __forceinline__ void pool_phase(
    const float* pt, float* __restrict__ feat, size_t rstr, size_t base_bc,
    float* tsum, float* tsq, int tid)
{
  int lane = tid & 63, wv = tid >> 6;
  #pragma unroll
  for (int f8=0; f8<8; f8++){
    int fi = wv*8 + f8;
    float val=0.f, vsq=0.f;
    #pragma unroll
    for (int ch=0; ch<4; ch++){
      int p = ch*64 + lane;
      if (p < P){
        const float* pp = &pt[(size_t)fi*261 + p];
        float pooled = (pp[0]+pp[1]+pp[2]+pp[3])*(1.f/16.f);
        float lv = __logf(pooled);
        feat[base_bc + (size_t)fi*rstr + OFF + p] = lv;
        val += lv; vsq += lv*lv;
      }
    }
    #pragma unroll
    for (int o=32;o>0;o>>=1){ val += __shfl_down(val,o,64); vsq += __shfl_down(vsq,o,64); }
    if (lane==0){ tsum[fi] += val; tsq[fi] += vsq; }   // fi owned by this wave only
  }
}

__global__ __launch_bounds__(256) void k_conv(
    const float* __restrict__ x,
    const unsigned short* __restrict__ wH, const unsigned short* __restrict__ wL,
    const float* __restrict__ b1, const float* __restrict__ b2, const float* __restrict__ b3,
    float* __restrict__ feat, float* __restrict__ part1)
{
  __shared__ unsigned short xH[4*1160];
  __shared__ unsigned short xL[4*1160];
  __shared__ float pt[32*261];
  __shared__ float tsum[32], tsq[32];
  int b = blockIdx.x / cC, c = blockIdx.x % cC;
  int tid = threadIdx.x;
  const float* xg = x + (size_t)(b*cC+c)*cT;
  if (tid<32){ tsum[tid]=0.f; tsq[tid]=0.f; }
  for (int i=tid; i<4*1160; i+=256){
    int s = i / 1160, idx = i - s*1160;
    int src = idx + s;
    float v = (src < 1024) ? xg[src] : 0.f;
    unsigned short h = bf16rne(v);
    float hf = __uint_as_float(((unsigned int)h)<<16);
    xH[i] = h;
    xL[i] = bf16rne(v - hf);
  }
  size_t base_bc = ((size_t)(b*cNT)*cC + c)*cLT;
  size_t rstr = (size_t)cC*cLT;
  __syncthreads();
  mfma_branch<1,63,0>(xH,xL,wH,wL,b1,pt,tid);
  __syncthreads();
  pool_phase<247,0>(pt,feat,rstr,base_bc,tsum,tsq,tid);
  __syncthreads();
  mfma_branch<2,61,1024>(xH,xL,wH,wL,b2,pt,tid);
  __syncthreads();
  pool_phase<240,247>(pt,feat,rstr,base_bc,tsum,tsq,tid);
  __syncthreads();
  mfma_branch<4,57,3072>(xH,xL,wH,wL,b3,pt,tid);
  __syncthreads();
  pool_phase<221,487>(pt,feat,rstr,base_bc,tsum,tsq,tid);
  __syncthreads();
  if (tid<32){
    part1[(size_t)blockIdx.x*64 + tid*2]   = tsum[tid];
    part1[(size_t)blockIdx.x*64 + tid*2+1] = tsq[tid];
  }
}

// ---------------- partial-stat reduction ----------------
__global__ __launch_bounds__(256) void k_reduce_stats(
    const float* __restrict__ part, double* __restrict__ stat, int nblk, int nch)
{
  int ch = blockIdx.x, tid = threadIdx.x;
  double s=0,q=0;
  for (int i=tid;i<nblk;i+=256){
    s += (double)part[(size_t)i*nch*2 + ch*2];
    q += (double)part[(size_t)i*nch*2 + ch*2 + 1];
  }
  __shared__ double ls[256], lq[256];
  ls[tid]=s; lq[tid]=q; __syncthreads();
  for (int o=128;o>0;o>>=1){ if(tid<o){ls[tid]+=ls[tid+o]; lq[tid]+=lq[tid+o];} __syncthreads(); }
  if (tid==0){ stat[ch*2]=ls[0]; stat[ch*2+1]=lq[0]; }
}

// ---------------- fold BN1 into mix weights ----------------
__global__ void k_foldw(const double* __restrict__ stat1,
                        const float* __restrict__ oxo_w, const float* __restrict__ oxo_b,
                        float* __restrict__ W2T, float* __restrict__ Cf)
{
  __shared__ float mu[32], inv[32];
  int tid = threadIdx.x;
  if (tid<32){
    double cnt = (double)cB*cC*cLT;
    double m = stat1[tid*2]/cnt;
    double v = stat1[tid*2+1]/cnt - m*m;
    mu[tid] = (float)m; inv[tid] = (float)(1.0/sqrt(v+1e-5));
  }
  __syncthreads();
  for (int i=tid;i<1024;i+=256){
    int t=i>>5, o=i&31;
    W2T[t*32+o] = oxo_w[o*32+t]*inv[t];
  }
  if (tid<32){
    float cacc = oxo_b[tid];
    for (int t=0;t<32;t++) cacc -= oxo_w[tid*32+t]*inv[t]*mu[t];
    Cf[tid] = cacc;
  }
}

// ---------------- mix: BN folded, all-LDS inner, IN-PLACE ----------------
__global__ __launch_bounds__(256) void k_mix(
    float* __restrict__ feat, const float* __restrict__ W2T,
    const float* __restrict__ Cf, float* __restrict__ part2)
{
  __shared__ float ft[32*240];
  __shared__ float wLh[1024];
  __shared__ float cL[32];
  int b = blockIdx.x / cC, c = blockIdx.x % cC;
  int tid = threadIdx.x;
  int lane = tid & 63, oset = (tid>>6)*8;
  for (int i=tid;i<1024;i+=256) wLh[i] = W2T[i];
  if (tid<32) cL[tid] = Cf[tid];
  float sacc[8]={0,0,0,0,0,0,0,0}, qacc[8]={0,0,0,0,0,0,0,0};
  for (int ch=0; ch<3; ch++){
    int l0 = ch*236;
    __syncthreads();
    for (int g=tid; g<32*59; g+=256){
      int t = g/59, l4 = (g - t*59)*4;
      *(float4*)&ft[t*240+l4] = *(const float4*)&feat[((size_t)(b*cNT+t)*cC + c)*cLT + l0 + l4];
    }
    __syncthreads();
    if (lane < 59){
      float m[8][4];
      #pragma unroll
      for (int f=0;f<8;f++){ float cv=cL[oset+f]; m[f][0]=cv;m[f][1]=cv;m[f][2]=cv;m[f][3]=cv; }
      #pragma unroll 4
      for (int t=0;t<32;t++){
        float4 z = *(const float4*)&ft[t*240 + 4*lane];
        float4 wa = *(const float4*)&wLh[t*32+oset];
        float4 wb = *(const float4*)&wLh[t*32+oset+4];
        float w8a[8] = {wa.x,wa.y,wa.z,wa.w, wb.x,wb.y,wb.z,wb.w};
        #pragma unroll
        for (int f=0;f<8;f++){
          m[f][0]=fmaf(z.x,w8a[f],m[f][0]);
          m[f][1]=fmaf(z.y,w8a[f],m[f][1]);
          m[f][2]=fmaf(z.z,w8a[f],m[f][2]);
          m[f][3]=fmaf(z.w,w8a[f],m[f][3]);
        }
      }
      #pragma unroll
      for (int f=0;f<8;f++){
        float a0 = m[f][0]>0.f ? m[f][0] : 0.01f*m[f][0];
        float a1 = m[f][1]>0.f ? m[f][1] : 0.01f*m[f][1];
        float a2 = m[f][2]>0.f ? m[f][2] : 0.01f*m[f][2];
        float a3 = m[f][3]>0.f ? m[f][3] : 0.01f*m[f][3];
        float v0 = 0.5f*(a0+a1), v1 = 0.5f*(a2+a3);
        float2 st; st.x=v0; st.y=v1;
        *(float2*)&feat[((size_t)(b*cNT+oset+f)*cC + c)*cLT + 118*ch + 2*lane] = st;
        sacc[f] += v0+v1; qacc[f] += v0*v0+v1*v1;
      }
    }
  }
  #pragma unroll
  for (int f=0;f<8;f++){
    float s = sacc[f], q = qacc[f];
    #pragma unroll
    for (int o=32;o>0;o>>=1){ s += __shfl_down(s,o,64); q += __shfl_down(q,o,64); }
    if (lane==0){
      part2[(size_t)blockIdx.x*64 + (oset+f)*2]   = s;
      part2[(size_t)blockIdx.x*64 + (oset+f)*2+1] = q;
    }
  }
}

// ---------------- vstat: exact fp32 rowsum / sumsq of V (no write-back) ----------------
__global__ __launch_bounds__(256) void k_vstat(
    const float* __restrict__ feat, const double* __restrict__ stat2,
    const float* __restrict__ lf_w, const float* __restrict__ lf_b,
    float* __restrict__ r_g, float* __restrict__ SQb)
{
  __shared__ float a_s[32], b_s[32];
  __shared__ float red[256], red2[256];
  int b = blockIdx.x / cC, c = blockIdx.x % cC;
  int tid = threadIdx.x;
  if (tid<32){
    double cnt = (double)cB*cC*cLT2;
    double m = stat2[tid*2]/cnt;
    double v = stat2[tid*2+1]/cnt - m*m;
    float inv = (float)(1.0/sqrt(v+1e-5));
    a_s[tid] = inv;
    b_s[tid] = -(float)m*inv;
  }
  __syncthreads();
  float lb = lf_b[c];
  float S=0.f, SQ=0.f;
  for (int i=tid;i<cFD;i+=256){
    int t = i/cLT2, l2 = i - t*cLT2;
    float raw = feat[((size_t)(b*cNT+t)*cC + c)*cLT + l2];
    float z = fmaf(raw, a_s[t], b_s[t]);
    float v = fmaxf(fmaf(z, lf_w[(size_t)c*cFD + i], -lb), 0.f);
    S += v; SQ = fmaf(v,v,SQ);
  }
  red[tid]=S; red2[tid]=SQ; __syncthreads();
  for (int o=128;o>0;o>>=1){ if(tid<o){red[tid]+=red[tid+o]; red2[tid]+=red2[tid+o];} __syncthreads(); }
  if (tid==0){ r_g[b*64+c]=red[0]; SQb[b*64+c]=red2[0]; }
}

// ---------------- MFMA gram/ow with fused V loader (bn2+lf+split-bf16 in registers) ----------------
__global__ __launch_bounds__(256) void k_gram(
    const float* __restrict__ feat, const double* __restrict__ stat2,
    const float* __restrict__ lf_w, const float* __restrict__ lf_b,
    const unsigned short* __restrict__ WTH, const unsigned short* __restrict__ WTL,
    float* __restrict__ P, float* __restrict__ Q)
{
  __shared__ unsigned short VH[64*72];
  __shared__ unsigned short VL[64*72];
  __shared__ unsigned short WH[96*72];
  __shared__ unsigned short WL[96*72];
  __shared__ float a_s[32], b_s[32], lbs[64];
  int b = blockIdx.x >> 4, ks = blockIdx.x & 15;
  int tid = threadIdx.x;
  int lane = tid & 63, wv = tid >> 6;
  int cn = lane & 15, q = lane >> 4;
  if (tid<32){
    double cnt = (double)cB*cC*cLT2;
    double m = stat2[tid*2]/cnt;
    double v = stat2[tid*2+1]/cnt - m*m;
    float inv = (float)(1.0/sqrt(v+1e-5));
    a_s[tid] = inv;
    b_s[tid] = -(float)m*inv;
  }
  if (tid>=64 && tid<128) lbs[tid-64] = (tid-64<62) ? lf_b[tid-64] : 0.f;
  int nts[3]; int nnt = 0;
  for (int t = wv; t < 10; t += 4) nts[nnt++] = t;
  f32x4 acc[4][3];
  #pragma unroll
  for (int mt=0;mt<4;mt++)
    #pragma unroll
    for (int j=0;j<3;j++) acc[mt][j] = (f32x4){0.f,0.f,0.f,0.f};

  int t0 = (ks*64)/cLT2;
  int l20 = ks*64 - t0*cLT2;
  for (int chunk = ks; chunk < 177; chunk += 16){
    int k0 = chunk*64;
    __syncthreads();
    for (int i=tid; i<62*64; i+=256){
      int n = i>>6, k = i&63;
      int fl = l20 + k;
      int cross = (fl >= cLT2);
      int t = t0 + cross;
      int l2 = fl - (cross ? cLT2 : 0);
      float raw = feat[((size_t)(b*cNT+t)*cC + n)*cLT + l2];
      float z = fmaf(raw, a_s[t], b_s[t]);
      float v = fmaxf(fmaf(z, lf_w[(size_t)n*cFD + k0 + k], -lbs[n]), 0.f);
      unsigned short h = bf16rne(v);
      float hf = __uint_as_float(((unsigned int)h)<<16);
      VH[n*72+k] = h;
      VL[n*72+k] = bf16rne(v - hf);
    }
    for (int i=tid; i<96*64; i+=256){
      int n = i>>6, k = i&63;
      WH[n*72+k] = WTH[(size_t)n*cFD + k0 + k];
      WL[n*72+k] = WTL[(size_t)n*cFD + k0 + k];
    }
    __syncthreads();
    #pragma unroll
    for (int kst=0;kst<2;kst++){
      s16x8 AH[4], AL[4];
      #pragma unroll
      for (int mt=0;mt<4;mt++){
        AH[mt] = *(const s16x8*)&VH[(mt*16+cn)*72 + kst*32 + q*8];
        AL[mt] = *(const s16x8*)&VL[(mt*16+cn)*72 + kst*32 + q*8];
      }
      for (int j=0;j<nnt;j++){
        int nt = nts[j];
        s16x8 BH, BL;
        if (nt < 4){
          BH = *(const s16x8*)&VH[(nt*16+cn)*72 + kst*32 + q*8];
          BL = *(const s16x8*)&VL[(nt*16+cn)*72 + kst*32 + q*8];
        } else {
          BH = *(const s16x8*)&WH[((nt-4)*16+cn)*72 + kst*32 + q*8];
          BL = *(const s16x8*)&WL[((nt-4)*16+cn)*72 + kst*32 + q*8];
        }
        #pragma unroll
        for (int mt=0;mt<4;mt++){
          acc[mt][j] = __builtin_amdgcn_mfma_f32_16x16x32_bf16(AH[mt], BH, acc[mt][j],0,0,0);
          acc[mt][j] = __builtin_amdgcn_mfma_f32_16x16x32_bf16(AH[mt], BL, acc[mt][j],0,0,0);
          acc[mt][j] = __builtin_amdgcn_mfma_f32_16x16x32_bf16(AL[mt], BH, acc[mt][j],0,0,0);
        }
      }
    }
    l20 += 1024;
    while (l20 >= cLT2){ l20 -= cLT2; t0++; }
  }
  for (int j=0;j<nnt;j++){
    int nt = nts[j];
    for (int mt=0;mt<4;mt++){
      #pragma unroll
      for (int r=0;r<4;r++){
        int m = mt*16 + q*4 + r;
        if (m >= 62) continue;
        float v = acc[mt][j][r];
        if (nt < 4){
          int n = nt*16 + cn;
          if (n < 62) atomicAdd(&P[((size_t)b*cC+m)*cC + n], v);
        } else {
          int jn = (nt-4)*16 + cn;
          atomicAdd(&Q[((size_t)b*cC+m)*96 + jn], v);
        }
      }
    }
  }
}

// ---------------- merged: statC + adjacency + GCN1 ----------------
__global__ __launch_bounds__(256) void k_adjgcn(
    const float* __restrict__ P, const float* __restrict__ r_g,
    const float* __restrict__ SQb,
    const float* __restrict__ gadj, const float* __restrict__ Q,
    const float* __restrict__ wcol,
    const float* __restrict__ entry_b, const float* __restrict__ pool_b,
    float* __restrict__ adj, float* __restrict__ hE, float* __restrict__ hP,
    double* __restrict__ statE, double* __restrict__ statP)
{
  __shared__ float a[3844];
  __shared__ float oL[5952];
  __shared__ float dsh[62];
  __shared__ float rL[62], mL[62], iL[62], wcL[96];
  __shared__ float es[62], eq[62], ps[62], pq[62];
  int b = blockIdx.x, tid = threadIdx.x;
  if (tid<62){
    double S=0, SQ=0;
    for (int b2=0;b2<32;b2++){
      S  += (double)r_g[(size_t)b2*64 + tid];
      SQ += (double)SQb[(size_t)b2*64 + tid];
    }
    double cnt = (double)cB*cFD;
    double m = S/cnt, var = SQ/cnt - m*m;
    mL[tid] = (float)m;
    iL[tid] = (float)(1.0/sqrt(var+1e-5));
    rL[tid] = r_g[(size_t)b*64+tid];
    es[tid]=0.f; eq[tid]=0.f; ps[tid]=0.f; pq[tid]=0.f;
  }
  if (tid>=64 && tid<160) wcL[tid-64]=wcol[tid-64];
  __syncthreads();
  for (int i=tid;i<3844;i+=256){
    int n=i/62, m=i-n*62;
    float sv = (P[(size_t)b*3844+i] - mL[n]*rL[m] - mL[m]*rL[n] + (float)cFD*mL[n]*mL[m]) * iL[n]*iL[m];
    float g = gadj[n*62+m] + gadj[m*62+n];
    float v = sv*g;
    v = v>0.f ? v : 0.f;
    if (n==m) v += 1.f;
    a[i]=v;
  }
  for (int i=tid;i<5952;i+=256){
    int m=i/96, j=i-m*96;
    oL[i] = (Q[(size_t)b*5952+i] - mL[m]*wcL[j]) * iL[m];
  }
  __syncthreads();
  if (tid<62){
    float rsum=0.f;
    for (int m=0;m<62;m++) rsum += a[tid*62+m];
    if (rsum==0.f) rsum=1.f;
    dsh[tid] = 1.0f/sqrtf(rsum);
  }
  __syncthreads();
  for (int i=tid;i<3844;i+=256){
    int n=i/62, m=i-n*62;
    float v = a[i]*dsh[n]*dsh[m];
    a[i] = v;
    adj[(size_t)b*3844+i] = v;
  }
  __syncthreads();
  for (int i=tid;i<5952;i+=256){
    int n=i/96, j=i-n*96;
    float v=0.f;
    for (int m=0;m<62;m++) v = fmaf(a[n*62+m], oL[m*96+j], v);
    if (j<64){
      v -= entry_b[j];
      hE[((size_t)b*62+n)*64 + j] = v;
      atomicAdd(&es[n],v); atomicAdd(&eq[n],v*v);
    } else {
      int j2=j-64;
      v -= pool_b[j2];
      hP[((size_t)b*62+n)*32 + j2] = v;
      atomicAdd(&ps[n],v); atomicAdd(&pq[n],v*v);
    }
  }
  __syncthreads();
  if (tid<62){
    atomicAdd(&statE[tid*2],(double)es[tid]);
    atomicAdd(&statE[tid*2+1],(double)eq[tid]);
    atomicAdd(&statP[tid*2],(double)ps[tid]);
    atomicAdd(&statP[tid*2+1],(double)pq[tid]);
  }
}

// ---------------- dense_diff_pool + in-block assign/bn + embed GCN pre + losses ----------------
__global__ __launch_bounds__(256) void k_pool(
    const float* __restrict__ adj, const float* __restrict__ hEraw,
    const float* __restrict__ hPraw,
    const double* __restrict__ statE, const double* __restrict__ statP,
    const float* __restrict__ pl_w, const float* __restrict__ pl_b,
    const float* __restrict__ embed_w, const float* __restrict__ embed_b,
    float* __restrict__ hpre, double* __restrict__ statH, double* __restrict__ accs)
{
  __shared__ float aL[3844];
  __shared__ float sL[1984];
  __shared__ float hL[3968];
  __shared__ float t1[1984];
  __shared__ float xp[2048];
  __shared__ float ap[1024];
  __shared__ float red[256];
  __shared__ float ksum[32], ksq[32];
  __shared__ float mE[62], iE[62], mP[62], iP[62];
  float* e1 = hL;
  float* sT = t1;
  float* hPL = xp;
  float* plw = ap;
  int b = blockIdx.x, tid = threadIdx.x;
  if (tid<62){
    double cntE = (double)cB*64;
    double m = statE[tid*2]/cntE;
    double v = statE[tid*2+1]/cntE - m*m;
    mE[tid]=(float)m; iE[tid]=(float)(1.0/sqrt(v+1e-5));
    double cntP = (double)cB*32;
    double m2 = statP[tid*2]/cntP;
    double v2 = statP[tid*2+1]/cntP - m2*m2;
    mP[tid]=(float)m2; iP[tid]=(float)(1.0/sqrt(v2+1e-5));
  }
  if (tid<32){ksum[tid]=0.f;ksq[tid]=0.f;}
  for (int i=tid;i<3844;i+=256) aL[i]=adj[(size_t)b*3844+i];
  for (int i=tid;i<1984;i+=256) hPL[i]=hPraw[(size_t)b*1984+i];
  for (int i=tid;i<1024;i+=256) plw[i]=pl_w[i];
  __syncthreads();
  for (int i=tid;i<3968;i+=256){
    int n = i>>6;
    hL[i] = (hEraw[(size_t)b*3968+i]-mE[n])*iE[n];
  }
  int r0 = tid>>5, o = tid&31;
  float entacc = 0.f;
  for (int n=r0; n<62; n+=8){
    float y = pl_b[o];
    float mm = mP[n], ii = iP[n];
    #pragma unroll 8
    for (int j=0;j<32;j++)
      y = fmaf((hPL[n*32+j]-mm)*ii, plw[j*32+o], y);
    float mx = y;
    for (int d=16;d>0;d>>=1) mx = fmaxf(mx, __shfl_xor(mx,d,32));
    float e = expf(y-mx);
    float sum = e;
    for (int d=16;d>0;d>>=1) sum += __shfl_xor(sum,d,32);
    float p = e/sum;
    sL[n*32+o] = p;
    entacc += -p*logf(p+1e-30f);
  }
  red[tid]=entacc; __syncthreads();
  for (int o2=128;o2>0;o2>>=1){ if(tid<o2) red[tid]+=red[tid+o2]; __syncthreads(); }
  if (tid==0) atomicAdd(&accs[1], (double)red[0]);
  __syncthreads();
  for (int i=tid;i<2048;i+=256){
    int k=i>>6, f=i&63;
    float v=0.f;
    for (int n=0;n<62;n++) v = fmaf(sL[n*32+k], hL[n*64+f], v);
    xp[i]=v;
  }
  for (int i=tid;i<1984;i+=256){
    int n=i>>5, k=i&31;
    float v=0.f;
    for (int m=0;m<62;m++) v = fmaf(aL[n*62+m], sL[m*32+k], v);
    t1[i]=v;
  }
  __syncthreads();
  for (int i=tid;i<1024;i+=256){
    int k=i>>5, l=i&31;
    float v=0.f;
    for (int n=0;n<62;n++) v = fmaf(sL[n*32+k], t1[n*32+l], v);
    ap[i]=v;
  }
  __syncthreads();
  for (int i=tid;i<1984;i+=256){
    int k=i/62, n=i-k*62;
    sT[k*62+n] = sL[n*32+k];
  }
  __syncthreads();
  float lacc=0.f;
  for (int i=tid;i<3844;i+=256){
    int n=i/62, m=i-n*62;
    float v=0.f;
    for (int k=0;k<32;k++) v = fmaf(sT[k*62+n], sT[k*62+m], v);
    float d = aL[i]-v+1e-30f;
    lacc = fmaf(d,d,lacc);
  }
  red[tid]=lacc; __syncthreads();
  for (int o2=128;o2>0;o2>>=1){ if(tid<o2) red[tid]+=red[tid+o2]; __syncthreads(); }
  if (tid==0) atomicAdd(&accs[0], (double)red[0]);
  __syncthreads();
  for (int i=tid;i<2048;i+=256){
    int k=i>>6, f=i&63;
    float v=0.f;
    for (int l=0;l<32;l++) v = fmaf(ap[k*32+l], xp[l*64+f], v);
    e1[i]=v;
  }
  __syncthreads();
  for (int i=tid;i<2048;i+=256){
    int k=i>>6, j=i&63;
    float v=0.f;
    for (int f=0;f<64;f++) v = fmaf(e1[k*64+f], embed_w[f*64+j], v);
    v -= embed_b[j];
    hpre[(size_t)b*2048 + i] = v;
    atomicAdd(&ksum[k], v);
    atomicAdd(&ksq[k], v*v);
  }
  __syncthreads();
  if (tid<32){
    atomicAdd(&statH[tid*2],   (double)ksum[tid]);
    atomicAdd(&statH[tid*2+1], (double)ksq[tid]);
  }
}

// ---------------- reps + MLP head ----------------
__global__ __launch_bounds__(128) void k_head(
    const float* __restrict__ hEraw, const float* __restrict__ hpre,
    const double* __restrict__ statE, const double* __restrict__ statH,
    const float* __restrict__ fc1_w, const float* __restrict__ fc1_b,
    const float* __restrict__ fc2_w, const float* __restrict__ fc2_b,
    const float* __restrict__ fc3_w, const float* __restrict__ fc3_b,
    float* __restrict__ o_pre)
{
  __shared__ float o1[128], y1[128], y2[64];
  __shared__ float mk[32], ik[32];
  __shared__ float mE[62], iE[62];
  int b = blockIdx.x, tid = threadIdx.x;
  if (tid<32){
    double cnt = 2048.0;
    double m = statH[tid*2]/cnt;
    double v = statH[tid*2+1]/cnt - m*m;
    mk[tid]=(float)m; ik[tid]=(float)(1.0/sqrt(v+1e-5));
  }
  if (tid>=64 && tid<126){
    int n = tid-64;
    double cnt = (double)cB*64;
    double m = statE[n*2]/cnt;
    double v = statE[n*2+1]/cnt - m*m;
    mE[n]=(float)m; iE[n]=(float)(1.0/sqrt(v+1e-5));
  }
  __syncthreads();
  if (tid<64){
    float s1=0.f;
    for (int n=0;n<62;n++)
      s1 += (hEraw[((size_t)b*62+n)*64+tid]-mE[n])*iE[n];
    o1[tid]=s1;
    float s2=0.f;
    for (int k=0;k<32;k++) s2 += (hpre[(size_t)b*2048 + k*64+tid]-mk[k])*ik[k];
    o1[64+tid]=s2;
  }
  __syncthreads();
  {
    float y = fc1_b[tid];
    for (int j=0;j<128;j++) y = fmaf(o1[j], fc1_w[j*128+tid], y);
    y1[tid] = fmaxf(y,0.f);
  }
  __syncthreads();
  if (tid<64){
    float z = fc2_b[tid];
    for (int j=0;j<128;j++) z = fmaf(y1[j], fc2_w[j*64+tid], z);
    y2[tid]=fmaxf(z,0.f);
  }
  __syncthreads();
  if (tid<4){
    float w = fc3_b[tid];
    for (int j=0;j<64;j++) w = fmaf(y2[j], fc3_w[j*4+tid], w);
    o_pre[b*4+tid]=w;
  }
}

// ---------------- final BN + losses ----------------
__global__ void k_final(const float* __restrict__ o_pre, const double* __restrict__ accs,
                        float* __restrict__ out)
{
  int tid = threadIdx.x;
  if (tid<4){
    float s=0.f,q=0.f;
    for (int b=0;b<32;b++){ float v=o_pre[b*4+tid]; s+=v; q+=v*v; }
    float m = s*(1.f/32.f);
    float var = q*(1.f/32.f) - m*m;
    float inv = 1.0f/sqrtf(var+1e-5f);
    for (int b=0;b<32;b++) out[b*4+tid] = (o_pre[b*4+tid]-m)*inv;
  }
  if (tid==4) out[128] = (float)(sqrt(accs[0])/123008.0);
  if (tid==5) out[129] = (float)(accs[1]/1984.0);
}

__global__ void k_wsfail(float* __restrict__ out, int n)
{
  int i = blockIdx.x*256 + threadIdx.x;
  if (i < n) out[i] = 12345.0f;
}

// ============================================================================
extern "C" void kernel_launch(void* const* d_in, const int* in_sizes, int n_in,
                              void* d_out, int out_size, void* d_ws, size_t ws_size,
                              hipStream_t stream)
{
  const float* x       = (const float*)d_in[0];
  const float* w1      = (const float*)d_in[1];
  const float* b1      = (const float*)d_in[2];
  const float* w2      = (const float*)d_in[3];
  const float* b2      = (const float*)d_in[4];
  const float* w3      = (const float*)d_in[5];
  const float* b3      = (const float*)d_in[6];
  const float* oxo_w   = (const float*)d_in[7];
  const float* oxo_b   = (const float*)d_in[8];
  const float* lf_w    = (const float*)d_in[9];
  const float* lf_b    = (const float*)d_in[10];
  const float* gadj    = (const float*)d_in[11];
  const float* entry_w = (const float*)d_in[12];
  const float* entry_b = (const float*)d_in[13];
  const float* pool_w  = (const float*)d_in[14];
  const float* pool_b  = (const float*)d_in[15];
  const float* pl_w    = (const float*)d_in[16];
  const float* pl_b    = (const float*)d_in[17];
  const float* embed_w = (const float*)d_in[18];
  const float* embed_b = (const float*)d_in[19];
  const float* fc1_w   = (const float*)d_in[20];
  const float* fc1_b   = (const float*)d_in[21];
  const float* fc2_w   = (const float*)d_in[22];
  const float* fc2_b   = (const float*)d_in[23];
  const float* fc3_w   = (const float*)d_in[24];
  const float* fc3_b   = (const float*)d_in[25];

  char* ws = (char*)d_ws;
  size_t off = 0;
  auto take = [&](size_t bytes){ size_t o = off; off = (off + bytes + 15) & ~(size_t)15; return o; };

  size_t feat_o = take(FEAT_N*4);
  size_t zstart = off;
  size_t P_o     = take(P_N*4);
  size_t Q_o     = take(Q_N*4);
  size_t statE_o = take(124*8);
  size_t statP_o = take(124*8);
  size_t statH_o = take(64*8);
  size_t accs_o  = take(2*8);
  size_t zend = off;
  size_t r_o     = take(R_N*4);
  size_t sqb_o   = take(R_N*4);
  size_t stat1_o = take(64*8);
  size_t stat2_o = take(64*8);
  size_t wcol_o  = take(96*4);
  size_t w2t_o   = take(1024*4);
  size_t cf_o    = take(32*4);
  size_t part1_o = take(PART_N*4);
  size_t part2_o = take(PART_N*4);
  size_t adj_o   = take(ADJ_N*4);
  size_t hE_o    = take(HE_N*4);
  size_t hP_o    = take(HP_N*4);
  size_t hpre_o  = take(HPRE_N*4);
  size_t opre_o  = take(128*4);
  size_t wbfH_o  = take(WBF_N*2);
  size_t wbfL_o  = take(WBF_N*2);
  size_t wtH_o   = take(WT_N*2);
  size_t wtL_o   = take(WT_N*2);

  if (off > ws_size) {
    k_wsfail<<<(out_size+255)/256, 256, 0, stream>>>((float*)d_out, out_size);
    return;
  }

  float*  feat  = (float*)(ws+feat_o);
  float*  P_g   = (float*)(ws+P_o);
  float*  Q_g   = (float*)(ws+Q_o);
  float*  r_g   = (float*)(ws+r_o);
  float*  SQb   = (float*)(ws+sqb_o);
  double* statE = (double*)(ws+statE_o);
  double* statP = (double*)(ws+statP_o);
  double* statH = (double*)(ws+statH_o);
  double* accs  = (double*)(ws+accs_o);
  double* stat1 = (double*)(ws+stat1_o);
  double* stat2 = (double*)(ws+stat2_o);
  float*  wcol  = (float*)(ws+wcol_o);
  float*  W2T   = (float*)(ws+w2t_o);
  float*  Cf    = (float*)(ws+cf_o);
  float*  part1 = (float*)(ws+part1_o);
  float*  part2 = (float*)(ws+part2_o);
  float*  adj_g = (float*)(ws+adj_o);
  float*  hE_g  = (float*)(ws+hE_o);
  float*  hP_g  = (float*)(ws+hP_o);
  float*  hpre  = (float*)(ws+hpre_o);
  float*  opre  = (float*)(ws+opre_o);
  unsigned short* wbfH = (unsigned short*)(ws+wbfH_o);
  unsigned short* wbfL = (unsigned short*)(ws+wbfL_o);
  unsigned short* WTH  = (unsigned short*)(ws+wtH_o);
  unsigned short* WTL  = (unsigned short*)(ws+wtL_o);
  float*  out   = (float*)d_out;

  hipMemsetAsync(ws + zstart, 0, zend - zstart, stream);

  k_prep<<<124, 256, 0, stream>>>(w1, w2, w3, entry_w, pool_w, wbfH, wbfL, wcol, WTH, WTL);
  k_conv<<<cNBC, 256, 0, stream>>>(x, wbfH, wbfL, b1, b2, b3, feat, part1);
  k_reduce_stats<<<32, 256, 0, stream>>>(part1, stat1, cNBC, 32);
  k_foldw<<<1, 256, 0, stream>>>(stat1, oxo_w, oxo_b, W2T, Cf);
  k_mix<<<cNBC, 256, 0, stream>>>(feat, W2T, Cf, part2);
  k_reduce_stats<<<32, 256, 0, stream>>>(part2, stat2, cNBC, 32);
  k_vstat<<<cNBC, 256, 0, stream>>>(feat, stat2, lf_w, lf_b, r_g, SQb);
  k_gram<<<cB*16, 256, 0, stream>>>(feat, stat2, lf_w, lf_b, WTH, WTL, P_g, Q_g);
  k_adjgcn<<<cB, 256, 0, stream>>>(P_g, r_g, SQb, gadj, Q_g, wcol, entry_b, pool_b,
                                   adj_g, hE_g, hP_g, statE, statP);
  k_pool<<<cB, 256, 0, stream>>>(adj_g, hE_g, hP_g, statE, statP, pl_w, pl_b,
                                 embed_w, embed_b, hpre, statH, accs);
  k_head<<<cB, 128, 0, stream>>>(hE_g, hpre, statE, statH, fc1_w, fc1_b, fc2_w, fc2_b, fc3_w, fc3_b, opre);
  k_final<<<1, 64, 0, stream>>>(opre, accs, out);
}